// Round 2
// baseline (375.856 us; speedup 1.0000x reference)
//
#include <hip/hip_runtime.h>
#include <hip/hip_fp16.h>
#include <math.h>

#define F_IN 128
#define H 16
#define C 40
#define K_HOPS 10
#define ALPHA 0.1f
#define BN_EPS 1e-5f

#define RB 256          // nodes per bucket
#define RB_BITS 8
#define NBKT_MAX 512    // ceil(100000/256)=391
#define SRC_MASK 0x1FFFF
#define PADQ 16         // node segment padded to multiple of 16 entries (even pair split)
#define NDUMMY 2048     // dummy zero rows spread over L2
#define SPLIT 4         // scatter blocks per bucket

typedef int v4i __attribute__((ext_vector_type(4)));

// ---------------- zero: gbcnt=0, stats=0, dummy rows of both tables = 0 ----------------
__global__ void k_zero(int* __restrict__ gbcnt, float* __restrict__ stats,
                       __half* __restrict__ h1h, __half* __restrict__ hh, int n) {
    int id = blockIdx.x * blockDim.x + threadIdx.x;
    if (id < NBKT_MAX) gbcnt[id] = 0;
    if (id < 32) stats[id] = 0.0f;
    // NDUMMY rows x 16 halves = 64KB per table = 16384 ints
    int* z1 = (int*)(h1h + (size_t)n * H);
    int* z2 = (int*)(hh + (size_t)n * H);
    if (id < NDUMMY * H / 2) { z1[id] = 0; z2[id] = 0; }
}

// ---------------- bucket counts ----------------
__global__ __launch_bounds__(256) void k_bcnt(const int* __restrict__ dst,
                                              int* __restrict__ gbcnt, int e) {
    __shared__ int hist[NBKT_MAX];
    int t = threadIdx.x;
    hist[t] = 0; hist[t + 256] = 0;
    __syncthreads();
    int base = blockIdx.x * 4096;
    int endi = base + 4096; if (endi > e) endi = e;
    for (int i = base + t; i < endi; i += 256)
        atomicAdd(&hist[dst[i] >> RB_BITS], 1);
    __syncthreads();
    for (int b = t; b < NBKT_MAX; b += 256)
        if (hist[b]) atomicAdd(&gbcnt[b], hist[b]);
}

// ---------------- scans: raw bucket offsets (temp) + padded csr bases ----------------
__global__ __launch_bounds__(512) void k_bscan(const int* __restrict__ gbcnt,
                                               int* __restrict__ gboff,
                                               int* __restrict__ gcur,
                                               int* __restrict__ gcsr, int nbkt) {
    __shared__ int sd[512];
    int t = threadIdx.x;
    int v = (t < nbkt) ? gbcnt[t] : 0;
    sd[t] = v;
    __syncthreads();
    for (int off = 1; off < 512; off <<= 1) {
        int tmp = (t >= off) ? sd[t - off] : 0;
        __syncthreads();
        sd[t] += tmp;
        __syncthreads();
    }
    if (t < nbkt) { int o = sd[t] - v; gboff[t] = o; gcur[t] = o; }
    if (t == nbkt - 1) gboff[nbkt] = sd[t];
    __syncthreads();
    // padded csr capacity: worst-case per-node padding (PADQ-1 each)
    int cap = (t < nbkt) ? ((v + RB * (PADQ - 1) + PADQ - 1) & ~(PADQ - 1)) : 0;
    sd[t] = cap;
    __syncthreads();
    for (int off = 1; off < 512; off <<= 1) {
        int tmp = (t >= off) ? sd[t - off] : 0;
        __syncthreads();
        sd[t] += tmp;
        __syncthreads();
    }
    if (t < nbkt) gcsr[t] = sd[t] - cap;
}

// ---------------- bin edges into bucket runs (dense 4B writes) ----------------
#define BIN_CHUNK 4096
__global__ __launch_bounds__(256) void k_bin(const int* __restrict__ src,
                                             const int* __restrict__ dst,
                                             int* __restrict__ gcur,
                                             int* __restrict__ temp, int e) {
    __shared__ int hist[NBKT_MAX];
    __shared__ int lcur[NBKT_MAX];
    int t = threadIdx.x;
    hist[t] = 0; hist[t + 256] = 0;
    __syncthreads();
    int base = blockIdx.x * BIN_CHUNK;
    int ss[16], dd[16];
#pragma unroll
    for (int i = 0; i < 16; ++i) {
        int idx = base + i * 256 + t;
        if (idx < e) {
            ss[i] = src[idx]; dd[i] = dst[idx];
            atomicAdd(&hist[dd[i] >> RB_BITS], 1);
        } else ss[i] = -1;
    }
    __syncthreads();
    for (int b = t; b < NBKT_MAX; b += 256) {
        int hv = hist[b];
        lcur[b] = hv ? atomicAdd(&gcur[b], hv) : 0;
    }
    __syncthreads();
#pragma unroll
    for (int i = 0; i < 16; ++i) {
        if (ss[i] >= 0) {
            int d = dd[i];
            int b = d >> RB_BITS;
            int pos = atomicAdd(&lcur[b], 1);
            temp[pos] = ss[i] | ((d & (RB - 1)) << 17);
        }
    }
}

// ---------------- per-bucket hist -> padded CSR layout; deg->dinv;
//                  degree-sorted node order (ostart/oend/onode); global cursors ----------------
__global__ __launch_bounds__(256) void k_sort(const int* __restrict__ gboff,
                                              const int* __restrict__ gcsr,
                                              const int* __restrict__ temp,
                                              int* __restrict__ csr,
                                              int* __restrict__ ostart,
                                              int* __restrict__ oend,
                                              int* __restrict__ onode,
                                              int* __restrict__ ncur,
                                              float* __restrict__ dinv, int n) {
    __shared__ int hist[RB];
    __shared__ int psum[256];
    __shared__ int qh[64];
    __shared__ int qb[64];
    int t = threadIdx.x;
    int bkt = blockIdx.x;
    int start = gboff[bkt], endi = gboff[bkt + 1];
    hist[t] = 0;
    if (t < 64) qh[t] = 0;
    __syncthreads();
    for (int k = start + t; k < endi; k += 256)
        atomicAdd(&hist[temp[k] >> 17], 1);
    __syncthreads();
    int node = (bkt << RB_BITS) + t;
    int h = hist[t];
    int p = (h + PADQ - 1) & ~(PADQ - 1);
    bool va = (node < n);
    if (va) dinv[node] = rsqrtf((float)(h + 1));
    psum[t] = p;
    __syncthreads();
    for (int off = 1; off < 256; off <<= 1) {
        int tmp = (t >= off) ? psum[t - off] : 0;
        __syncthreads();
        psum[t] += tmp;
        __syncthreads();
    }
    int pexcl = psum[t] - p;
    int s0 = gcsr[bkt] + pexcl;
    // degree bins (iterations = padded/16); invalid nodes go to bin 0 with onode=-1
    int q = va ? min(p >> 4, 63) : 0;
    int r = atomicAdd(&qh[q], 1);
    __syncthreads();
    if (t == 0) {
        int run = 0;
        for (int i = 0; i < 64; ++i) { qb[i] = run; run += qh[i]; }
    }
    __syncthreads();
    int ga = (bkt << RB_BITS) + qb[q] + r;
    ostart[ga] = s0; oend[ga] = s0 + p; onode[ga] = va ? node : -1;
    if (va) ncur[node] = s0;
    // pad with distinct dummy zero rows
    for (int i = s0 + h; i < s0 + p; ++i) csr[i] = n + (i & (NDUMMY - 1));
}

// ---------------- scatter edges into csr (SPLIT blocks per bucket, global cursors) ----------------
__global__ __launch_bounds__(256) void k_scat(const int* __restrict__ gboff,
                                              const int* __restrict__ temp,
                                              int* __restrict__ ncur,
                                              int* __restrict__ csr) {
    int t = threadIdx.x;
    int bkt = blockIdx.x / SPLIT;
    int part = blockIdx.x - bkt * SPLIT;
    int start = gboff[bkt], endi = gboff[bkt + 1];
    int len = endi - start;
    int c0 = start + (len * part) / SPLIT;
    int c1 = start + (len * (part + 1)) / SPLIT;
    int nodeBase = bkt << RB_BITS;
    for (int k = c0 + t; k < c1; k += 256) {
        int v = temp[k];
        int nd = nodeBase + (v >> 17);
        int pos = atomicAdd(&ncur[nd], 1);
        csr[pos] = v & SRC_MASK;
    }
}

// ---------------- h1' = dinv .* (x @ W1) -> fp16 table ----------------
__global__ __launch_bounds__(256) void k_mm1(const float* __restrict__ x,
                                             const float* __restrict__ W1,
                                             const float* __restrict__ dinv,
                                             __half* __restrict__ h1h, int n) {
    __shared__ float xs[16 * 132];
    __shared__ float ws[128 * 16];
    int t = threadIdx.x;
    int node0 = blockIdx.x * 16;
#pragma unroll
    for (int r = 0; r < 8; ++r) {
        int idx = t + r * 256;
        int nl = idx >> 7, k = idx & 127;
        int nn = node0 + nl; if (nn >= n) nn = n - 1;
        xs[nl * 132 + k] = x[(size_t)nn * F_IN + k];
        ws[idx] = W1[idx];
    }
    __syncthreads();
    int nl = t >> 4, j = t & 15;
    float acc = 0.0f;
#pragma unroll 8
    for (int k = 0; k < 128; ++k)
        acc = fmaf(xs[nl * 132 + k], ws[k * 16 + j], acc);
    int node = node0 + nl;
    if (node < n) h1h[(size_t)node * H + j] = __float2half(acc * dinv[node]);
}

__device__ __forceinline__ void acc8(float* a, int4 gv) {
    const __half2* h = reinterpret_cast<const __half2*>(&gv);
    float2 f0 = __half22float2(h[0]);
    float2 f1 = __half22float2(h[1]);
    float2 f2 = __half22float2(h[2]);
    float2 f3 = __half22float2(h[3]);
    a[0] += f0.x; a[1] += f0.y; a[2] += f1.x; a[3] += f1.y;
    a[4] += f2.x; a[5] += f2.y; a[6] += f3.x; a[7] += f3.y;
}

// ---------------- gather conv1: 4 lanes/node (2 pairs x 16B), degree-sorted order;
//                  + bias + ReLU + BN stats ----------------
__global__ __launch_bounds__(256) void k_gather1(const int* __restrict__ ostart,
                                                 const int* __restrict__ oend,
                                                 const int* __restrict__ onode,
                                                 const int* __restrict__ csr,
                                                 const __half* __restrict__ h1h,
                                                 const float* __restrict__ dinv,
                                                 const float* __restrict__ b1,
                                                 float* __restrict__ hout,
                                                 float* __restrict__ stats, int n) {
    __shared__ float sm[32];
    __shared__ float b1s[16];
    int t = threadIdx.x;
    if (t < 32) sm[t] = 0.0f;
    if (t < 16) b1s[t] = b1[t];
    __syncthreads();
    int idx = blockIdx.x * 256 + t;
    int g = idx >> 2;
    int L = idx & 3, p = L >> 1, jj = L & 1;
    int node = __builtin_nontemporal_load(onode + g);
    float a[8];
#pragma unroll
    for (int k = 0; k < 8; ++k) a[k] = 0.0f;
    const int4* tab = reinterpret_cast<const int4*>(h1h);
    if (node >= 0) {
        int c  = (__builtin_nontemporal_load(ostart + g) >> 2) + (p << 1);
        int ce = __builtin_nontemporal_load(oend + g) >> 2;
        const v4i* csr4 = reinterpret_cast<const v4i*>(csr);
        for (; c < ce; c += 4) {
            v4i e0 = __builtin_nontemporal_load(csr4 + c);
            v4i e1 = __builtin_nontemporal_load(csr4 + c + 1);
            int4 g0 = tab[(size_t)e0.x * 2 + jj];
            int4 g1 = tab[(size_t)e0.y * 2 + jj];
            int4 g2 = tab[(size_t)e0.z * 2 + jj];
            int4 g3 = tab[(size_t)e0.w * 2 + jj];
            int4 g4 = tab[(size_t)e1.x * 2 + jj];
            int4 g5 = tab[(size_t)e1.y * 2 + jj];
            int4 g6 = tab[(size_t)e1.z * 2 + jj];
            int4 g7 = tab[(size_t)e1.w * 2 + jj];
            acc8(a, g0); acc8(a, g1); acc8(a, g2); acc8(a, g3);
            acc8(a, g4); acc8(a, g5); acc8(a, g6); acc8(a, g7);
        }
    }
    // combine the two pairs (lane ^ 2)
#pragma unroll
    for (int k = 0; k < 8; ++k) a[k] += __shfl_xor(a[k], 2);
    float din = 0.0f;
    int4 sv = make_int4(0, 0, 0, 0);
    if (node >= 0) {
        din = dinv[node];
        sv = tab[(size_t)node * 2 + jj];
    }
    float v[8];
    {
        const __half2* h = reinterpret_cast<const __half2*>(&sv);
        float2 f0 = __half22float2(h[0]), f1 = __half22float2(h[1]);
        float2 f2 = __half22float2(h[2]), f3 = __half22float2(h[3]);
        float s8[8] = { f0.x, f0.y, f1.x, f1.y, f2.x, f2.y, f3.x, f3.y };
        bool writer = (node >= 0) && (p == 0);
#pragma unroll
        for (int k = 0; k < 8; ++k) {
            float val = fmaxf(din * (a[k] + s8[k]) + b1s[jj * 8 + k], 0.0f);
            v[k] = writer ? val : 0.0f;
        }
        if (writer) {
            float4* o = reinterpret_cast<float4*>(hout + (size_t)node * H + jj * 8);
            o[0] = make_float4(v[0], v[1], v[2], v[3]);
            o[1] = make_float4(v[4], v[5], v[6], v[7]);
        }
    }
    // BN stats: reduce over wave (p1 lanes are zero, so each node counted once)
#pragma unroll
    for (int k = 0; k < 8; ++k) {
        float s1 = v[k], s2 = v[k] * v[k];
        s1 += __shfl_xor(s1, 2);  s2 += __shfl_xor(s2, 2);
        s1 += __shfl_xor(s1, 4);  s2 += __shfl_xor(s2, 4);
        s1 += __shfl_xor(s1, 8);  s2 += __shfl_xor(s2, 8);
        s1 += __shfl_xor(s1, 16); s2 += __shfl_xor(s2, 16);
        s1 += __shfl_xor(s1, 32); s2 += __shfl_xor(s2, 32);
        if ((t & 63) < 2) {
            atomicAdd(&sm[jj * 8 + k], s1);
            atomicAdd(&sm[16 + jj * 8 + k], s2);
        }
    }
    __syncthreads();
    if (t < 32) atomicAdd(&stats[t], sm[t]);
}

// ---------------- BN coefficients ----------------
__global__ void k_bncoef(float* __restrict__ stats, const float* __restrict__ gamma,
                         const float* __restrict__ beta, float nf) {
    int j = threadIdx.x;
    if (j < 16) {
        float mean = stats[j] / nf;
        float var = stats[16 + j] / nf - mean * mean;
        float a = gamma[j] * rsqrtf(var + BN_EPS);
        float c = beta[j] - mean * a;
        stats[j] = a;
        stats[16 + j] = c;
    }
}

// ---------------- BN apply + K_HOPS residual blocks -> scaled fp16 table ----------------
__global__ __launch_bounds__(256) void k_hops(const float* __restrict__ h,
                                              __half* __restrict__ hh,
                                              const float* __restrict__ stats,
                                              const float* __restrict__ Wl,
                                              const float* __restrict__ bl,
                                              const float* __restrict__ dinv, int n) {
    __shared__ float wl[256], bls[16], av[16], cv[16];
    int t = threadIdx.x;
    // transposed layout: wl[j*16+k] = Wl[k*16+j] -> contiguous k (ds_read_b128)
    wl[t] = Wl[(t & 15) * 16 + (t >> 4)];
    if (t < 16) { bls[t] = bl[t]; av[t] = stats[t]; cv[t] = stats[16 + t]; }
    __syncthreads();
    int node = blockIdx.x * 256 + t;
    if (node >= n) return;
    float hr[16];
    {
        const float4* hp = reinterpret_cast<const float4*>(h + (size_t)node * H);
        float4 v0 = hp[0], v1 = hp[1], v2 = hp[2], v3 = hp[3];
        hr[0] = v0.x; hr[1] = v0.y; hr[2] = v0.z; hr[3] = v0.w;
        hr[4] = v1.x; hr[5] = v1.y; hr[6] = v1.z; hr[7] = v1.w;
        hr[8] = v2.x; hr[9] = v2.y; hr[10] = v2.z; hr[11] = v2.w;
        hr[12] = v3.x; hr[13] = v3.y; hr[14] = v3.z; hr[15] = v3.w;
    }
#pragma unroll
    for (int j = 0; j < 16; ++j) hr[j] = hr[j] * av[j] + cv[j];
    for (int it = 0; it < K_HOPS; ++it) {
        float tmp[16];
#pragma unroll
        for (int j = 0; j < 16; ++j) {
            float a = bls[j];
#pragma unroll
            for (int k = 0; k < 16; ++k) a = fmaf(hr[k], wl[j * 16 + k], a);
            tmp[j] = fmaxf(a, 0.0f);
        }
#pragma unroll
        for (int j = 0; j < 16; ++j) hr[j] = ALPHA * tmp[j] + (1.0f - ALPHA) * hr[j];
    }
    {
        float din = dinv[node];
        __half2 ph[8];
#pragma unroll
        for (int i = 0; i < 8; ++i)
            ph[i] = __floats2half2_rn(hr[2 * i] * din, hr[2 * i + 1] * din);
        int4* hp = reinterpret_cast<int4*>(hh + (size_t)node * H);
        hp[0] = *reinterpret_cast<int4*>(&ph[0]);
        hp[1] = *reinterpret_cast<int4*>(&ph[4]);
    }
}

// ---------------- gather conv2: 4 lanes/node (2 pairs x 16B); + self-loop ----------------
__global__ __launch_bounds__(256) void k_gather2(const int* __restrict__ ostart,
                                                 const int* __restrict__ oend,
                                                 const int* __restrict__ onode,
                                                 const int* __restrict__ csr,
                                                 const __half* __restrict__ hh,
                                                 const float* __restrict__ dinv,
                                                 float* __restrict__ agg, int n) {
    int t = threadIdx.x;
    int idx = blockIdx.x * 256 + t;
    int g = idx >> 2;
    int L = idx & 3, p = L >> 1, jj = L & 1;
    int node = __builtin_nontemporal_load(onode + g);
    float a[8];
#pragma unroll
    for (int k = 0; k < 8; ++k) a[k] = 0.0f;
    const int4* tab = reinterpret_cast<const int4*>(hh);
    if (node >= 0) {
        int c  = (__builtin_nontemporal_load(ostart + g) >> 2) + (p << 1);
        int ce = __builtin_nontemporal_load(oend + g) >> 2;
        const v4i* csr4 = reinterpret_cast<const v4i*>(csr);
        for (; c < ce; c += 4) {
            v4i e0 = __builtin_nontemporal_load(csr4 + c);
            v4i e1 = __builtin_nontemporal_load(csr4 + c + 1);
            int4 g0 = tab[(size_t)e0.x * 2 + jj];
            int4 g1 = tab[(size_t)e0.y * 2 + jj];
            int4 g2 = tab[(size_t)e0.z * 2 + jj];
            int4 g3 = tab[(size_t)e0.w * 2 + jj];
            int4 g4 = tab[(size_t)e1.x * 2 + jj];
            int4 g5 = tab[(size_t)e1.y * 2 + jj];
            int4 g6 = tab[(size_t)e1.z * 2 + jj];
            int4 g7 = tab[(size_t)e1.w * 2 + jj];
            acc8(a, g0); acc8(a, g1); acc8(a, g2); acc8(a, g3);
            acc8(a, g4); acc8(a, g5); acc8(a, g6); acc8(a, g7);
        }
    }
#pragma unroll
    for (int k = 0; k < 8; ++k) a[k] += __shfl_xor(a[k], 2);
    if (node >= 0 && p == 0) {
        float din = dinv[node];
        int4 sv = tab[(size_t)node * 2 + jj];
        const __half2* h = reinterpret_cast<const __half2*>(&sv);
        float2 f0 = __half22float2(h[0]), f1 = __half22float2(h[1]);
        float2 f2 = __half22float2(h[2]), f3 = __half22float2(h[3]);
        float s8[8] = { f0.x, f0.y, f1.x, f1.y, f2.x, f2.y, f3.x, f3.y };
        float v[8];
#pragma unroll
        for (int k = 0; k < 8; ++k) v[k] = din * (a[k] + s8[k]);
        float4* o = reinterpret_cast<float4*>(agg + (size_t)node * H + jj * 8);
        o[0] = make_float4(v[0], v[1], v[2], v[3]);
        o[1] = make_float4(v[4], v[5], v[6], v[7]);
    }
}

// ---------------- final: agg2 @ W2 + b2 -> log_softmax ----------------
__global__ __launch_bounds__(256) void k_final(const float* __restrict__ agg2,
                                               const float* __restrict__ W2,
                                               const float* __restrict__ b2,
                                               float* __restrict__ out, int n) {
    __shared__ float w2s[16 * 40];
    __shared__ float b2s[40];
    __shared__ float ostage[40 * 257];
    int t = threadIdx.x;
    for (int i = t; i < 640; i += 256) w2s[i] = W2[i];
    if (t < 40) b2s[t] = b2[t];
    __syncthreads();
    int node = blockIdx.x * 256 + t;
    if (node < n) {
        float g[16];
        const float4* ap = reinterpret_cast<const float4*>(agg2 + (size_t)node * H);
#pragma unroll
        for (int r = 0; r < 4; ++r) {
            float4 a = ap[r];
            g[r * 4 + 0] = a.x; g[r * 4 + 1] = a.y; g[r * 4 + 2] = a.z; g[r * 4 + 3] = a.w;
        }
        float z[40];
#pragma unroll
        for (int j = 0; j < 40; ++j) {
            float a = b2s[j];
#pragma unroll
            for (int k = 0; k < 16; ++k) a = fmaf(g[k], w2s[k * 40 + j], a);
            z[j] = a;
        }
        float m = z[0];
#pragma unroll
        for (int j = 1; j < 40; ++j) m = fmaxf(m, z[j]);
        float s = 0.0f;
#pragma unroll
        for (int j = 0; j < 40; ++j) s += expf(z[j] - m);
        float lse = m + logf(s);
#pragma unroll
        for (int j = 0; j < 40; ++j) ostage[j * 257 + t] = z[j] - lse;
    }
    __syncthreads();
    int nodes = n - blockIdx.x * 256;
    if (nodes > 256) nodes = 256;
    int total = nodes * 40;
    size_t base = (size_t)blockIdx.x * 256 * 40;
    for (int i = t; i < total; i += 256) {
        int nl = i / 40;
        int j = i - nl * 40;
        out[base + i] = ostage[j * 257 + nl];
    }
}

extern "C" void kernel_launch(void* const* d_in, const int* in_sizes, int n_in,
                              void* d_out, int out_size, void* d_ws, size_t ws_size,
                              hipStream_t stream) {
    const float* x     = (const float*)d_in[0];
    const int*   src   = (const int*)d_in[1];
    const int*   dst   = (const int*)d_in[2];
    const float* W1    = (const float*)d_in[3];
    const float* b1    = (const float*)d_in[4];
    const float* gamma = (const float*)d_in[5];
    const float* beta  = (const float*)d_in[6];
    const float* Wl    = (const float*)d_in[7];
    const float* bl    = (const float*)d_in[8];
    const float* W2    = (const float*)d_in[9];
    const float* b2    = (const float*)d_in[10];
    float* out = (float*)d_out;

    int n = in_sizes[0] / F_IN;   // 100000
    int e = in_sizes[1];          // 3200000
    int nbkt = (n + RB - 1) >> RB_BITS;   // 391
    int nAlign = (n + 15) & ~15;
    int nG = nbkt * RB;                                      // ordered-node slots
    size_t csrCap = (size_t)e + (size_t)nG * (PADQ - 1) + (size_t)nbkt * PADQ + 64;
    size_t hTileB = (size_t)nAlign * H * 4;                  // 6.4 MB
    size_t unionB = (size_t)e * 4;                           // temp (12.8 MB)
    if (unionB < 2 * hTileB) unionB = 2 * hTileB;            // also holds hbuf+agg2 later

    char* wsb = (char*)d_ws;
    int*    csr      = (int*)wsb;      wsb += csrCap * 4;
    char*   uni      = wsb;            wsb += unionB;
    int*    temp     = (int*)uni;                  // alive: k_bin .. k_scat
    float*  hbuf     = (float*)uni;                // alive: k_gather1 .. k_hops
    float*  agg2     = (float*)(uni + hTileB);     // alive: k_gather2 .. k_final
    int*    ostart   = (int*)wsb;      wsb += (size_t)(nG + 16) * 4;
    int*    oend     = (int*)wsb;      wsb += (size_t)(nG + 16) * 4;
    int*    onode    = (int*)wsb;      wsb += (size_t)(nG + 16) * 4;
    int*    ncur     = (int*)wsb;      wsb += (size_t)(nAlign + 16) * 4;
    float*  dinv     = (float*)wsb;    wsb += (size_t)nAlign * 4;
    int*    gbcnt    = (int*)wsb;      wsb += NBKT_MAX * 4;
    int*    gboff    = (int*)wsb;      wsb += (NBKT_MAX + 16) * 4;
    int*    gcur     = (int*)wsb;      wsb += NBKT_MAX * 4;
    int*    gcsr     = (int*)wsb;      wsb += (NBKT_MAX + 16) * 4;
    float*  stats    = (float*)wsb;    wsb += 64 * 4;
    __half* h1h      = (__half*)wsb;   wsb += (size_t)(nAlign + NDUMMY + 16) * H * 2;
    __half* hh       = (__half*)wsb;   wsb += (size_t)(nAlign + NDUMMY + 16) * H * 2;

    int nbE = (e + 4095) / 4096;   // 782

    k_zero<<<64, 256, 0, stream>>>(gbcnt, stats, h1h, hh, n);
    k_bcnt<<<nbE, 256, 0, stream>>>(dst, gbcnt, e);
    k_bscan<<<1, 512, 0, stream>>>(gbcnt, gboff, gcur, gcsr, nbkt);
    k_bin<<<(e + BIN_CHUNK - 1) / BIN_CHUNK, 256, 0, stream>>>(src, dst, gcur, temp, e);
    k_sort<<<nbkt, 256, 0, stream>>>(gboff, gcsr, temp, csr, ostart, oend, onode, ncur, dinv, n);
    k_scat<<<nbkt * SPLIT, 256, 0, stream>>>(gboff, temp, ncur, csr);
    k_mm1<<<(n + 15) / 16, 256, 0, stream>>>(x, W1, dinv, h1h, n);
    k_gather1<<<nbkt * 4, 256, 0, stream>>>(ostart, oend, onode, csr, h1h, dinv, b1, hbuf, stats, n);
    k_bncoef<<<1, 16, 0, stream>>>(stats, gamma, beta, (float)n);
    k_hops<<<(n + 255) / 256, 256, 0, stream>>>(hbuf, hh, stats, Wl, bl, dinv, n);
    k_gather2<<<nbkt * 4, 256, 0, stream>>>(ostart, oend, onode, csr, hh, dinv, agg2, n);
    k_final<<<(n + 255) / 256, 256, 0, stream>>>(agg2, W2, b2, out, n);
}

// Round 3
// 311.430 us; speedup vs baseline: 1.2069x; 1.2069x over previous
//
#include <hip/hip_runtime.h>
#include <hip/hip_fp16.h>
#include <math.h>

#define F_IN 128
#define H 16
#define C 40
#define K_HOPS 10
#define ALPHA 0.1f
#define BN_EPS 1e-5f

#define RB 256          // nodes per bucket
#define RB_BITS 8
#define NBKT_MAX 512    // ceil(100000/256)=391
#define SRC_MASK 0x1FFFF
#define PADQ 16         // node segment padded to multiple of 16 entries (even pair split)
#define NDUMMY 2048     // dummy zero rows spread over L2
#define STAGE_CAP 14336 // ints (56 KB) LDS staging for csr scatter

typedef int v4i __attribute__((ext_vector_type(4)));

// ---------------- zero: gbcnt=0, stats=0, dummy rows of both tables = 0 ----------------
__global__ void k_zero(int* __restrict__ gbcnt, float* __restrict__ stats,
                       __half* __restrict__ h1h, __half* __restrict__ hh, int n) {
    int id = blockIdx.x * blockDim.x + threadIdx.x;
    if (id < NBKT_MAX) gbcnt[id] = 0;
    if (id < 32) stats[id] = 0.0f;
    // NDUMMY rows x 16 halves = 64KB per table = 16384 ints
    int* z1 = (int*)(h1h + (size_t)n * H);
    int* z2 = (int*)(hh + (size_t)n * H);
    if (id < NDUMMY * H / 2) { z1[id] = 0; z2[id] = 0; }
}

// ---------------- bucket counts ----------------
__global__ __launch_bounds__(256) void k_bcnt(const int* __restrict__ dst,
                                              int* __restrict__ gbcnt, int e) {
    __shared__ int hist[NBKT_MAX];
    int t = threadIdx.x;
    hist[t] = 0; hist[t + 256] = 0;
    __syncthreads();
    int base = blockIdx.x * 4096;
    int endi = base + 4096; if (endi > e) endi = e;
    for (int i = base + t; i < endi; i += 256)
        atomicAdd(&hist[dst[i] >> RB_BITS], 1);
    __syncthreads();
    for (int b = t; b < NBKT_MAX; b += 256)
        if (hist[b]) atomicAdd(&gbcnt[b], hist[b]);
}

// ---------------- scans: raw bucket offsets (temp) + padded csr bases ----------------
__global__ __launch_bounds__(512) void k_bscan(const int* __restrict__ gbcnt,
                                               int* __restrict__ gboff,
                                               int* __restrict__ gcur,
                                               int* __restrict__ gcsr, int nbkt) {
    __shared__ int sd[512];
    int t = threadIdx.x;
    int v = (t < nbkt) ? gbcnt[t] : 0;
    sd[t] = v;
    __syncthreads();
    for (int off = 1; off < 512; off <<= 1) {
        int tmp = (t >= off) ? sd[t - off] : 0;
        __syncthreads();
        sd[t] += tmp;
        __syncthreads();
    }
    if (t < nbkt) { int o = sd[t] - v; gboff[t] = o; gcur[t] = o; }
    if (t == nbkt - 1) gboff[nbkt] = sd[t];
    __syncthreads();
    // padded csr capacity: worst-case per-node padding (PADQ-1 each)
    int cap = (t < nbkt) ? ((v + RB * (PADQ - 1) + PADQ - 1) & ~(PADQ - 1)) : 0;
    sd[t] = cap;
    __syncthreads();
    for (int off = 1; off < 512; off <<= 1) {
        int tmp = (t >= off) ? sd[t - off] : 0;
        __syncthreads();
        sd[t] += tmp;
        __syncthreads();
    }
    if (t < nbkt) gcsr[t] = sd[t] - cap;
}

// ---------------- bin edges into bucket runs (dense 4B writes) ----------------
#define BIN_CHUNK 4096
__global__ __launch_bounds__(256) void k_bin(const int* __restrict__ src,
                                             const int* __restrict__ dst,
                                             int* __restrict__ gcur,
                                             int* __restrict__ temp, int e) {
    __shared__ int hist[NBKT_MAX];
    __shared__ int lcur[NBKT_MAX];
    int t = threadIdx.x;
    hist[t] = 0; hist[t + 256] = 0;
    __syncthreads();
    int base = blockIdx.x * BIN_CHUNK;
    int ss[16], dd[16];
#pragma unroll
    for (int i = 0; i < 16; ++i) {
        int idx = base + i * 256 + t;
        if (idx < e) {
            ss[i] = src[idx]; dd[i] = dst[idx];
            atomicAdd(&hist[dd[i] >> RB_BITS], 1);
        } else ss[i] = -1;
    }
    __syncthreads();
    for (int b = t; b < NBKT_MAX; b += 256) {
        int hv = hist[b];
        lcur[b] = hv ? atomicAdd(&gcur[b], hv) : 0;
    }
    __syncthreads();
#pragma unroll
    for (int i = 0; i < 16; ++i) {
        if (ss[i] >= 0) {
            int d = dd[i];
            int b = d >> RB_BITS;
            int pos = atomicAdd(&lcur[b], 1);
            temp[pos] = ss[i] | ((d & (RB - 1)) << 17);
        }
    }
}

// ---------------- per-bucket counting sort -> padded CSR (LDS-staged scatter);
//                  deg->dinv; degree-sorted node order (ostart/oend/onode) ----------------
__global__ __launch_bounds__(256) void k_sort(const int* __restrict__ gboff,
                                              const int* __restrict__ gcsr,
                                              const int* __restrict__ temp,
                                              int* __restrict__ csr,
                                              int* __restrict__ ostart,
                                              int* __restrict__ oend,
                                              int* __restrict__ onode,
                                              float* __restrict__ dinv, int n) {
    __shared__ int hist[RB];
    __shared__ int cur[RB];
    __shared__ int psum[256];
    __shared__ int qh[64];
    __shared__ int qb[64];
    __shared__ int stage[STAGE_CAP];
    int t = threadIdx.x;
    int bkt = blockIdx.x;
    int start = gboff[bkt], endi = gboff[bkt + 1];
    hist[t] = 0;
    if (t < 64) qh[t] = 0;
    __syncthreads();
    for (int k = start + t; k < endi; k += 256)
        atomicAdd(&hist[temp[k] >> 17], 1);
    __syncthreads();
    int node = (bkt << RB_BITS) + t;
    int h = hist[t];
    int p = (h + PADQ - 1) & ~(PADQ - 1);
    bool va = (node < n);
    if (va) dinv[node] = rsqrtf((float)(h + 1));
    psum[t] = p;
    __syncthreads();
    for (int off = 1; off < 256; off <<= 1) {
        int tmp = (t >= off) ? psum[t - off] : 0;
        __syncthreads();
        psum[t] += tmp;
        __syncthreads();
    }
    int pexcl = psum[t] - p;
    int cbase = gcsr[bkt];
    int s0 = cbase + pexcl;
    // degree bins (iterations = padded/16); invalid nodes go to bin 0 with onode=-1
    int q = va ? min(p >> 4, 63) : 0;
    int r = atomicAdd(&qh[q], 1);
    __syncthreads();
    int ptotal = psum[255];
    if (t == 0) {
        int run = 0;
        for (int i = 0; i < 64; ++i) { qb[i] = run; run += qh[i]; }
    }
    __syncthreads();
    int ga = (bkt << RB_BITS) + qb[q] + r;
    ostart[ga] = s0; oend[ga] = s0 + p; onode[ga] = va ? node : -1;

    if (ptotal <= STAGE_CAP) {
        // fast path: scatter into LDS stage (bucket-local offsets), then dense copy out
        cur[t] = pexcl;
        for (int i = t; i < ptotal; i += 256) stage[i] = -1;
        __syncthreads();
        for (int k = start + t; k < endi; k += 256) {
            int v = temp[k];
            int dl = v >> 17;
            int pos = atomicAdd(&cur[dl], 1);
            stage[pos] = v & SRC_MASK;
        }
        __syncthreads();
        // coalesced int4 copy; sentinel -> distinct dummy zero row
        for (int i = t * 4; i < ptotal; i += 1024) {
            v4i v = *reinterpret_cast<const v4i*>(&stage[i]);
            int gi = cbase + i;
            v.x = (v.x < 0) ? n + ((gi + 0) & (NDUMMY - 1)) : v.x;
            v.y = (v.y < 0) ? n + ((gi + 1) & (NDUMMY - 1)) : v.y;
            v.z = (v.z < 0) ? n + ((gi + 2) & (NDUMMY - 1)) : v.z;
            v.w = (v.w < 0) ? n + ((gi + 3) & (NDUMMY - 1)) : v.w;
            *reinterpret_cast<v4i*>(&csr[gi]) = v;
        }
    } else {
        // fallback: absolute-position scatter (single block per bucket keeps writes on one XCD)
        cur[t] = s0;
        __syncthreads();
        for (int k = start + t; k < endi; k += 256) {
            int v = temp[k];
            int pos = atomicAdd(&cur[v >> 17], 1);
            csr[pos] = v & SRC_MASK;
        }
        __syncthreads();
        for (int i = s0 + h; i < s0 + p; ++i) csr[i] = n + (i & (NDUMMY - 1));
    }
}

// ---------------- h1' = dinv .* (x @ W1) -> fp16 table ----------------
__global__ __launch_bounds__(256) void k_mm1(const float* __restrict__ x,
                                             const float* __restrict__ W1,
                                             const float* __restrict__ dinv,
                                             __half* __restrict__ h1h, int n) {
    __shared__ float xs[16 * 132];
    __shared__ float ws[128 * 16];
    int t = threadIdx.x;
    int node0 = blockIdx.x * 16;
#pragma unroll
    for (int r = 0; r < 8; ++r) {
        int idx = t + r * 256;
        int nl = idx >> 7, k = idx & 127;
        int nn = node0 + nl; if (nn >= n) nn = n - 1;
        xs[nl * 132 + k] = x[(size_t)nn * F_IN + k];
        ws[idx] = W1[idx];
    }
    __syncthreads();
    int nl = t >> 4, j = t & 15;
    float acc = 0.0f;
#pragma unroll 8
    for (int k = 0; k < 128; ++k)
        acc = fmaf(xs[nl * 132 + k], ws[k * 16 + j], acc);
    int node = node0 + nl;
    if (node < n) h1h[(size_t)node * H + j] = __float2half(acc * dinv[node]);
}

__device__ __forceinline__ void acc8(float* a, int4 gv) {
    const __half2* h = reinterpret_cast<const __half2*>(&gv);
    float2 f0 = __half22float2(h[0]);
    float2 f1 = __half22float2(h[1]);
    float2 f2 = __half22float2(h[2]);
    float2 f3 = __half22float2(h[3]);
    a[0] += f0.x; a[1] += f0.y; a[2] += f1.x; a[3] += f1.y;
    a[4] += f2.x; a[5] += f2.y; a[6] += f3.x; a[7] += f3.y;
}

// ---------------- gather conv1: 4 lanes/node (2 pairs x 16B), degree-sorted order;
//                  + bias + ReLU + BN stats ----------------
__global__ __launch_bounds__(256) void k_gather1(const int* __restrict__ ostart,
                                                 const int* __restrict__ oend,
                                                 const int* __restrict__ onode,
                                                 const int* __restrict__ csr,
                                                 const __half* __restrict__ h1h,
                                                 const float* __restrict__ dinv,
                                                 const float* __restrict__ b1,
                                                 float* __restrict__ hout,
                                                 float* __restrict__ stats, int n) {
    __shared__ float sm[32];
    __shared__ float b1s[16];
    int t = threadIdx.x;
    if (t < 32) sm[t] = 0.0f;
    if (t < 16) b1s[t] = b1[t];
    __syncthreads();
    int idx = blockIdx.x * 256 + t;
    int g = idx >> 2;
    int L = idx & 3, p = L >> 1, jj = L & 1;
    int node = __builtin_nontemporal_load(onode + g);
    float a[8];
#pragma unroll
    for (int k = 0; k < 8; ++k) a[k] = 0.0f;
    const int4* tab = reinterpret_cast<const int4*>(h1h);
    if (node >= 0) {
        int c  = (__builtin_nontemporal_load(ostart + g) >> 2) + (p << 1);
        int ce = __builtin_nontemporal_load(oend + g) >> 2;
        const v4i* csr4 = reinterpret_cast<const v4i*>(csr);
        for (; c < ce; c += 4) {
            v4i e0 = __builtin_nontemporal_load(csr4 + c);
            v4i e1 = __builtin_nontemporal_load(csr4 + c + 1);
            int4 g0 = tab[(size_t)e0.x * 2 + jj];
            int4 g1 = tab[(size_t)e0.y * 2 + jj];
            int4 g2 = tab[(size_t)e0.z * 2 + jj];
            int4 g3 = tab[(size_t)e0.w * 2 + jj];
            int4 g4 = tab[(size_t)e1.x * 2 + jj];
            int4 g5 = tab[(size_t)e1.y * 2 + jj];
            int4 g6 = tab[(size_t)e1.z * 2 + jj];
            int4 g7 = tab[(size_t)e1.w * 2 + jj];
            acc8(a, g0); acc8(a, g1); acc8(a, g2); acc8(a, g3);
            acc8(a, g4); acc8(a, g5); acc8(a, g6); acc8(a, g7);
        }
    }
    // combine the two pairs (lane ^ 2)
#pragma unroll
    for (int k = 0; k < 8; ++k) a[k] += __shfl_xor(a[k], 2);
    float din = 0.0f;
    int4 sv = make_int4(0, 0, 0, 0);
    if (node >= 0) {
        din = dinv[node];
        sv = tab[(size_t)node * 2 + jj];
    }
    float v[8];
    {
        const __half2* h = reinterpret_cast<const __half2*>(&sv);
        float2 f0 = __half22float2(h[0]), f1 = __half22float2(h[1]);
        float2 f2 = __half22float2(h[2]), f3 = __half22float2(h[3]);
        float s8[8] = { f0.x, f0.y, f1.x, f1.y, f2.x, f2.y, f3.x, f3.y };
        bool writer = (node >= 0) && (p == 0);
#pragma unroll
        for (int k = 0; k < 8; ++k) {
            float val = fmaxf(din * (a[k] + s8[k]) + b1s[jj * 8 + k], 0.0f);
            v[k] = writer ? val : 0.0f;
        }
        if (writer) {
            float4* o = reinterpret_cast<float4*>(hout + (size_t)node * H + jj * 8);
            o[0] = make_float4(v[0], v[1], v[2], v[3]);
            o[1] = make_float4(v[4], v[5], v[6], v[7]);
        }
    }
    // BN stats: reduce over wave (p1 lanes are zero, so each node counted once)
#pragma unroll
    for (int k = 0; k < 8; ++k) {
        float s1 = v[k], s2 = v[k] * v[k];
        s1 += __shfl_xor(s1, 2);  s2 += __shfl_xor(s2, 2);
        s1 += __shfl_xor(s1, 4);  s2 += __shfl_xor(s2, 4);
        s1 += __shfl_xor(s1, 8);  s2 += __shfl_xor(s2, 8);
        s1 += __shfl_xor(s1, 16); s2 += __shfl_xor(s2, 16);
        s1 += __shfl_xor(s1, 32); s2 += __shfl_xor(s2, 32);
        if ((t & 63) < 2) {
            atomicAdd(&sm[jj * 8 + k], s1);
            atomicAdd(&sm[16 + jj * 8 + k], s2);
        }
    }
    __syncthreads();
    if (t < 32) atomicAdd(&stats[t], sm[t]);
}

// ---------------- BN coefficients ----------------
__global__ void k_bncoef(float* __restrict__ stats, const float* __restrict__ gamma,
                         const float* __restrict__ beta, float nf) {
    int j = threadIdx.x;
    if (j < 16) {
        float mean = stats[j] / nf;
        float var = stats[16 + j] / nf - mean * mean;
        float a = gamma[j] * rsqrtf(var + BN_EPS);
        float c = beta[j] - mean * a;
        stats[j] = a;
        stats[16 + j] = c;
    }
}

// ---------------- BN apply + K_HOPS residual blocks -> scaled fp16 table ----------------
__global__ __launch_bounds__(256) void k_hops(const float* __restrict__ h,
                                              __half* __restrict__ hh,
                                              const float* __restrict__ stats,
                                              const float* __restrict__ Wl,
                                              const float* __restrict__ bl,
                                              const float* __restrict__ dinv, int n) {
    __shared__ float wl[256], bls[16], av[16], cv[16];
    int t = threadIdx.x;
    // transposed layout: wl[j*16+k] = Wl[k*16+j] -> contiguous k (ds_read_b128)
    wl[t] = Wl[(t & 15) * 16 + (t >> 4)];
    if (t < 16) { bls[t] = bl[t]; av[t] = stats[t]; cv[t] = stats[16 + t]; }
    __syncthreads();
    int node = blockIdx.x * 256 + t;
    if (node >= n) return;
    float hr[16];
    {
        const float4* hp = reinterpret_cast<const float4*>(h + (size_t)node * H);
        float4 v0 = hp[0], v1 = hp[1], v2 = hp[2], v3 = hp[3];
        hr[0] = v0.x; hr[1] = v0.y; hr[2] = v0.z; hr[3] = v0.w;
        hr[4] = v1.x; hr[5] = v1.y; hr[6] = v1.z; hr[7] = v1.w;
        hr[8] = v2.x; hr[9] = v2.y; hr[10] = v2.z; hr[11] = v2.w;
        hr[12] = v3.x; hr[13] = v3.y; hr[14] = v3.z; hr[15] = v3.w;
    }
#pragma unroll
    for (int j = 0; j < 16; ++j) hr[j] = hr[j] * av[j] + cv[j];
    for (int it = 0; it < K_HOPS; ++it) {
        float tmp[16];
#pragma unroll
        for (int j = 0; j < 16; ++j) {
            float a = bls[j];
#pragma unroll
            for (int k = 0; k < 16; ++k) a = fmaf(hr[k], wl[j * 16 + k], a);
            tmp[j] = fmaxf(a, 0.0f);
        }
#pragma unroll
        for (int j = 0; j < 16; ++j) hr[j] = ALPHA * tmp[j] + (1.0f - ALPHA) * hr[j];
    }
    {
        float din = dinv[node];
        __half2 ph[8];
#pragma unroll
        for (int i = 0; i < 8; ++i)
            ph[i] = __floats2half2_rn(hr[2 * i] * din, hr[2 * i + 1] * din);
        int4* hp = reinterpret_cast<int4*>(hh + (size_t)node * H);
        hp[0] = *reinterpret_cast<int4*>(&ph[0]);
        hp[1] = *reinterpret_cast<int4*>(&ph[4]);
    }
}

// ---------------- gather conv2: 4 lanes/node (2 pairs x 16B); + self-loop ----------------
__global__ __launch_bounds__(256) void k_gather2(const int* __restrict__ ostart,
                                                 const int* __restrict__ oend,
                                                 const int* __restrict__ onode,
                                                 const int* __restrict__ csr,
                                                 const __half* __restrict__ hh,
                                                 const float* __restrict__ dinv,
                                                 float* __restrict__ agg, int n) {
    int t = threadIdx.x;
    int idx = blockIdx.x * 256 + t;
    int g = idx >> 2;
    int L = idx & 3, p = L >> 1, jj = L & 1;
    int node = __builtin_nontemporal_load(onode + g);
    float a[8];
#pragma unroll
    for (int k = 0; k < 8; ++k) a[k] = 0.0f;
    const int4* tab = reinterpret_cast<const int4*>(hh);
    if (node >= 0) {
        int c  = (__builtin_nontemporal_load(ostart + g) >> 2) + (p << 1);
        int ce = __builtin_nontemporal_load(oend + g) >> 2;
        const v4i* csr4 = reinterpret_cast<const v4i*>(csr);
        for (; c < ce; c += 4) {
            v4i e0 = __builtin_nontemporal_load(csr4 + c);
            v4i e1 = __builtin_nontemporal_load(csr4 + c + 1);
            int4 g0 = tab[(size_t)e0.x * 2 + jj];
            int4 g1 = tab[(size_t)e0.y * 2 + jj];
            int4 g2 = tab[(size_t)e0.z * 2 + jj];
            int4 g3 = tab[(size_t)e0.w * 2 + jj];
            int4 g4 = tab[(size_t)e1.x * 2 + jj];
            int4 g5 = tab[(size_t)e1.y * 2 + jj];
            int4 g6 = tab[(size_t)e1.z * 2 + jj];
            int4 g7 = tab[(size_t)e1.w * 2 + jj];
            acc8(a, g0); acc8(a, g1); acc8(a, g2); acc8(a, g3);
            acc8(a, g4); acc8(a, g5); acc8(a, g6); acc8(a, g7);
        }
    }
#pragma unroll
    for (int k = 0; k < 8; ++k) a[k] += __shfl_xor(a[k], 2);
    if (node >= 0 && p == 0) {
        float din = dinv[node];
        int4 sv = tab[(size_t)node * 2 + jj];
        const __half2* h = reinterpret_cast<const __half2*>(&sv);
        float2 f0 = __half22float2(h[0]), f1 = __half22float2(h[1]);
        float2 f2 = __half22float2(h[2]), f3 = __half22float2(h[3]);
        float s8[8] = { f0.x, f0.y, f1.x, f1.y, f2.x, f2.y, f3.x, f3.y };
        float v[8];
#pragma unroll
        for (int k = 0; k < 8; ++k) v[k] = din * (a[k] + s8[k]);
        float4* o = reinterpret_cast<float4*>(agg + (size_t)node * H + jj * 8);
        o[0] = make_float4(v[0], v[1], v[2], v[3]);
        o[1] = make_float4(v[4], v[5], v[6], v[7]);
    }
}

// ---------------- final: agg2 @ W2 + b2 -> log_softmax ----------------
__global__ __launch_bounds__(256) void k_final(const float* __restrict__ agg2,
                                               const float* __restrict__ W2,
                                               const float* __restrict__ b2,
                                               float* __restrict__ out, int n) {
    __shared__ float w2s[16 * 40];
    __shared__ float b2s[40];
    __shared__ float ostage[40 * 257];
    int t = threadIdx.x;
    for (int i = t; i < 640; i += 256) w2s[i] = W2[i];
    if (t < 40) b2s[t] = b2[t];
    __syncthreads();
    int node = blockIdx.x * 256 + t;
    if (node < n) {
        float g[16];
        const float4* ap = reinterpret_cast<const float4*>(agg2 + (size_t)node * H);
#pragma unroll
        for (int r = 0; r < 4; ++r) {
            float4 a = ap[r];
            g[r * 4 + 0] = a.x; g[r * 4 + 1] = a.y; g[r * 4 + 2] = a.z; g[r * 4 + 3] = a.w;
        }
        float z[40];
#pragma unroll
        for (int j = 0; j < 40; ++j) {
            float a = b2s[j];
#pragma unroll
            for (int k = 0; k < 16; ++k) a = fmaf(g[k], w2s[k * 40 + j], a);
            z[j] = a;
        }
        float m = z[0];
#pragma unroll
        for (int j = 1; j < 40; ++j) m = fmaxf(m, z[j]);
        float s = 0.0f;
#pragma unroll
        for (int j = 0; j < 40; ++j) s += expf(z[j] - m);
        float lse = m + logf(s);
#pragma unroll
        for (int j = 0; j < 40; ++j) ostage[j * 257 + t] = z[j] - lse;
    }
    __syncthreads();
    int nodes = n - blockIdx.x * 256;
    if (nodes > 256) nodes = 256;
    int total = nodes * 40;
    size_t base = (size_t)blockIdx.x * 256 * 40;
    for (int i = t; i < total; i += 256) {
        int nl = i / 40;
        int j = i - nl * 40;
        out[base + i] = ostage[j * 257 + nl];
    }
}

extern "C" void kernel_launch(void* const* d_in, const int* in_sizes, int n_in,
                              void* d_out, int out_size, void* d_ws, size_t ws_size,
                              hipStream_t stream) {
    const float* x     = (const float*)d_in[0];
    const int*   src   = (const int*)d_in[1];
    const int*   dst   = (const int*)d_in[2];
    const float* W1    = (const float*)d_in[3];
    const float* b1    = (const float*)d_in[4];
    const float* gamma = (const float*)d_in[5];
    const float* beta  = (const float*)d_in[6];
    const float* Wl    = (const float*)d_in[7];
    const float* bl    = (const float*)d_in[8];
    const float* W2    = (const float*)d_in[9];
    const float* b2    = (const float*)d_in[10];
    float* out = (float*)d_out;

    int n = in_sizes[0] / F_IN;   // 100000
    int e = in_sizes[1];          // 3200000
    int nbkt = (n + RB - 1) >> RB_BITS;   // 391
    int nAlign = (n + 15) & ~15;
    int nG = nbkt * RB;                                      // ordered-node slots
    size_t csrCap = (size_t)e + (size_t)nG * (PADQ - 1) + (size_t)nbkt * PADQ + 64;
    size_t hTileB = (size_t)nAlign * H * 4;                  // 6.4 MB
    size_t unionB = (size_t)e * 4;                           // temp (12.8 MB)
    if (unionB < 2 * hTileB) unionB = 2 * hTileB;            // also holds hbuf+agg2 later

    char* wsb = (char*)d_ws;
    int*    csr      = (int*)wsb;      wsb += csrCap * 4;
    char*   uni      = wsb;            wsb += unionB;
    int*    temp     = (int*)uni;                  // alive: k_bin .. k_sort
    float*  hbuf     = (float*)uni;                // alive: k_gather1 .. k_hops
    float*  agg2     = (float*)(uni + hTileB);     // alive: k_gather2 .. k_final
    int*    ostart   = (int*)wsb;      wsb += (size_t)(nG + 16) * 4;
    int*    oend     = (int*)wsb;      wsb += (size_t)(nG + 16) * 4;
    int*    onode    = (int*)wsb;      wsb += (size_t)(nG + 16) * 4;
    float*  dinv     = (float*)wsb;    wsb += (size_t)nAlign * 4;
    int*    gbcnt    = (int*)wsb;      wsb += NBKT_MAX * 4;
    int*    gboff    = (int*)wsb;      wsb += (NBKT_MAX + 16) * 4;
    int*    gcur     = (int*)wsb;      wsb += NBKT_MAX * 4;
    int*    gcsr     = (int*)wsb;      wsb += (NBKT_MAX + 16) * 4;
    float*  stats    = (float*)wsb;    wsb += 64 * 4;
    __half* h1h      = (__half*)wsb;   wsb += (size_t)(nAlign + NDUMMY + 16) * H * 2;
    __half* hh       = (__half*)wsb;   wsb += (size_t)(nAlign + NDUMMY + 16) * H * 2;

    int nbE = (e + 4095) / 4096;   // 782

    k_zero<<<64, 256, 0, stream>>>(gbcnt, stats, h1h, hh, n);
    k_bcnt<<<nbE, 256, 0, stream>>>(dst, gbcnt, e);
    k_bscan<<<1, 512, 0, stream>>>(gbcnt, gboff, gcur, gcsr, nbkt);
    k_bin<<<(e + BIN_CHUNK - 1) / BIN_CHUNK, 256, 0, stream>>>(src, dst, gcur, temp, e);
    k_sort<<<nbkt, 256, 0, stream>>>(gboff, gcsr, temp, csr, ostart, oend, onode, dinv, n);
    k_mm1<<<(n + 15) / 16, 256, 0, stream>>>(x, W1, dinv, h1h, n);
    k_gather1<<<nbkt * 4, 256, 0, stream>>>(ostart, oend, onode, csr, h1h, dinv, b1, hbuf, stats, n);
    k_bncoef<<<1, 16, 0, stream>>>(stats, gamma, beta, (float)n);
    k_hops<<<(n + 255) / 256, 256, 0, stream>>>(hbuf, hh, stats, Wl, bl, dinv, n);
    k_gather2<<<nbkt * 4, 256, 0, stream>>>(ostart, oend, onode, csr, hh, dinv, agg2, n);
    k_final<<<(n + 255) / 256, 256, 0, stream>>>(agg2, W2, b2, out, n);
}

// Round 4
// 299.552 us; speedup vs baseline: 1.2547x; 1.0397x over previous
//
#include <hip/hip_runtime.h>
#include <hip/hip_fp16.h>
#include <math.h>

#define F_IN 128
#define H 16
#define C 40
#define K_HOPS 10
#define ALPHA 0.1f
#define BN_EPS 1e-5f

#define RB 256          // nodes per bucket
#define RB_BITS 8
#define NBKT_MAX 512    // ceil(100000/256)=391
#define SRC_MASK 0x1FFFF
#define PADQ 32         // node segment padded to multiple of 32 entries (one full unrolled iter)
#define NDUMMY 2048     // dummy zero rows spread over L2
#define CAPB_BITS 14    // fixed per-bucket capacity for temp AND csr (16384 entries)
#define CAPB (1 << CAPB_BITS)
#define STAGE_CAP 14336 // ints (56 KB) LDS staging for csr scatter (>6 sigma above mean ptotal)

typedef int v4i __attribute__((ext_vector_type(4)));

// ---------------- zero: gcur = bucket bases, stats=0, dummy rows of both tables = 0 ----------------
__global__ void k_zero(int* __restrict__ gcur, float* __restrict__ stats,
                       __half* __restrict__ h1h, __half* __restrict__ hh, int n) {
    int id = blockIdx.x * blockDim.x + threadIdx.x;
    if (id < NBKT_MAX) gcur[id] = id << CAPB_BITS;
    if (id < 32) stats[id] = 0.0f;
    // NDUMMY rows x 16 halves = 64KB per table = 16384 ints
    int* z1 = (int*)(h1h + (size_t)n * H);
    int* z2 = (int*)(hh + (size_t)n * H);
    if (id < NDUMMY * H / 2) { z1[id] = 0; z2[id] = 0; }
}

// ---------------- bin edges into fixed-capacity bucket runs (dense 4B writes) ----------------
#define BIN_CHUNK 2048
__global__ __launch_bounds__(256) void k_bin(const int* __restrict__ src,
                                             const int* __restrict__ dst,
                                             int* __restrict__ gcur,
                                             int* __restrict__ temp, int e) {
    __shared__ int hist[NBKT_MAX];
    __shared__ int lcur[NBKT_MAX];
    int t = threadIdx.x;
    hist[t] = 0; hist[t + 256] = 0;
    __syncthreads();
    int base = blockIdx.x * BIN_CHUNK;
    int ss[8], dd[8];
#pragma unroll
    for (int i = 0; i < 8; ++i) {
        int idx = base + i * 256 + t;
        if (idx < e) {
            ss[i] = src[idx]; dd[i] = dst[idx];
            atomicAdd(&hist[dd[i] >> RB_BITS], 1);
        } else ss[i] = -1;
    }
    __syncthreads();
    for (int b = t; b < NBKT_MAX; b += 256) {
        int hv = hist[b];
        lcur[b] = hv ? atomicAdd(&gcur[b], hv) : 0;
    }
    __syncthreads();
#pragma unroll
    for (int i = 0; i < 8; ++i) {
        if (ss[i] >= 0) {
            int d = dd[i];
            int b = d >> RB_BITS;
            int pos = atomicAdd(&lcur[b], 1);
            temp[pos] = ss[i] | ((d & (RB - 1)) << 17);
        }
    }
}

// ---------------- per-bucket counting sort -> padded CSR (LDS-staged scatter, 8-batched);
//                  deg->dinv; HEAVY-FIRST degree-sorted node order (ostart/oend/onode) ----------------
__global__ __launch_bounds__(256) void k_sort(const int* __restrict__ gcur,
                                              const int* __restrict__ temp,
                                              int* __restrict__ csr,
                                              int* __restrict__ ostart,
                                              int* __restrict__ oend,
                                              int* __restrict__ onode,
                                              float* __restrict__ dinv, int n) {
    __shared__ int hist[RB];
    __shared__ int cur[RB];
    __shared__ int psum[256];
    __shared__ int qh[64];
    __shared__ int qb[64];
    __shared__ int stage[STAGE_CAP];
    int t = threadIdx.x;
    int bkt = blockIdx.x;
    int start = bkt << CAPB_BITS;
    int endi = gcur[bkt];
    hist[t] = 0;
    if (t < 64) qh[t] = 0;
    __syncthreads();
    // hist pass, 8-deep load batching to break the load->atomic chain
    for (int k = start + t; k < endi; k += 2048) {
        int v[8];
#pragma unroll
        for (int i = 0; i < 8; ++i) { int ix = k + i * 256; v[i] = (ix < endi) ? temp[ix] : -1; }
#pragma unroll
        for (int i = 0; i < 8; ++i) if (v[i] >= 0) atomicAdd(&hist[v[i] >> 17], 1);
    }
    __syncthreads();
    int node = (bkt << RB_BITS) + t;
    int h = hist[t];
    int p = (h + PADQ - 1) & ~(PADQ - 1);
    bool va = (node < n);
    if (va) dinv[node] = rsqrtf((float)(h + 1));
    psum[t] = p;
    __syncthreads();
    for (int off = 1; off < 256; off <<= 1) {
        int tmp = (t >= off) ? psum[t - off] : 0;
        __syncthreads();
        psum[t] += tmp;
        __syncthreads();
    }
    int pexcl = psum[t] - p;
    int s0 = start + pexcl;   // csr strided identically to temp (base = bkt<<CAPB_BITS)
    // degree bins, HEAVY FIRST (big nodes get low order index -> launched early)
    int q = 63 - min(p >> 5, 63);
    int r = atomicAdd(&qh[q], 1);
    __syncthreads();
    int ptotal = psum[255];
    if (t == 0) {
        int run = 0;
        for (int i = 0; i < 64; ++i) { qb[i] = run; run += qh[i]; }
    }
    __syncthreads();
    int ga = (bkt << RB_BITS) + qb[q] + r;
    ostart[ga] = s0; oend[ga] = s0 + p; onode[ga] = va ? node : -1;

    if (ptotal <= STAGE_CAP) {
        // fast path: scatter into LDS stage (bucket-local offsets), then dense copy out
        cur[t] = pexcl;
        for (int i = t; i < ptotal; i += 256) stage[i] = -1;
        __syncthreads();
        for (int k = start + t; k < endi; k += 2048) {
            int v[8];
#pragma unroll
            for (int i = 0; i < 8; ++i) { int ix = k + i * 256; v[i] = (ix < endi) ? temp[ix] : -1; }
#pragma unroll
            for (int i = 0; i < 8; ++i) {
                if (v[i] >= 0) {
                    int pos = atomicAdd(&cur[v[i] >> 17], 1);
                    stage[pos] = v[i] & SRC_MASK;
                }
            }
        }
        __syncthreads();
        // coalesced int4 copy; sentinel -> distinct dummy zero row
        for (int i = t * 4; i < ptotal; i += 1024) {
            v4i v = *reinterpret_cast<const v4i*>(&stage[i]);
            int gi = start + i;
            v.x = (v.x < 0) ? n + ((gi + 0) & (NDUMMY - 1)) : v.x;
            v.y = (v.y < 0) ? n + ((gi + 1) & (NDUMMY - 1)) : v.y;
            v.z = (v.z < 0) ? n + ((gi + 2) & (NDUMMY - 1)) : v.z;
            v.w = (v.w < 0) ? n + ((gi + 3) & (NDUMMY - 1)) : v.w;
            *reinterpret_cast<v4i*>(&csr[gi]) = v;
        }
    } else {
        // fallback: absolute-position scatter (single block per bucket keeps writes on one XCD)
        cur[t] = s0;
        __syncthreads();
        for (int k = start + t; k < endi; k += 256) {
            int v = temp[k];
            int pos = atomicAdd(&cur[v >> 17], 1);
            csr[pos] = v & SRC_MASK;
        }
        __syncthreads();
        for (int i = s0 + h; i < s0 + p; ++i) csr[i] = n + (i & (NDUMMY - 1));
    }
}

// ---------------- h1' = dinv .* (x @ W1) -> fp16 table ----------------
__global__ __launch_bounds__(256) void k_mm1(const float* __restrict__ x,
                                             const float* __restrict__ W1,
                                             const float* __restrict__ dinv,
                                             __half* __restrict__ h1h, int n) {
    __shared__ __align__(16) float xs[16 * 132];
    __shared__ __align__(16) float ws[128 * 16];
    int t = threadIdx.x;
    int node0 = blockIdx.x * 16;
    const float4* x4 = reinterpret_cast<const float4*>(x);
    const float4* w4 = reinterpret_cast<const float4*>(W1);
#pragma unroll
    for (int r = 0; r < 2; ++r) {
        int f = t + r * 256;            // 0..511 float4 chunks
        int nl = f >> 5, k4 = f & 31;
        int nn = node0 + nl; if (nn >= n) nn = n - 1;
        *reinterpret_cast<float4*>(&xs[nl * 132 + k4 * 4]) = x4[(size_t)nn * 32 + k4];
        *reinterpret_cast<float4*>(&ws[f * 4]) = w4[f];
    }
    __syncthreads();
    int nl = t >> 4, j = t & 15;
    float acc = 0.0f;
#pragma unroll 8
    for (int k = 0; k < 128; ++k)
        acc = fmaf(xs[nl * 132 + k], ws[k * 16 + j], acc);
    int node = node0 + nl;
    if (node < n) h1h[(size_t)node * H + j] = __float2half(acc * dinv[node]);
}

__device__ __forceinline__ void acc8(float* a, int4 gv) {
    const __half2* h = reinterpret_cast<const __half2*>(&gv);
    float2 f0 = __half22float2(h[0]);
    float2 f1 = __half22float2(h[1]);
    float2 f2 = __half22float2(h[2]);
    float2 f3 = __half22float2(h[3]);
    a[0] += f0.x; a[1] += f0.y; a[2] += f1.x; a[3] += f1.y;
    a[4] += f2.x; a[5] += f2.y; a[6] += f3.x; a[7] += f3.y;
}

// ---------------- gather conv1: 4 lanes/node (2 pairs x 16B), 16 gathers in flight/lane;
//                  heavy-first order; + bias + ReLU + BN stats ----------------
__global__ __launch_bounds__(256) void k_gather1(const int* __restrict__ ostart,
                                                 const int* __restrict__ oend,
                                                 const int* __restrict__ onode,
                                                 const int* __restrict__ csr,
                                                 const __half* __restrict__ h1h,
                                                 const float* __restrict__ dinv,
                                                 const float* __restrict__ b1,
                                                 float* __restrict__ hout,
                                                 float* __restrict__ stats, int n) {
    __shared__ float sm[32];
    __shared__ float b1s[16];
    int t = threadIdx.x;
    if (t < 32) sm[t] = 0.0f;
    if (t < 16) b1s[t] = b1[t];
    __syncthreads();
    int idx = blockIdx.x * 256 + t;
    int g = idx >> 2;
    int L = idx & 3, p = L >> 1, jj = L & 1;
    int node = __builtin_nontemporal_load(onode + g);
    float a[8];
#pragma unroll
    for (int k = 0; k < 8; ++k) a[k] = 0.0f;
    const int4* tab = reinterpret_cast<const int4*>(h1h);
    if (node >= 0) {
        int c  = (__builtin_nontemporal_load(ostart + g) >> 2) + (p << 2);
        int ce = __builtin_nontemporal_load(oend + g) >> 2;
        const v4i* csr4 = reinterpret_cast<const v4i*>(csr);
        for (; c < ce; c += 8) {
            v4i e0 = __builtin_nontemporal_load(csr4 + c);
            v4i e1 = __builtin_nontemporal_load(csr4 + c + 1);
            v4i e2 = __builtin_nontemporal_load(csr4 + c + 2);
            v4i e3 = __builtin_nontemporal_load(csr4 + c + 3);
            int4 g0  = tab[(size_t)e0.x * 2 + jj];
            int4 g1  = tab[(size_t)e0.y * 2 + jj];
            int4 g2  = tab[(size_t)e0.z * 2 + jj];
            int4 g3  = tab[(size_t)e0.w * 2 + jj];
            int4 g4  = tab[(size_t)e1.x * 2 + jj];
            int4 g5  = tab[(size_t)e1.y * 2 + jj];
            int4 g6  = tab[(size_t)e1.z * 2 + jj];
            int4 g7  = tab[(size_t)e1.w * 2 + jj];
            int4 g8  = tab[(size_t)e2.x * 2 + jj];
            int4 g9  = tab[(size_t)e2.y * 2 + jj];
            int4 g10 = tab[(size_t)e2.z * 2 + jj];
            int4 g11 = tab[(size_t)e2.w * 2 + jj];
            int4 g12 = tab[(size_t)e3.x * 2 + jj];
            int4 g13 = tab[(size_t)e3.y * 2 + jj];
            int4 g14 = tab[(size_t)e3.z * 2 + jj];
            int4 g15 = tab[(size_t)e3.w * 2 + jj];
            acc8(a, g0);  acc8(a, g1);  acc8(a, g2);  acc8(a, g3);
            acc8(a, g4);  acc8(a, g5);  acc8(a, g6);  acc8(a, g7);
            acc8(a, g8);  acc8(a, g9);  acc8(a, g10); acc8(a, g11);
            acc8(a, g12); acc8(a, g13); acc8(a, g14); acc8(a, g15);
        }
    }
    // combine the two pairs (lane ^ 2)
#pragma unroll
    for (int k = 0; k < 8; ++k) a[k] += __shfl_xor(a[k], 2);
    float din = 0.0f;
    int4 sv = make_int4(0, 0, 0, 0);
    if (node >= 0) {
        din = dinv[node];
        sv = tab[(size_t)node * 2 + jj];
    }
    float v[8];
    {
        const __half2* h = reinterpret_cast<const __half2*>(&sv);
        float2 f0 = __half22float2(h[0]), f1 = __half22float2(h[1]);
        float2 f2 = __half22float2(h[2]), f3 = __half22float2(h[3]);
        float s8[8] = { f0.x, f0.y, f1.x, f1.y, f2.x, f2.y, f3.x, f3.y };
        bool writer = (node >= 0) && (p == 0);
#pragma unroll
        for (int k = 0; k < 8; ++k) {
            float val = fmaxf(din * (a[k] + s8[k]) + b1s[jj * 8 + k], 0.0f);
            v[k] = writer ? val : 0.0f;
        }
        if (writer) {
            float4* o = reinterpret_cast<float4*>(hout + (size_t)node * H + jj * 8);
            o[0] = make_float4(v[0], v[1], v[2], v[3]);
            o[1] = make_float4(v[4], v[5], v[6], v[7]);
        }
    }
    // BN stats: reduce over wave (p1 lanes are zero, so each node counted once)
#pragma unroll
    for (int k = 0; k < 8; ++k) {
        float s1 = v[k], s2 = v[k] * v[k];
        s1 += __shfl_xor(s1, 2);  s2 += __shfl_xor(s2, 2);
        s1 += __shfl_xor(s1, 4);  s2 += __shfl_xor(s2, 4);
        s1 += __shfl_xor(s1, 8);  s2 += __shfl_xor(s2, 8);
        s1 += __shfl_xor(s1, 16); s2 += __shfl_xor(s2, 16);
        s1 += __shfl_xor(s1, 32); s2 += __shfl_xor(s2, 32);
        if ((t & 63) < 2) {
            atomicAdd(&sm[jj * 8 + k], s1);
            atomicAdd(&sm[16 + jj * 8 + k], s2);
        }
    }
    __syncthreads();
    if (t < 32) atomicAdd(&stats[t], sm[t]);
}

// ---------------- BN coefficients ----------------
__global__ void k_bncoef(float* __restrict__ stats, const float* __restrict__ gamma,
                         const float* __restrict__ beta, float nf) {
    int j = threadIdx.x;
    if (j < 16) {
        float mean = stats[j] / nf;
        float var = stats[16 + j] / nf - mean * mean;
        float a = gamma[j] * rsqrtf(var + BN_EPS);
        float c = beta[j] - mean * a;
        stats[j] = a;
        stats[16 + j] = c;
    }
}

// ---------------- BN apply + K_HOPS residual blocks -> scaled fp16 table ----------------
__global__ __launch_bounds__(256) void k_hops(const float* __restrict__ h,
                                              __half* __restrict__ hh,
                                              const float* __restrict__ stats,
                                              const float* __restrict__ Wl,
                                              const float* __restrict__ bl,
                                              const float* __restrict__ dinv, int n) {
    __shared__ float wl[256], bls[16], av[16], cv[16];
    int t = threadIdx.x;
    // transposed layout: wl[j*16+k] = Wl[k*16+j] -> contiguous k (ds_read_b128)
    wl[t] = Wl[(t & 15) * 16 + (t >> 4)];
    if (t < 16) { bls[t] = bl[t]; av[t] = stats[t]; cv[t] = stats[16 + t]; }
    __syncthreads();
    int node = blockIdx.x * 256 + t;
    if (node >= n) return;
    float hr[16];
    {
        const float4* hp = reinterpret_cast<const float4*>(h + (size_t)node * H);
        float4 v0 = hp[0], v1 = hp[1], v2 = hp[2], v3 = hp[3];
        hr[0] = v0.x; hr[1] = v0.y; hr[2] = v0.z; hr[3] = v0.w;
        hr[4] = v1.x; hr[5] = v1.y; hr[6] = v1.z; hr[7] = v1.w;
        hr[8] = v2.x; hr[9] = v2.y; hr[10] = v2.z; hr[11] = v2.w;
        hr[12] = v3.x; hr[13] = v3.y; hr[14] = v3.z; hr[15] = v3.w;
    }
#pragma unroll
    for (int j = 0; j < 16; ++j) hr[j] = hr[j] * av[j] + cv[j];
    for (int it = 0; it < K_HOPS; ++it) {
        float tmp[16];
#pragma unroll
        for (int j = 0; j < 16; ++j) {
            float a = bls[j];
#pragma unroll
            for (int k = 0; k < 16; ++k) a = fmaf(hr[k], wl[j * 16 + k], a);
            tmp[j] = fmaxf(a, 0.0f);
        }
#pragma unroll
        for (int j = 0; j < 16; ++j) hr[j] = ALPHA * tmp[j] + (1.0f - ALPHA) * hr[j];
    }
    {
        float din = dinv[node];
        __half2 ph[8];
#pragma unroll
        for (int i = 0; i < 8; ++i)
            ph[i] = __floats2half2_rn(hr[2 * i] * din, hr[2 * i + 1] * din);
        int4* hp = reinterpret_cast<int4*>(hh + (size_t)node * H);
        hp[0] = *reinterpret_cast<int4*>(&ph[0]);
        hp[1] = *reinterpret_cast<int4*>(&ph[4]);
    }
}

// ---------------- gather conv2: 4 lanes/node, 16 gathers in flight/lane; + self-loop ----------------
__global__ __launch_bounds__(256) void k_gather2(const int* __restrict__ ostart,
                                                 const int* __restrict__ oend,
                                                 const int* __restrict__ onode,
                                                 const int* __restrict__ csr,
                                                 const __half* __restrict__ hh,
                                                 const float* __restrict__ dinv,
                                                 float* __restrict__ agg, int n) {
    int t = threadIdx.x;
    int idx = blockIdx.x * 256 + t;
    int g = idx >> 2;
    int L = idx & 3, p = L >> 1, jj = L & 1;
    int node = __builtin_nontemporal_load(onode + g);
    float a[8];
#pragma unroll
    for (int k = 0; k < 8; ++k) a[k] = 0.0f;
    const int4* tab = reinterpret_cast<const int4*>(hh);
    if (node >= 0) {
        int c  = (__builtin_nontemporal_load(ostart + g) >> 2) + (p << 2);
        int ce = __builtin_nontemporal_load(oend + g) >> 2;
        const v4i* csr4 = reinterpret_cast<const v4i*>(csr);
        for (; c < ce; c += 8) {
            v4i e0 = __builtin_nontemporal_load(csr4 + c);
            v4i e1 = __builtin_nontemporal_load(csr4 + c + 1);
            v4i e2 = __builtin_nontemporal_load(csr4 + c + 2);
            v4i e3 = __builtin_nontemporal_load(csr4 + c + 3);
            int4 g0  = tab[(size_t)e0.x * 2 + jj];
            int4 g1  = tab[(size_t)e0.y * 2 + jj];
            int4 g2  = tab[(size_t)e0.z * 2 + jj];
            int4 g3  = tab[(size_t)e0.w * 2 + jj];
            int4 g4  = tab[(size_t)e1.x * 2 + jj];
            int4 g5  = tab[(size_t)e1.y * 2 + jj];
            int4 g6  = tab[(size_t)e1.z * 2 + jj];
            int4 g7  = tab[(size_t)e1.w * 2 + jj];
            int4 g8  = tab[(size_t)e2.x * 2 + jj];
            int4 g9  = tab[(size_t)e2.y * 2 + jj];
            int4 g10 = tab[(size_t)e2.z * 2 + jj];
            int4 g11 = tab[(size_t)e2.w * 2 + jj];
            int4 g12 = tab[(size_t)e3.x * 2 + jj];
            int4 g13 = tab[(size_t)e3.y * 2 + jj];
            int4 g14 = tab[(size_t)e3.z * 2 + jj];
            int4 g15 = tab[(size_t)e3.w * 2 + jj];
            acc8(a, g0);  acc8(a, g1);  acc8(a, g2);  acc8(a, g3);
            acc8(a, g4);  acc8(a, g5);  acc8(a, g6);  acc8(a, g7);
            acc8(a, g8);  acc8(a, g9);  acc8(a, g10); acc8(a, g11);
            acc8(a, g12); acc8(a, g13); acc8(a, g14); acc8(a, g15);
        }
    }
#pragma unroll
    for (int k = 0; k < 8; ++k) a[k] += __shfl_xor(a[k], 2);
    if (node >= 0 && p == 0) {
        float din = dinv[node];
        int4 sv = tab[(size_t)node * 2 + jj];
        const __half2* h = reinterpret_cast<const __half2*>(&sv);
        float2 f0 = __half22float2(h[0]), f1 = __half22float2(h[1]);
        float2 f2 = __half22float2(h[2]), f3 = __half22float2(h[3]);
        float s8[8] = { f0.x, f0.y, f1.x, f1.y, f2.x, f2.y, f3.x, f3.y };
        float v[8];
#pragma unroll
        for (int k = 0; k < 8; ++k) v[k] = din * (a[k] + s8[k]);
        float4* o = reinterpret_cast<float4*>(agg + (size_t)node * H + jj * 8);
        o[0] = make_float4(v[0], v[1], v[2], v[3]);
        o[1] = make_float4(v[4], v[5], v[6], v[7]);
    }
}

// ---------------- final: agg2 @ W2 + b2 -> log_softmax ----------------
__global__ __launch_bounds__(256) void k_final(const float* __restrict__ agg2,
                                               const float* __restrict__ W2,
                                               const float* __restrict__ b2,
                                               float* __restrict__ out, int n) {
    __shared__ float w2s[16 * 40];
    __shared__ float b2s[40];
    __shared__ float ostage[40 * 257];
    int t = threadIdx.x;
    for (int i = t; i < 640; i += 256) w2s[i] = W2[i];
    if (t < 40) b2s[t] = b2[t];
    __syncthreads();
    int node = blockIdx.x * 256 + t;
    if (node < n) {
        float g[16];
        const float4* ap = reinterpret_cast<const float4*>(agg2 + (size_t)node * H);
#pragma unroll
        for (int r = 0; r < 4; ++r) {
            float4 a = ap[r];
            g[r * 4 + 0] = a.x; g[r * 4 + 1] = a.y; g[r * 4 + 2] = a.z; g[r * 4 + 3] = a.w;
        }
        float z[40];
#pragma unroll
        for (int j = 0; j < 40; ++j) {
            float a = b2s[j];
#pragma unroll
            for (int k = 0; k < 16; ++k) a = fmaf(g[k], w2s[k * 40 + j], a);
            z[j] = a;
        }
        float m = z[0];
#pragma unroll
        for (int j = 1; j < 40; ++j) m = fmaxf(m, z[j]);
        float s = 0.0f;
#pragma unroll
        for (int j = 0; j < 40; ++j) s += expf(z[j] - m);
        float lse = m + logf(s);
#pragma unroll
        for (int j = 0; j < 40; ++j) ostage[j * 257 + t] = z[j] - lse;
    }
    __syncthreads();
    int nodes = n - blockIdx.x * 256;
    if (nodes > 256) nodes = 256;
    int total = nodes * 40;
    size_t base = (size_t)blockIdx.x * 256 * 40;
    for (int i = t; i < total; i += 256) {
        int nl = i / 40;
        int j = i - nl * 40;
        out[base + i] = ostage[j * 257 + nl];
    }
}

extern "C" void kernel_launch(void* const* d_in, const int* in_sizes, int n_in,
                              void* d_out, int out_size, void* d_ws, size_t ws_size,
                              hipStream_t stream) {
    const float* x     = (const float*)d_in[0];
    const int*   src   = (const int*)d_in[1];
    const int*   dst   = (const int*)d_in[2];
    const float* W1    = (const float*)d_in[3];
    const float* b1    = (const float*)d_in[4];
    const float* gamma = (const float*)d_in[5];
    const float* beta  = (const float*)d_in[6];
    const float* Wl    = (const float*)d_in[7];
    const float* bl    = (const float*)d_in[8];
    const float* W2    = (const float*)d_in[9];
    const float* b2    = (const float*)d_in[10];
    float* out = (float*)d_out;

    int n = in_sizes[0] / F_IN;   // 100000
    int e = in_sizes[1];          // 3200000
    int nbkt = (n + RB - 1) >> RB_BITS;   // 391
    int nAlign = (n + 15) & ~15;
    int nG = nbkt * RB;                                      // ordered-node slots
    size_t bktB = (size_t)nbkt << CAPB_BITS;                 // fixed-capacity entries (temp & csr)
    size_t hTileB = (size_t)nAlign * H * 4;                  // 6.4 MB
    size_t unionB = bktB * 4;                                // temp (25.6 MB)
    if (unionB < 2 * hTileB) unionB = 2 * hTileB;            // also holds hbuf+agg2 later

    char* wsb = (char*)d_ws;
    int*    csr      = (int*)wsb;      wsb += (bktB + 64) * 4;
    char*   uni      = wsb;            wsb += unionB;
    int*    temp     = (int*)uni;                  // alive: k_bin .. k_sort
    float*  hbuf     = (float*)uni;                // alive: k_gather1 .. k_hops
    float*  agg2     = (float*)(uni + hTileB);     // alive: k_gather2 .. k_final
    int*    ostart   = (int*)wsb;      wsb += (size_t)(nG + 16) * 4;
    int*    oend     = (int*)wsb;      wsb += (size_t)(nG + 16) * 4;
    int*    onode    = (int*)wsb;      wsb += (size_t)(nG + 16) * 4;
    float*  dinv     = (float*)wsb;    wsb += (size_t)nAlign * 4;
    int*    gcur     = (int*)wsb;      wsb += NBKT_MAX * 4;
    float*  stats    = (float*)wsb;    wsb += 64 * 4;
    __half* h1h      = (__half*)wsb;   wsb += (size_t)(nAlign + NDUMMY + 16) * H * 2;
    __half* hh       = (__half*)wsb;   wsb += (size_t)(nAlign + NDUMMY + 16) * H * 2;

    k_zero<<<64, 256, 0, stream>>>(gcur, stats, h1h, hh, n);
    k_bin<<<(e + BIN_CHUNK - 1) / BIN_CHUNK, 256, 0, stream>>>(src, dst, gcur, temp, e);
    k_sort<<<nbkt, 256, 0, stream>>>(gcur, temp, csr, ostart, oend, onode, dinv, n);
    k_mm1<<<(n + 15) / 16, 256, 0, stream>>>(x, W1, dinv, h1h, n);
    k_gather1<<<nbkt * 4, 256, 0, stream>>>(ostart, oend, onode, csr, h1h, dinv, b1, hbuf, stats, n);
    k_bncoef<<<1, 16, 0, stream>>>(stats, gamma, beta, (float)n);
    k_hops<<<(n + 255) / 256, 256, 0, stream>>>(hbuf, hh, stats, Wl, bl, dinv, n);
    k_gather2<<<nbkt * 4, 256, 0, stream>>>(ostart, oend, onode, csr, hh, dinv, agg2, n);
    k_final<<<(n + 255) / 256, 256, 0, stream>>>(agg2, W2, b2, out, n);
}

// Round 5
// 286.772 us; speedup vs baseline: 1.3106x; 1.0446x over previous
//
#include <hip/hip_runtime.h>
#include <hip/hip_fp16.h>
#include <math.h>

#define F_IN 128
#define H 16
#define C 40
#define K_HOPS 10
#define ALPHA 0.1f
#define BN_EPS 1e-5f

#define RB 256          // nodes per bucket
#define RB_BITS 8
#define NBKT_MAX 512    // ceil(100000/256)=391
#define SRC_MASK 0x1FFFF
#define PADQ 32         // node segment padded to multiple of 32 entries
#define NDUMMY 2048     // dummy zero rows spread over L2
#define CAPB_BITS 14    // fixed per-bucket capacity for temp AND csr (16384 entries)
#define CAPB (1 << CAPB_BITS)
#define STAGE_CAP 14336 // ints (56 KB) LDS staging for csr scatter

typedef int v4i __attribute__((ext_vector_type(4)));

// ---------------- zero: gcur = bucket bases, stats=0, dummy rows of both tables = 0 ----------------
__global__ void k_zero(int* __restrict__ gcur, float* __restrict__ stats,
                       __half* __restrict__ h1h, __half* __restrict__ hh, int n) {
    int id = blockIdx.x * blockDim.x + threadIdx.x;
    if (id < NBKT_MAX) gcur[id] = id << CAPB_BITS;
    if (id < 32) stats[id] = 0.0f;
    int* z1 = (int*)(h1h + (size_t)n * H);
    int* z2 = (int*)(hh + (size_t)n * H);
    if (id < NDUMMY * H / 2) { z1[id] = 0; z2[id] = 0; }
}

// ---------------- bin edges: LDS counting sort per block -> dense run writes ----------------
#define BIN_CHUNK 4096
__global__ __launch_bounds__(256) void k_bin(const int* __restrict__ src,
                                             const int* __restrict__ dst,
                                             int* __restrict__ gcur,
                                             int* __restrict__ temp, int e) {
    __shared__ int hist[NBKT_MAX];
    __shared__ int runst[NBKT_MAX];
    __shared__ int cur[NBKT_MAX];
    __shared__ int gofs[NBKT_MAX];
    __shared__ int psum[256];
    __shared__ int stageV[BIN_CHUNK];
    __shared__ unsigned short stageB[BIN_CHUNK];
    int t = threadIdx.x;
    hist[t] = 0; hist[t + 256] = 0;
    __syncthreads();
    int base = blockIdx.x * BIN_CHUNK;
    int cnt = e - base; if (cnt > BIN_CHUNK) cnt = BIN_CHUNK;
    const v4i* s4 = reinterpret_cast<const v4i*>(src + base);
    const v4i* d4 = reinterpret_cast<const v4i*>(dst + base);
    v4i sv[4], dv[4];
#pragma unroll
    for (int i = 0; i < 4; ++i) {
        int e0 = (t * 4 + i) * 4;
        if (e0 + 3 < cnt) { sv[i] = s4[t * 4 + i]; dv[i] = d4[t * 4 + i]; }
        else if (e0 < cnt) {
            int ts[4], td[4];
#pragma unroll
            for (int j = 0; j < 4; ++j) {
                int ei = e0 + j;
                ts[j] = (ei < cnt) ? src[base + ei] : 0;
                td[j] = (ei < cnt) ? dst[base + ei] : -1;
            }
            sv[i] = *reinterpret_cast<v4i*>(ts); dv[i] = *reinterpret_cast<v4i*>(td);
        } else { dv[i] = (v4i){-1, -1, -1, -1}; sv[i] = dv[i]; }
    }
#pragma unroll
    for (int i = 0; i < 4; ++i) {
        if (dv[i].x >= 0) atomicAdd(&hist[dv[i].x >> RB_BITS], 1);
        if (dv[i].y >= 0) atomicAdd(&hist[dv[i].y >> RB_BITS], 1);
        if (dv[i].z >= 0) atomicAdd(&hist[dv[i].z >> RB_BITS], 1);
        if (dv[i].w >= 0) atomicAdd(&hist[dv[i].w >> RB_BITS], 1);
    }
    __syncthreads();
    int b0 = 2 * t, b1 = 2 * t + 1;
    int h0 = hist[b0], h1 = hist[b1];
    psum[t] = h0 + h1;
    __syncthreads();
    for (int off = 1; off < 256; off <<= 1) {
        int tmp = (t >= off) ? psum[t - off] : 0;
        __syncthreads();
        psum[t] += tmp;
        __syncthreads();
    }
    int excl = psum[t] - (h0 + h1);
    runst[b0] = excl; runst[b1] = excl + h0;
    int g0 = h0 ? atomicAdd(&gcur[b0], h0) : 0;
    int g1 = h1 ? atomicAdd(&gcur[b1], h1) : 0;
    gofs[b0] = g0 - excl; gofs[b1] = g1 - (excl + h0);
    cur[b0] = excl; cur[b1] = excl + h0;
    __syncthreads();
#pragma unroll
    for (int i = 0; i < 4; ++i) {
        int ds[4] = { dv[i].x, dv[i].y, dv[i].z, dv[i].w };
        int ssx[4] = { sv[i].x, sv[i].y, sv[i].z, sv[i].w };
#pragma unroll
        for (int j = 0; j < 4; ++j) {
            int d = ds[j];
            if (d >= 0) {
                int b = d >> RB_BITS;
                int pos = atomicAdd(&cur[b], 1);
                stageV[pos] = ssx[j] | ((d & (RB - 1)) << 17);
                stageB[pos] = (unsigned short)b;
            }
        }
    }
    __syncthreads();
    // stage-order copy out: consecutive threads -> consecutive slots of same run
    for (int i = t; i < cnt; i += 256) {
        int b = stageB[i];
        temp[gofs[b] + i] = stageV[i];
    }
}

// ---------------- per-bucket counting sort -> padded CSR (LDS-staged scatter, int4 loads);
//                  deg->dinv; HEAVY-FIRST degree-sorted node order ----------------
__global__ __launch_bounds__(256) void k_sort(const int* __restrict__ gcur,
                                              const int* __restrict__ temp,
                                              int* __restrict__ csr,
                                              int* __restrict__ ostart,
                                              int* __restrict__ oend,
                                              int* __restrict__ onode,
                                              float* __restrict__ dinv, int n) {
    __shared__ int hist[RB];
    __shared__ int cur[RB];
    __shared__ int psum[256];
    __shared__ int qh[64];
    __shared__ int qb[64];
    __shared__ int stage[STAGE_CAP];
    int t = threadIdx.x;
    int bkt = blockIdx.x;
    int start = bkt << CAPB_BITS;
    int endi = gcur[bkt];
    int nv = endi - start;
    int n4 = nv >> 2;
    const v4i* t4 = reinterpret_cast<const v4i*>(temp + start);
    hist[t] = 0;
    if (t < 64) qh[t] = 0;
    __syncthreads();
    for (int k = t; k < n4; k += 256) {
        v4i v = t4[k];
        atomicAdd(&hist[v.x >> 17], 1);
        atomicAdd(&hist[v.y >> 17], 1);
        atomicAdd(&hist[v.z >> 17], 1);
        atomicAdd(&hist[v.w >> 17], 1);
    }
    for (int k = start + (n4 << 2) + t; k < endi; k += 256)
        atomicAdd(&hist[temp[k] >> 17], 1);
    __syncthreads();
    int node = (bkt << RB_BITS) + t;
    int h = hist[t];
    int p = (h + PADQ - 1) & ~(PADQ - 1);
    bool va = (node < n);
    if (va) dinv[node] = rsqrtf((float)(h + 1));
    psum[t] = p;
    __syncthreads();
    for (int off = 1; off < 256; off <<= 1) {
        int tmp = (t >= off) ? psum[t - off] : 0;
        __syncthreads();
        psum[t] += tmp;
        __syncthreads();
    }
    int pexcl = psum[t] - p;
    int s0 = start + pexcl;
    // heavy-first degree bins
    int q = 63 - min(p >> 5, 63);
    int r = atomicAdd(&qh[q], 1);
    __syncthreads();
    int ptotal = psum[255];
    if (t == 0) {
        int run = 0;
        for (int i = 0; i < 64; ++i) { qb[i] = run; run += qh[i]; }
    }
    __syncthreads();
    int ga = (bkt << RB_BITS) + qb[q] + r;
    ostart[ga] = s0; oend[ga] = s0 + p; onode[ga] = va ? node : -1;

    if (ptotal <= STAGE_CAP) {
        cur[t] = pexcl;
        for (int i = t; i < ptotal; i += 256) stage[i] = -1;
        __syncthreads();
        for (int k = t; k < n4; k += 256) {
            v4i v = t4[k];
            int p0 = atomicAdd(&cur[v.x >> 17], 1); stage[p0] = v.x & SRC_MASK;
            int p1 = atomicAdd(&cur[v.y >> 17], 1); stage[p1] = v.y & SRC_MASK;
            int p2 = atomicAdd(&cur[v.z >> 17], 1); stage[p2] = v.z & SRC_MASK;
            int p3 = atomicAdd(&cur[v.w >> 17], 1); stage[p3] = v.w & SRC_MASK;
        }
        for (int k = start + (n4 << 2) + t; k < endi; k += 256) {
            int v = temp[k];
            int pos = atomicAdd(&cur[v >> 17], 1);
            stage[pos] = v & SRC_MASK;
        }
        __syncthreads();
        for (int i = t * 4; i < ptotal; i += 1024) {
            v4i v = *reinterpret_cast<const v4i*>(&stage[i]);
            int gi = start + i;
            v.x = (v.x < 0) ? n + ((gi + 0) & (NDUMMY - 1)) : v.x;
            v.y = (v.y < 0) ? n + ((gi + 1) & (NDUMMY - 1)) : v.y;
            v.z = (v.z < 0) ? n + ((gi + 2) & (NDUMMY - 1)) : v.z;
            v.w = (v.w < 0) ? n + ((gi + 3) & (NDUMMY - 1)) : v.w;
            *reinterpret_cast<v4i*>(&csr[gi]) = v;
        }
    } else {
        cur[t] = s0;
        __syncthreads();
        for (int k = start + t; k < endi; k += 256) {
            int v = temp[k];
            int pos = atomicAdd(&cur[v >> 17], 1);
            csr[pos] = v & SRC_MASK;
        }
        __syncthreads();
        for (int i = s0 + h; i < s0 + p; ++i) csr[i] = n + (i & (NDUMMY - 1));
    }
}

// ---------------- h1' = dinv .* (x @ W1) -> fp16 table ----------------
__global__ __launch_bounds__(256) void k_mm1(const float* __restrict__ x,
                                             const float* __restrict__ W1,
                                             const float* __restrict__ dinv,
                                             __half* __restrict__ h1h, int n) {
    __shared__ __align__(16) float xs[16 * 132];
    __shared__ __align__(16) float ws[128 * 16];
    int t = threadIdx.x;
    int node0 = blockIdx.x * 16;
    const float4* x4 = reinterpret_cast<const float4*>(x);
    const float4* w4 = reinterpret_cast<const float4*>(W1);
#pragma unroll
    for (int r = 0; r < 2; ++r) {
        int f = t + r * 256;
        int nl = f >> 5, k4 = f & 31;
        int nn = node0 + nl; if (nn >= n) nn = n - 1;
        *reinterpret_cast<float4*>(&xs[nl * 132 + k4 * 4]) = x4[(size_t)nn * 32 + k4];
        *reinterpret_cast<float4*>(&ws[f * 4]) = w4[f];
    }
    __syncthreads();
    int nl = t >> 4, j = t & 15;
    float acc = 0.0f;
#pragma unroll 8
    for (int k = 0; k < 128; ++k)
        acc = fmaf(xs[nl * 132 + k], ws[k * 16 + j], acc);
    int node = node0 + nl;
    if (node < n) h1h[(size_t)node * H + j] = __float2half(acc * dinv[node]);
}

__device__ __forceinline__ void acc8(float* a, int4 gv) {
    const __half2* h = reinterpret_cast<const __half2*>(&gv);
    float2 f0 = __half22float2(h[0]);
    float2 f1 = __half22float2(h[1]);
    float2 f2 = __half22float2(h[2]);
    float2 f3 = __half22float2(h[3]);
    a[0] += f0.x; a[1] += f0.y; a[2] += f1.x; a[3] += f1.y;
    a[4] += f2.x; a[5] += f2.y; a[6] += f3.x; a[7] += f3.y;
}

// ---------------- gather conv1: 4 lanes/node, 16 gathers in flight/lane;
//                  heavy-first order; + bias + ReLU + BN stats ----------------
__global__ __launch_bounds__(256) void k_gather1(const int* __restrict__ ostart,
                                                 const int* __restrict__ oend,
                                                 const int* __restrict__ onode,
                                                 const int* __restrict__ csr,
                                                 const __half* __restrict__ h1h,
                                                 const float* __restrict__ dinv,
                                                 const float* __restrict__ b1,
                                                 float* __restrict__ hout,
                                                 float* __restrict__ stats, int n) {
    __shared__ float sm[32];
    __shared__ float b1s[16];
    int t = threadIdx.x;
    if (t < 32) sm[t] = 0.0f;
    if (t < 16) b1s[t] = b1[t];
    __syncthreads();
    int idx = blockIdx.x * 256 + t;
    int g = idx >> 2;
    int L = idx & 3, p = L >> 1, jj = L & 1;
    int node = __builtin_nontemporal_load(onode + g);
    float a[8];
#pragma unroll
    for (int k = 0; k < 8; ++k) a[k] = 0.0f;
    const int4* tab = reinterpret_cast<const int4*>(h1h);
    if (node >= 0) {
        int c  = (__builtin_nontemporal_load(ostart + g) >> 2) + (p << 2);
        int ce = __builtin_nontemporal_load(oend + g) >> 2;
        const v4i* csr4 = reinterpret_cast<const v4i*>(csr);
        for (; c < ce; c += 8) {
            v4i e0 = __builtin_nontemporal_load(csr4 + c);
            v4i e1 = __builtin_nontemporal_load(csr4 + c + 1);
            v4i e2 = __builtin_nontemporal_load(csr4 + c + 2);
            v4i e3 = __builtin_nontemporal_load(csr4 + c + 3);
            int4 g0  = tab[(size_t)e0.x * 2 + jj];
            int4 g1  = tab[(size_t)e0.y * 2 + jj];
            int4 g2  = tab[(size_t)e0.z * 2 + jj];
            int4 g3  = tab[(size_t)e0.w * 2 + jj];
            int4 g4  = tab[(size_t)e1.x * 2 + jj];
            int4 g5  = tab[(size_t)e1.y * 2 + jj];
            int4 g6  = tab[(size_t)e1.z * 2 + jj];
            int4 g7  = tab[(size_t)e1.w * 2 + jj];
            int4 g8  = tab[(size_t)e2.x * 2 + jj];
            int4 g9  = tab[(size_t)e2.y * 2 + jj];
            int4 g10 = tab[(size_t)e2.z * 2 + jj];
            int4 g11 = tab[(size_t)e2.w * 2 + jj];
            int4 g12 = tab[(size_t)e3.x * 2 + jj];
            int4 g13 = tab[(size_t)e3.y * 2 + jj];
            int4 g14 = tab[(size_t)e3.z * 2 + jj];
            int4 g15 = tab[(size_t)e3.w * 2 + jj];
            acc8(a, g0);  acc8(a, g1);  acc8(a, g2);  acc8(a, g3);
            acc8(a, g4);  acc8(a, g5);  acc8(a, g6);  acc8(a, g7);
            acc8(a, g8);  acc8(a, g9);  acc8(a, g10); acc8(a, g11);
            acc8(a, g12); acc8(a, g13); acc8(a, g14); acc8(a, g15);
        }
    }
#pragma unroll
    for (int k = 0; k < 8; ++k) a[k] += __shfl_xor(a[k], 2);
    float din = 0.0f;
    int4 sv = make_int4(0, 0, 0, 0);
    if (node >= 0) {
        din = dinv[node];
        sv = tab[(size_t)node * 2 + jj];
    }
    float v[8];
    {
        const __half2* h = reinterpret_cast<const __half2*>(&sv);
        float2 f0 = __half22float2(h[0]), f1 = __half22float2(h[1]);
        float2 f2 = __half22float2(h[2]), f3 = __half22float2(h[3]);
        float s8[8] = { f0.x, f0.y, f1.x, f1.y, f2.x, f2.y, f3.x, f3.y };
        bool writer = (node >= 0) && (p == 0);
#pragma unroll
        for (int k = 0; k < 8; ++k) {
            float val = fmaxf(din * (a[k] + s8[k]) + b1s[jj * 8 + k], 0.0f);
            v[k] = writer ? val : 0.0f;
        }
        if (writer) {
            float4* o = reinterpret_cast<float4*>(hout + (size_t)node * H + jj * 8);
            o[0] = make_float4(v[0], v[1], v[2], v[3]);
            o[1] = make_float4(v[4], v[5], v[6], v[7]);
        }
    }
#pragma unroll
    for (int k = 0; k < 8; ++k) {
        float s1 = v[k], s2 = v[k] * v[k];
        s1 += __shfl_xor(s1, 2);  s2 += __shfl_xor(s2, 2);
        s1 += __shfl_xor(s1, 4);  s2 += __shfl_xor(s2, 4);
        s1 += __shfl_xor(s1, 8);  s2 += __shfl_xor(s2, 8);
        s1 += __shfl_xor(s1, 16); s2 += __shfl_xor(s2, 16);
        s1 += __shfl_xor(s1, 32); s2 += __shfl_xor(s2, 32);
        if ((t & 63) < 2) {
            atomicAdd(&sm[jj * 8 + k], s1);
            atomicAdd(&sm[16 + jj * 8 + k], s2);
        }
    }
    __syncthreads();
    if (t < 32) atomicAdd(&stats[t], sm[t]);
}

// ---------------- BN coefficients ----------------
__global__ void k_bncoef(float* __restrict__ stats, const float* __restrict__ gamma,
                         const float* __restrict__ beta, float nf) {
    int j = threadIdx.x;
    if (j < 16) {
        float mean = stats[j] / nf;
        float var = stats[16 + j] / nf - mean * mean;
        float a = gamma[j] * rsqrtf(var + BN_EPS);
        float c = beta[j] - mean * a;
        stats[j] = a;
        stats[16 + j] = c;
    }
}

// ---------------- BN apply + K_HOPS residual blocks -> scaled fp16 table ----------------
__global__ __launch_bounds__(256) void k_hops(const float* __restrict__ h,
                                              __half* __restrict__ hh,
                                              const float* __restrict__ stats,
                                              const float* __restrict__ Wl,
                                              const float* __restrict__ bl,
                                              const float* __restrict__ dinv, int n) {
    __shared__ float wl[256], bls[16], av[16], cv[16];
    int t = threadIdx.x;
    wl[t] = Wl[(t & 15) * 16 + (t >> 4)];
    if (t < 16) { bls[t] = bl[t]; av[t] = stats[t]; cv[t] = stats[16 + t]; }
    __syncthreads();
    int node = blockIdx.x * 256 + t;
    if (node >= n) return;
    float hr[16];
    {
        const float4* hp = reinterpret_cast<const float4*>(h + (size_t)node * H);
        float4 v0 = hp[0], v1 = hp[1], v2 = hp[2], v3 = hp[3];
        hr[0] = v0.x; hr[1] = v0.y; hr[2] = v0.z; hr[3] = v0.w;
        hr[4] = v1.x; hr[5] = v1.y; hr[6] = v1.z; hr[7] = v1.w;
        hr[8] = v2.x; hr[9] = v2.y; hr[10] = v2.z; hr[11] = v2.w;
        hr[12] = v3.x; hr[13] = v3.y; hr[14] = v3.z; hr[15] = v3.w;
    }
#pragma unroll
    for (int j = 0; j < 16; ++j) hr[j] = hr[j] * av[j] + cv[j];
    for (int it = 0; it < K_HOPS; ++it) {
        float tmp[16];
#pragma unroll
        for (int j = 0; j < 16; ++j) {
            float a = bls[j];
#pragma unroll
            for (int k = 0; k < 16; ++k) a = fmaf(hr[k], wl[j * 16 + k], a);
            tmp[j] = fmaxf(a, 0.0f);
        }
#pragma unroll
        for (int j = 0; j < 16; ++j) hr[j] = ALPHA * tmp[j] + (1.0f - ALPHA) * hr[j];
    }
    {
        float din = dinv[node];
        __half2 ph[8];
#pragma unroll
        for (int i = 0; i < 8; ++i)
            ph[i] = __floats2half2_rn(hr[2 * i] * din, hr[2 * i + 1] * din);
        int4* hp = reinterpret_cast<int4*>(hh + (size_t)node * H);
        hp[0] = *reinterpret_cast<int4*>(&ph[0]);
        hp[1] = *reinterpret_cast<int4*>(&ph[4]);
    }
}

// ---------------- gather conv2: 4 lanes/node, 16 gathers in flight/lane; + self-loop ----------------
__global__ __launch_bounds__(256) void k_gather2(const int* __restrict__ ostart,
                                                 const int* __restrict__ oend,
                                                 const int* __restrict__ onode,
                                                 const int* __restrict__ csr,
                                                 const __half* __restrict__ hh,
                                                 const float* __restrict__ dinv,
                                                 float* __restrict__ agg, int n) {
    int t = threadIdx.x;
    int idx = blockIdx.x * 256 + t;
    int g = idx >> 2;
    int L = idx & 3, p = L >> 1, jj = L & 1;
    int node = __builtin_nontemporal_load(onode + g);
    float a[8];
#pragma unroll
    for (int k = 0; k < 8; ++k) a[k] = 0.0f;
    const int4* tab = reinterpret_cast<const int4*>(hh);
    if (node >= 0) {
        int c  = (__builtin_nontemporal_load(ostart + g) >> 2) + (p << 2);
        int ce = __builtin_nontemporal_load(oend + g) >> 2;
        const v4i* csr4 = reinterpret_cast<const v4i*>(csr);
        for (; c < ce; c += 8) {
            v4i e0 = __builtin_nontemporal_load(csr4 + c);
            v4i e1 = __builtin_nontemporal_load(csr4 + c + 1);
            v4i e2 = __builtin_nontemporal_load(csr4 + c + 2);
            v4i e3 = __builtin_nontemporal_load(csr4 + c + 3);
            int4 g0  = tab[(size_t)e0.x * 2 + jj];
            int4 g1  = tab[(size_t)e0.y * 2 + jj];
            int4 g2  = tab[(size_t)e0.z * 2 + jj];
            int4 g3  = tab[(size_t)e0.w * 2 + jj];
            int4 g4  = tab[(size_t)e1.x * 2 + jj];
            int4 g5  = tab[(size_t)e1.y * 2 + jj];
            int4 g6  = tab[(size_t)e1.z * 2 + jj];
            int4 g7  = tab[(size_t)e1.w * 2 + jj];
            int4 g8  = tab[(size_t)e2.x * 2 + jj];
            int4 g9  = tab[(size_t)e2.y * 2 + jj];
            int4 g10 = tab[(size_t)e2.z * 2 + jj];
            int4 g11 = tab[(size_t)e2.w * 2 + jj];
            int4 g12 = tab[(size_t)e3.x * 2 + jj];
            int4 g13 = tab[(size_t)e3.y * 2 + jj];
            int4 g14 = tab[(size_t)e3.z * 2 + jj];
            int4 g15 = tab[(size_t)e3.w * 2 + jj];
            acc8(a, g0);  acc8(a, g1);  acc8(a, g2);  acc8(a, g3);
            acc8(a, g4);  acc8(a, g5);  acc8(a, g6);  acc8(a, g7);
            acc8(a, g8);  acc8(a, g9);  acc8(a, g10); acc8(a, g11);
            acc8(a, g12); acc8(a, g13); acc8(a, g14); acc8(a, g15);
        }
    }
#pragma unroll
    for (int k = 0; k < 8; ++k) a[k] += __shfl_xor(a[k], 2);
    if (node >= 0 && p == 0) {
        float din = dinv[node];
        int4 sv = tab[(size_t)node * 2 + jj];
        const __half2* h = reinterpret_cast<const __half2*>(&sv);
        float2 f0 = __half22float2(h[0]), f1 = __half22float2(h[1]);
        float2 f2 = __half22float2(h[2]), f3 = __half22float2(h[3]);
        float s8[8] = { f0.x, f0.y, f1.x, f1.y, f2.x, f2.y, f3.x, f3.y };
        float v[8];
#pragma unroll
        for (int k = 0; k < 8; ++k) v[k] = din * (a[k] + s8[k]);
        float4* o = reinterpret_cast<float4*>(agg + (size_t)node * H + jj * 8);
        o[0] = make_float4(v[0], v[1], v[2], v[3]);
        o[1] = make_float4(v[4], v[5], v[6], v[7]);
    }
}

// ---------------- final: agg2 @ W2 + b2 -> log_softmax ----------------
__global__ __launch_bounds__(256) void k_final(const float* __restrict__ agg2,
                                               const float* __restrict__ W2,
                                               const float* __restrict__ b2,
                                               float* __restrict__ out, int n) {
    __shared__ float w2s[16 * 40];
    __shared__ float b2s[40];
    __shared__ float ostage[40 * 257];
    int t = threadIdx.x;
    for (int i = t; i < 640; i += 256) w2s[i] = W2[i];
    if (t < 40) b2s[t] = b2[t];
    __syncthreads();
    int node = blockIdx.x * 256 + t;
    if (node < n) {
        float g[16];
        const float4* ap = reinterpret_cast<const float4*>(agg2 + (size_t)node * H);
#pragma unroll
        for (int r = 0; r < 4; ++r) {
            float4 a = ap[r];
            g[r * 4 + 0] = a.x; g[r * 4 + 1] = a.y; g[r * 4 + 2] = a.z; g[r * 4 + 3] = a.w;
        }
        float z[40];
#pragma unroll
        for (int j = 0; j < 40; ++j) {
            float a = b2s[j];
#pragma unroll
            for (int k = 0; k < 16; ++k) a = fmaf(g[k], w2s[k * 40 + j], a);
            z[j] = a;
        }
        float m = z[0];
#pragma unroll
        for (int j = 1; j < 40; ++j) m = fmaxf(m, z[j]);
        float s = 0.0f;
#pragma unroll
        for (int j = 0; j < 40; ++j) s += expf(z[j] - m);
        float lse = m + logf(s);
#pragma unroll
        for (int j = 0; j < 40; ++j) ostage[j * 257 + t] = z[j] - lse;
    }
    __syncthreads();
    int nodes = n - blockIdx.x * 256;
    if (nodes > 256) nodes = 256;
    int total = nodes * 40;
    size_t base = (size_t)blockIdx.x * 256 * 40;
    for (int i = t; i < total; i += 256) {
        int nl = i / 40;
        int j = i - nl * 40;
        out[base + i] = ostage[j * 257 + nl];
    }
}

extern "C" void kernel_launch(void* const* d_in, const int* in_sizes, int n_in,
                              void* d_out, int out_size, void* d_ws, size_t ws_size,
                              hipStream_t stream) {
    const float* x     = (const float*)d_in[0];
    const int*   src   = (const int*)d_in[1];
    const int*   dst   = (const int*)d_in[2];
    const float* W1    = (const float*)d_in[3];
    const float* b1    = (const float*)d_in[4];
    const float* gamma = (const float*)d_in[5];
    const float* beta  = (const float*)d_in[6];
    const float* Wl    = (const float*)d_in[7];
    const float* bl    = (const float*)d_in[8];
    const float* W2    = (const float*)d_in[9];
    const float* b2    = (const float*)d_in[10];
    float* out = (float*)d_out;

    int n = in_sizes[0] / F_IN;   // 100000
    int e = in_sizes[1];          // 3200000
    int nbkt = (n + RB - 1) >> RB_BITS;   // 391
    int nAlign = (n + 15) & ~15;
    int nG = nbkt * RB;                                      // ordered-node slots
    size_t bktB = (size_t)nbkt << CAPB_BITS;                 // fixed-capacity entries (temp & csr)
    size_t hTileB = (size_t)nAlign * H * 4;                  // 6.4 MB
    size_t unionB = bktB * 4;                                // temp (25.6 MB)
    if (unionB < 2 * hTileB) unionB = 2 * hTileB;            // also holds hbuf+agg2 later

    char* wsb = (char*)d_ws;
    int*    csr      = (int*)wsb;      wsb += (bktB + 64) * 4;
    char*   uni      = wsb;            wsb += unionB;
    int*    temp     = (int*)uni;                  // alive: k_bin .. k_sort
    float*  hbuf     = (float*)uni;                // alive: k_gather1 .. k_hops
    float*  agg2     = (float*)(uni + hTileB);     // alive: k_gather2 .. k_final
    int*    ostart   = (int*)wsb;      wsb += (size_t)(nG + 16) * 4;
    int*    oend     = (int*)wsb;      wsb += (size_t)(nG + 16) * 4;
    int*    onode    = (int*)wsb;      wsb += (size_t)(nG + 16) * 4;
    float*  dinv     = (float*)wsb;    wsb += (size_t)nAlign * 4;
    int*    gcur     = (int*)wsb;      wsb += NBKT_MAX * 4;
    float*  stats    = (float*)wsb;    wsb += 64 * 4;
    __half* h1h      = (__half*)wsb;   wsb += (size_t)(nAlign + NDUMMY + 16) * H * 2;
    __half* hh       = (__half*)wsb;   wsb += (size_t)(nAlign + NDUMMY + 16) * H * 2;

    k_zero<<<64, 256, 0, stream>>>(gcur, stats, h1h, hh, n);
    k_bin<<<(e + BIN_CHUNK - 1) / BIN_CHUNK, 256, 0, stream>>>(src, dst, gcur, temp, e);
    k_sort<<<nbkt, 256, 0, stream>>>(gcur, temp, csr, ostart, oend, onode, dinv, n);
    k_mm1<<<(n + 15) / 16, 256, 0, stream>>>(x, W1, dinv, h1h, n);
    k_gather1<<<nbkt * 4, 256, 0, stream>>>(ostart, oend, onode, csr, h1h, dinv, b1, hbuf, stats, n);
    k_bncoef<<<1, 16, 0, stream>>>(stats, gamma, beta, (float)n);
    k_hops<<<(n + 255) / 256, 256, 0, stream>>>(hbuf, hh, stats, Wl, bl, dinv, n);
    k_gather2<<<nbkt * 4, 256, 0, stream>>>(ostart, oend, onode, csr, hh, dinv, agg2, n);
    k_final<<<(n + 255) / 256, 256, 0, stream>>>(agg2, W2, b2, out, n);
}

// Round 6
// 267.783 us; speedup vs baseline: 1.4036x; 1.0709x over previous
//
#include <hip/hip_runtime.h>
#include <hip/hip_fp16.h>
#include <math.h>

#define F_IN 128
#define H 16
#define C 40
#define K_HOPS 10
#define ALPHA 0.1f
#define BN_EPS 1e-5f

#define RB 256          // nodes per bucket
#define RB_BITS 8
#define NBKT_MAX 512    // ceil(100000/256)=391
#define SRC_MASK 0x1FFFF
#define PADQ 32         // node segment padded to multiple of 32 entries
#define NDUMMY 2048     // dummy zero rows spread over L2
#define CAPB_BITS 14    // fixed per-bucket capacity for temp AND csr (16384 entries)
#define CAPB (1 << CAPB_BITS)
#define STAGE_CAP 14336 // ints (56 KB) LDS staging for csr scatter

typedef int v4i __attribute__((ext_vector_type(4)));

// ---------------- zero: gcur = bucket bases, stats=0, dummy rows of both tables = 0 ----------------
__global__ void k_zero(int* __restrict__ gcur, float* __restrict__ stats,
                       __half* __restrict__ h1h, __half* __restrict__ hh, int n) {
    int id = blockIdx.x * blockDim.x + threadIdx.x;
    if (id < NBKT_MAX) gcur[id] = id << CAPB_BITS;
    if (id < 32) stats[id] = 0.0f;
    int* z1 = (int*)(h1h + (size_t)n * H);
    int* z2 = (int*)(hh + (size_t)n * H);
    if (id < NDUMMY * H / 2) { z1[id] = 0; z2[id] = 0; }
}

// ---------------- bin edges: LDS counting sort per block -> dense run writes ----------------
// 512 threads, 8 edges/thread; shfl scan (3 barriers); int stageD = precomputed global delta
#define BIN_CHUNK 4096
__global__ __launch_bounds__(512) void k_bin(const int* __restrict__ src,
                                             const int* __restrict__ dst,
                                             int* __restrict__ gcur,
                                             int* __restrict__ temp, int e) {
    __shared__ int hist[NBKT_MAX];
    __shared__ int cur[NBKT_MAX];
    __shared__ int gofs[NBKT_MAX];
    __shared__ int wsum[8];
    __shared__ int stageV[BIN_CHUNK];
    __shared__ int stageD[BIN_CHUNK];
    int t = threadIdx.x;
    hist[t] = 0;
    __syncthreads();
    int base = blockIdx.x * BIN_CHUNK;
    int cnt = e - base; if (cnt > BIN_CHUNK) cnt = BIN_CHUNK;
    const v4i* s4 = reinterpret_cast<const v4i*>(src + base);
    const v4i* d4 = reinterpret_cast<const v4i*>(dst + base);
    v4i sv[2], dv[2];
#pragma unroll
    for (int i = 0; i < 2; ++i) {
        int e0 = (t * 2 + i) * 4;
        if (e0 + 3 < cnt) { sv[i] = s4[t * 2 + i]; dv[i] = d4[t * 2 + i]; }
        else if (e0 < cnt) {
            int ts[4], td[4];
#pragma unroll
            for (int j = 0; j < 4; ++j) {
                int ei = e0 + j;
                ts[j] = (ei < cnt) ? src[base + ei] : 0;
                td[j] = (ei < cnt) ? dst[base + ei] : -1;
            }
            sv[i] = *reinterpret_cast<v4i*>(ts); dv[i] = *reinterpret_cast<v4i*>(td);
        } else { dv[i] = (v4i){-1, -1, -1, -1}; sv[i] = dv[i]; }
    }
#pragma unroll
    for (int i = 0; i < 2; ++i) {
        if (dv[i].x >= 0) atomicAdd(&hist[dv[i].x >> RB_BITS], 1);
        if (dv[i].y >= 0) atomicAdd(&hist[dv[i].y >> RB_BITS], 1);
        if (dv[i].z >= 0) atomicAdd(&hist[dv[i].z >> RB_BITS], 1);
        if (dv[i].w >= 0) atomicAdd(&hist[dv[i].w >> RB_BITS], 1);
    }
    __syncthreads();
    // inclusive shfl scan over 512 buckets (thread t owns bucket t)
    int v = hist[t];
    int lane = t & 63, wv = t >> 6;
    int s = v;
#pragma unroll
    for (int off = 1; off < 64; off <<= 1) { int u = __shfl_up(s, off); if (lane >= off) s += u; }
    if (lane == 63) wsum[wv] = s;
    __syncthreads();
    if (t < 8) {
        int x = wsum[t];
#pragma unroll
        for (int off = 1; off < 8; off <<= 1) { int u = __shfl_up(x, off); if (t >= off) x += u; }
        wsum[t] = x;
    }
    __syncthreads();
    int excl = s - v + (wv ? wsum[wv - 1] : 0);
    cur[t] = excl;
    int g = v ? atomicAdd(&gcur[t], v) : 0;
    gofs[t] = g - excl;
    __syncthreads();
#pragma unroll
    for (int i = 0; i < 2; ++i) {
        int ds[4] = { dv[i].x, dv[i].y, dv[i].z, dv[i].w };
        int ssx[4] = { sv[i].x, sv[i].y, sv[i].z, sv[i].w };
#pragma unroll
        for (int j = 0; j < 4; ++j) {
            int d = ds[j];
            if (d >= 0) {
                int b = d >> RB_BITS;
                int pos = atomicAdd(&cur[b], 1);
                stageV[pos] = ssx[j] | ((d & (RB - 1)) << 17);
                stageD[pos] = gofs[b];
            }
        }
    }
    __syncthreads();
    // stage-order copy out: consecutive threads -> consecutive slots of same run
    for (int i = t; i < cnt; i += 512)
        temp[stageD[i] + i] = stageV[i];
}

// ---------------- per-bucket counting sort -> padded CSR (LDS-staged scatter, int4 loads);
//                  deg->dinv; HEAVY-FIRST degree-sorted node order ----------------
__global__ __launch_bounds__(256) void k_sort(const int* __restrict__ gcur,
                                              const int* __restrict__ temp,
                                              int* __restrict__ csr,
                                              int* __restrict__ ostart,
                                              int* __restrict__ oend,
                                              int* __restrict__ onode,
                                              float* __restrict__ dinv, int n) {
    __shared__ int hist[RB];
    __shared__ int cur[RB];
    __shared__ int wsum[8];
    __shared__ int qh[64];
    __shared__ int qb[64];
    __shared__ int ptotS;
    __shared__ int stage[STAGE_CAP];
    int t = threadIdx.x;
    int bkt = blockIdx.x;
    int start = bkt << CAPB_BITS;
    int endi = gcur[bkt];
    int nv = endi - start;
    int n4 = nv >> 2;
    const v4i* t4 = reinterpret_cast<const v4i*>(temp + start);
    hist[t] = 0;
    if (t < 64) qh[t] = 0;
    __syncthreads();
    for (int k = t; k < n4; k += 256) {
        v4i v = t4[k];
        atomicAdd(&hist[v.x >> 17], 1);
        atomicAdd(&hist[v.y >> 17], 1);
        atomicAdd(&hist[v.z >> 17], 1);
        atomicAdd(&hist[v.w >> 17], 1);
    }
    for (int k = start + (n4 << 2) + t; k < endi; k += 256)
        atomicAdd(&hist[temp[k] >> 17], 1);
    __syncthreads();
    int node = (bkt << RB_BITS) + t;
    int h = hist[t];
    int p = (h + PADQ - 1) & ~(PADQ - 1);
    bool va = (node < n);
    if (va) dinv[node] = rsqrtf((float)(h + 1));
    // inclusive shfl scan over 256 padded degrees
    int lane = t & 63, wv = t >> 6;
    int s = p;
#pragma unroll
    for (int off = 1; off < 64; off <<= 1) { int u = __shfl_up(s, off); if (lane >= off) s += u; }
    if (lane == 63) wsum[wv] = s;
    __syncthreads();
    if (t < 4) {
        int x = wsum[t];
#pragma unroll
        for (int off = 1; off < 4; off <<= 1) { int u = __shfl_up(x, off); if (t >= off) x += u; }
        wsum[t] = x;
        if (t == 3) ptotS = x;
    }
    __syncthreads();
    int pexcl = s - p + (wv ? wsum[wv - 1] : 0);
    int s0 = start + pexcl;
    // heavy-first degree bins
    int q = 63 - min(p >> 5, 63);
    int r = atomicAdd(&qh[q], 1);
    __syncthreads();
    int ptotal = ptotS;
    if (t == 0) {
        int run = 0;
        for (int i = 0; i < 64; ++i) { qb[i] = run; run += qh[i]; }
    }
    __syncthreads();
    int ga = (bkt << RB_BITS) + qb[q] + r;
    ostart[ga] = s0; oend[ga] = s0 + p; onode[ga] = va ? node : -1;

    if (ptotal <= STAGE_CAP) {
        cur[t] = pexcl;
        for (int i = t; i < ptotal; i += 256) stage[i] = -1;
        __syncthreads();
        for (int k = t; k < n4; k += 256) {
            v4i v = t4[k];
            int p0 = atomicAdd(&cur[v.x >> 17], 1); stage[p0] = v.x & SRC_MASK;
            int p1 = atomicAdd(&cur[v.y >> 17], 1); stage[p1] = v.y & SRC_MASK;
            int p2 = atomicAdd(&cur[v.z >> 17], 1); stage[p2] = v.z & SRC_MASK;
            int p3 = atomicAdd(&cur[v.w >> 17], 1); stage[p3] = v.w & SRC_MASK;
        }
        for (int k = start + (n4 << 2) + t; k < endi; k += 256) {
            int v = temp[k];
            int pos = atomicAdd(&cur[v >> 17], 1);
            stage[pos] = v & SRC_MASK;
        }
        __syncthreads();
        for (int i = t * 4; i < ptotal; i += 1024) {
            v4i v = *reinterpret_cast<const v4i*>(&stage[i]);
            int gi = start + i;
            v.x = (v.x < 0) ? n + ((gi + 0) & (NDUMMY - 1)) : v.x;
            v.y = (v.y < 0) ? n + ((gi + 1) & (NDUMMY - 1)) : v.y;
            v.z = (v.z < 0) ? n + ((gi + 2) & (NDUMMY - 1)) : v.z;
            v.w = (v.w < 0) ? n + ((gi + 3) & (NDUMMY - 1)) : v.w;
            *reinterpret_cast<v4i*>(&csr[gi]) = v;
        }
    } else {
        cur[t] = s0;
        __syncthreads();
        for (int k = start + t; k < endi; k += 256) {
            int v = temp[k];
            int pos = atomicAdd(&cur[v >> 17], 1);
            csr[pos] = v & SRC_MASK;
        }
        __syncthreads();
        for (int i = s0 + h; i < s0 + p; ++i) csr[i] = n + (i & (NDUMMY - 1));
    }
}

// ---------------- h1' = dinv .* (x @ W1) -> fp16 table ----------------
__global__ __launch_bounds__(256) void k_mm1(const float* __restrict__ x,
                                             const float* __restrict__ W1,
                                             const float* __restrict__ dinv,
                                             __half* __restrict__ h1h, int n) {
    __shared__ __align__(16) float xs[16 * 132];
    __shared__ __align__(16) float ws[128 * 16];
    int t = threadIdx.x;
    int node0 = blockIdx.x * 16;
    const float4* x4 = reinterpret_cast<const float4*>(x);
    const float4* w4 = reinterpret_cast<const float4*>(W1);
#pragma unroll
    for (int r = 0; r < 2; ++r) {
        int f = t + r * 256;
        int nl = f >> 5, k4 = f & 31;
        int nn = node0 + nl; if (nn >= n) nn = n - 1;
        *reinterpret_cast<float4*>(&xs[nl * 132 + k4 * 4]) = x4[(size_t)nn * 32 + k4];
        *reinterpret_cast<float4*>(&ws[f * 4]) = w4[f];
    }
    __syncthreads();
    int nl = t >> 4, j = t & 15;
    float acc = 0.0f;
#pragma unroll 8
    for (int k = 0; k < 128; ++k)
        acc = fmaf(xs[nl * 132 + k], ws[k * 16 + j], acc);
    int node = node0 + nl;
    if (node < n) h1h[(size_t)node * H + j] = __float2half(acc * dinv[node]);
}

__device__ __forceinline__ void acc8(float* a, int4 gv) {
    const __half2* h = reinterpret_cast<const __half2*>(&gv);
    float2 f0 = __half22float2(h[0]);
    float2 f1 = __half22float2(h[1]);
    float2 f2 = __half22float2(h[2]);
    float2 f3 = __half22float2(h[3]);
    a[0] += f0.x; a[1] += f0.y; a[2] += f1.x; a[3] += f1.y;
    a[4] += f2.x; a[5] += f2.y; a[6] += f3.x; a[7] += f3.y;
}

// ---------------- gather conv1: 4 lanes/node, 16 gathers in flight/lane;
//                  heavy-first order; + bias + ReLU + BN stats ----------------
__global__ __launch_bounds__(256) void k_gather1(const int* __restrict__ ostart,
                                                 const int* __restrict__ oend,
                                                 const int* __restrict__ onode,
                                                 const int* __restrict__ csr,
                                                 const __half* __restrict__ h1h,
                                                 const float* __restrict__ dinv,
                                                 const float* __restrict__ b1,
                                                 float* __restrict__ hout,
                                                 float* __restrict__ stats, int n) {
    __shared__ float sm[32];
    __shared__ float b1s[16];
    int t = threadIdx.x;
    if (t < 32) sm[t] = 0.0f;
    if (t < 16) b1s[t] = b1[t];
    __syncthreads();
    int idx = blockIdx.x * 256 + t;
    int g = idx >> 2;
    int L = idx & 3, p = L >> 1, jj = L & 1;
    int node = __builtin_nontemporal_load(onode + g);
    float a[8];
#pragma unroll
    for (int k = 0; k < 8; ++k) a[k] = 0.0f;
    const int4* tab = reinterpret_cast<const int4*>(h1h);
    if (node >= 0) {
        int c  = (__builtin_nontemporal_load(ostart + g) >> 2) + (p << 2);
        int ce = __builtin_nontemporal_load(oend + g) >> 2;
        const v4i* csr4 = reinterpret_cast<const v4i*>(csr);
        for (; c < ce; c += 8) {
            v4i e0 = __builtin_nontemporal_load(csr4 + c);
            v4i e1 = __builtin_nontemporal_load(csr4 + c + 1);
            v4i e2 = __builtin_nontemporal_load(csr4 + c + 2);
            v4i e3 = __builtin_nontemporal_load(csr4 + c + 3);
            int4 g0  = tab[(size_t)e0.x * 2 + jj];
            int4 g1  = tab[(size_t)e0.y * 2 + jj];
            int4 g2  = tab[(size_t)e0.z * 2 + jj];
            int4 g3  = tab[(size_t)e0.w * 2 + jj];
            int4 g4  = tab[(size_t)e1.x * 2 + jj];
            int4 g5  = tab[(size_t)e1.y * 2 + jj];
            int4 g6  = tab[(size_t)e1.z * 2 + jj];
            int4 g7  = tab[(size_t)e1.w * 2 + jj];
            int4 g8  = tab[(size_t)e2.x * 2 + jj];
            int4 g9  = tab[(size_t)e2.y * 2 + jj];
            int4 g10 = tab[(size_t)e2.z * 2 + jj];
            int4 g11 = tab[(size_t)e2.w * 2 + jj];
            int4 g12 = tab[(size_t)e3.x * 2 + jj];
            int4 g13 = tab[(size_t)e3.y * 2 + jj];
            int4 g14 = tab[(size_t)e3.z * 2 + jj];
            int4 g15 = tab[(size_t)e3.w * 2 + jj];
            acc8(a, g0);  acc8(a, g1);  acc8(a, g2);  acc8(a, g3);
            acc8(a, g4);  acc8(a, g5);  acc8(a, g6);  acc8(a, g7);
            acc8(a, g8);  acc8(a, g9);  acc8(a, g10); acc8(a, g11);
            acc8(a, g12); acc8(a, g13); acc8(a, g14); acc8(a, g15);
        }
    }
#pragma unroll
    for (int k = 0; k < 8; ++k) a[k] += __shfl_xor(a[k], 2);
    float din = 0.0f;
    int4 sv = make_int4(0, 0, 0, 0);
    if (node >= 0) {
        din = dinv[node];
        sv = tab[(size_t)node * 2 + jj];
    }
    float v[8];
    {
        const __half2* h = reinterpret_cast<const __half2*>(&sv);
        float2 f0 = __half22float2(h[0]), f1 = __half22float2(h[1]);
        float2 f2 = __half22float2(h[2]), f3 = __half22float2(h[3]);
        float s8[8] = { f0.x, f0.y, f1.x, f1.y, f2.x, f2.y, f3.x, f3.y };
        bool writer = (node >= 0) && (p == 0);
#pragma unroll
        for (int k = 0; k < 8; ++k) {
            float val = fmaxf(din * (a[k] + s8[k]) + b1s[jj * 8 + k], 0.0f);
            v[k] = writer ? val : 0.0f;
        }
        if (writer) {
            float4* o = reinterpret_cast<float4*>(hout + (size_t)node * H + jj * 8);
            o[0] = make_float4(v[0], v[1], v[2], v[3]);
            o[1] = make_float4(v[4], v[5], v[6], v[7]);
        }
    }
#pragma unroll
    for (int k = 0; k < 8; ++k) {
        float s1 = v[k], s2 = v[k] * v[k];
        s1 += __shfl_xor(s1, 2);  s2 += __shfl_xor(s2, 2);
        s1 += __shfl_xor(s1, 4);  s2 += __shfl_xor(s2, 4);
        s1 += __shfl_xor(s1, 8);  s2 += __shfl_xor(s2, 8);
        s1 += __shfl_xor(s1, 16); s2 += __shfl_xor(s2, 16);
        s1 += __shfl_xor(s1, 32); s2 += __shfl_xor(s2, 32);
        if ((t & 63) < 2) {
            atomicAdd(&sm[jj * 8 + k], s1);
            atomicAdd(&sm[16 + jj * 8 + k], s2);
        }
    }
    __syncthreads();
    if (t < 32) atomicAdd(&stats[t], sm[t]);
}

// ---------------- BN coefficients ----------------
__global__ void k_bncoef(float* __restrict__ stats, const float* __restrict__ gamma,
                         const float* __restrict__ beta, float nf) {
    int j = threadIdx.x;
    if (j < 16) {
        float mean = stats[j] / nf;
        float var = stats[16 + j] / nf - mean * mean;
        float a = gamma[j] * rsqrtf(var + BN_EPS);
        float c = beta[j] - mean * a;
        stats[j] = a;
        stats[16 + j] = c;
    }
}

// ---------------- BN apply + K_HOPS residual blocks -> scaled fp16 table ----------------
__global__ __launch_bounds__(256) void k_hops(const float* __restrict__ h,
                                              __half* __restrict__ hh,
                                              const float* __restrict__ stats,
                                              const float* __restrict__ Wl,
                                              const float* __restrict__ bl,
                                              const float* __restrict__ dinv, int n) {
    __shared__ float wl[256], bls[16], av[16], cv[16];
    int t = threadIdx.x;
    wl[t] = Wl[(t & 15) * 16 + (t >> 4)];
    if (t < 16) { bls[t] = bl[t]; av[t] = stats[t]; cv[t] = stats[16 + t]; }
    __syncthreads();
    int node = blockIdx.x * 256 + t;
    if (node >= n) return;
    float hr[16];
    {
        const float4* hp = reinterpret_cast<const float4*>(h + (size_t)node * H);
        float4 v0 = hp[0], v1 = hp[1], v2 = hp[2], v3 = hp[3];
        hr[0] = v0.x; hr[1] = v0.y; hr[2] = v0.z; hr[3] = v0.w;
        hr[4] = v1.x; hr[5] = v1.y; hr[6] = v1.z; hr[7] = v1.w;
        hr[8] = v2.x; hr[9] = v2.y; hr[10] = v2.z; hr[11] = v2.w;
        hr[12] = v3.x; hr[13] = v3.y; hr[14] = v3.z; hr[15] = v3.w;
    }
#pragma unroll
    for (int j = 0; j < 16; ++j) hr[j] = hr[j] * av[j] + cv[j];
    for (int it = 0; it < K_HOPS; ++it) {
        float tmp[16];
#pragma unroll
        for (int j = 0; j < 16; ++j) {
            float a = bls[j];
#pragma unroll
            for (int k = 0; k < 16; ++k) a = fmaf(hr[k], wl[j * 16 + k], a);
            tmp[j] = fmaxf(a, 0.0f);
        }
#pragma unroll
        for (int j = 0; j < 16; ++j) hr[j] = ALPHA * tmp[j] + (1.0f - ALPHA) * hr[j];
    }
    {
        float din = dinv[node];
        __half2 ph[8];
#pragma unroll
        for (int i = 0; i < 8; ++i)
            ph[i] = __floats2half2_rn(hr[2 * i] * din, hr[2 * i + 1] * din);
        int4* hp = reinterpret_cast<int4*>(hh + (size_t)node * H);
        hp[0] = *reinterpret_cast<int4*>(&ph[0]);
        hp[1] = *reinterpret_cast<int4*>(&ph[4]);
    }
}

// ---------------- gather conv2: 4 lanes/node, 16 gathers in flight/lane; + self-loop ----------------
__global__ __launch_bounds__(256) void k_gather2(const int* __restrict__ ostart,
                                                 const int* __restrict__ oend,
                                                 const int* __restrict__ onode,
                                                 const int* __restrict__ csr,
                                                 const __half* __restrict__ hh,
                                                 const float* __restrict__ dinv,
                                                 float* __restrict__ agg, int n) {
    int t = threadIdx.x;
    int idx = blockIdx.x * 256 + t;
    int g = idx >> 2;
    int L = idx & 3, p = L >> 1, jj = L & 1;
    int node = __builtin_nontemporal_load(onode + g);
    float a[8];
#pragma unroll
    for (int k = 0; k < 8; ++k) a[k] = 0.0f;
    const int4* tab = reinterpret_cast<const int4*>(hh);
    if (node >= 0) {
        int c  = (__builtin_nontemporal_load(ostart + g) >> 2) + (p << 2);
        int ce = __builtin_nontemporal_load(oend + g) >> 2;
        const v4i* csr4 = reinterpret_cast<const v4i*>(csr);
        for (; c < ce; c += 8) {
            v4i e0 = __builtin_nontemporal_load(csr4 + c);
            v4i e1 = __builtin_nontemporal_load(csr4 + c + 1);
            v4i e2 = __builtin_nontemporal_load(csr4 + c + 2);
            v4i e3 = __builtin_nontemporal_load(csr4 + c + 3);
            int4 g0  = tab[(size_t)e0.x * 2 + jj];
            int4 g1  = tab[(size_t)e0.y * 2 + jj];
            int4 g2  = tab[(size_t)e0.z * 2 + jj];
            int4 g3  = tab[(size_t)e0.w * 2 + jj];
            int4 g4  = tab[(size_t)e1.x * 2 + jj];
            int4 g5  = tab[(size_t)e1.y * 2 + jj];
            int4 g6  = tab[(size_t)e1.z * 2 + jj];
            int4 g7  = tab[(size_t)e1.w * 2 + jj];
            int4 g8  = tab[(size_t)e2.x * 2 + jj];
            int4 g9  = tab[(size_t)e2.y * 2 + jj];
            int4 g10 = tab[(size_t)e2.z * 2 + jj];
            int4 g11 = tab[(size_t)e2.w * 2 + jj];
            int4 g12 = tab[(size_t)e3.x * 2 + jj];
            int4 g13 = tab[(size_t)e3.y * 2 + jj];
            int4 g14 = tab[(size_t)e3.z * 2 + jj];
            int4 g15 = tab[(size_t)e3.w * 2 + jj];
            acc8(a, g0);  acc8(a, g1);  acc8(a, g2);  acc8(a, g3);
            acc8(a, g4);  acc8(a, g5);  acc8(a, g6);  acc8(a, g7);
            acc8(a, g8);  acc8(a, g9);  acc8(a, g10); acc8(a, g11);
            acc8(a, g12); acc8(a, g13); acc8(a, g14); acc8(a, g15);
        }
    }
#pragma unroll
    for (int k = 0; k < 8; ++k) a[k] += __shfl_xor(a[k], 2);
    if (node >= 0 && p == 0) {
        float din = dinv[node];
        int4 sv = tab[(size_t)node * 2 + jj];
        const __half2* h = reinterpret_cast<const __half2*>(&sv);
        float2 f0 = __half22float2(h[0]), f1 = __half22float2(h[1]);
        float2 f2 = __half22float2(h[2]), f3 = __half22float2(h[3]);
        float s8[8] = { f0.x, f0.y, f1.x, f1.y, f2.x, f2.y, f3.x, f3.y };
        float v[8];
#pragma unroll
        for (int k = 0; k < 8; ++k) v[k] = din * (a[k] + s8[k]);
        float4* o = reinterpret_cast<float4*>(agg + (size_t)node * H + jj * 8);
        o[0] = make_float4(v[0], v[1], v[2], v[3]);
        o[1] = make_float4(v[4], v[5], v[6], v[7]);
    }
}

// ---------------- final: agg2 @ W2 + b2 -> log_softmax ----------------
__global__ __launch_bounds__(256) void k_final(const float* __restrict__ agg2,
                                               const float* __restrict__ W2,
                                               const float* __restrict__ b2,
                                               float* __restrict__ out, int n) {
    __shared__ float w2s[16 * 40];
    __shared__ float b2s[40];
    __shared__ float ostage[40 * 257];
    int t = threadIdx.x;
    for (int i = t; i < 640; i += 256) w2s[i] = W2[i];
    if (t < 40) b2s[t] = b2[t];
    __syncthreads();
    int node = blockIdx.x * 256 + t;
    if (node < n) {
        float g[16];
        const float4* ap = reinterpret_cast<const float4*>(agg2 + (size_t)node * H);
#pragma unroll
        for (int r = 0; r < 4; ++r) {
            float4 a = ap[r];
            g[r * 4 + 0] = a.x; g[r * 4 + 1] = a.y; g[r * 4 + 2] = a.z; g[r * 4 + 3] = a.w;
        }
        float z[40];
#pragma unroll
        for (int j = 0; j < 40; ++j) {
            float a = b2s[j];
#pragma unroll
            for (int k = 0; k < 16; ++k) a = fmaf(g[k], w2s[k * 40 + j], a);
            z[j] = a;
        }
        float m = z[0];
#pragma unroll
        for (int j = 1; j < 40; ++j) m = fmaxf(m, z[j]);
        float s = 0.0f;
#pragma unroll
        for (int j = 0; j < 40; ++j) s += expf(z[j] - m);
        float lse = m + logf(s);
#pragma unroll
        for (int j = 0; j < 40; ++j) ostage[j * 257 + t] = z[j] - lse;
    }
    __syncthreads();
    int nodes = n - blockIdx.x * 256;
    if (nodes > 256) nodes = 256;
    int total = nodes * 40;
    size_t base = (size_t)blockIdx.x * 256 * 40;
    for (int i = t; i < total; i += 256) {
        int nl = i / 40;
        int j = i - nl * 40;
        out[base + i] = ostage[j * 257 + nl];
    }
}

extern "C" void kernel_launch(void* const* d_in, const int* in_sizes, int n_in,
                              void* d_out, int out_size, void* d_ws, size_t ws_size,
                              hipStream_t stream) {
    const float* x     = (const float*)d_in[0];
    const int*   src   = (const int*)d_in[1];
    const int*   dst   = (const int*)d_in[2];
    const float* W1    = (const float*)d_in[3];
    const float* b1    = (const float*)d_in[4];
    const float* gamma = (const float*)d_in[5];
    const float* beta  = (const float*)d_in[6];
    const float* Wl    = (const float*)d_in[7];
    const float* bl    = (const float*)d_in[8];
    const float* W2    = (const float*)d_in[9];
    const float* b2    = (const float*)d_in[10];
    float* out = (float*)d_out;

    int n = in_sizes[0] / F_IN;   // 100000
    int e = in_sizes[1];          // 3200000
    int nbkt = (n + RB - 1) >> RB_BITS;   // 391
    int nAlign = (n + 15) & ~15;
    int nG = nbkt * RB;                                      // ordered-node slots
    size_t bktB = (size_t)nbkt << CAPB_BITS;                 // fixed-capacity entries (temp & csr)
    size_t hTileB = (size_t)nAlign * H * 4;                  // 6.4 MB
    size_t unionB = bktB * 4;                                // temp (25.6 MB)
    if (unionB < 2 * hTileB) unionB = 2 * hTileB;            // also holds hbuf+agg2 later

    char* wsb = (char*)d_ws;
    int*    csr      = (int*)wsb;      wsb += (bktB + 64) * 4;
    char*   uni      = wsb;            wsb += unionB;
    int*    temp     = (int*)uni;                  // alive: k_bin .. k_sort
    float*  hbuf     = (float*)uni;                // alive: k_gather1 .. k_hops
    float*  agg2     = (float*)(uni + hTileB);     // alive: k_gather2 .. k_final
    int*    ostart   = (int*)wsb;      wsb += (size_t)(nG + 16) * 4;
    int*    oend     = (int*)wsb;      wsb += (size_t)(nG + 16) * 4;
    int*    onode    = (int*)wsb;      wsb += (size_t)(nG + 16) * 4;
    float*  dinv     = (float*)wsb;    wsb += (size_t)nAlign * 4;
    int*    gcur     = (int*)wsb;      wsb += NBKT_MAX * 4;
    float*  stats    = (float*)wsb;    wsb += 64 * 4;
    __half* h1h      = (__half*)wsb;   wsb += (size_t)(nAlign + NDUMMY + 16) * H * 2;
    __half* hh       = (__half*)wsb;   wsb += (size_t)(nAlign + NDUMMY + 16) * H * 2;

    k_zero<<<64, 256, 0, stream>>>(gcur, stats, h1h, hh, n);
    k_bin<<<(e + BIN_CHUNK - 1) / BIN_CHUNK, 512, 0, stream>>>(src, dst, gcur, temp, e);
    k_sort<<<nbkt, 256, 0, stream>>>(gcur, temp, csr, ostart, oend, onode, dinv, n);
    k_mm1<<<(n + 15) / 16, 256, 0, stream>>>(x, W1, dinv, h1h, n);
    k_gather1<<<nbkt * 4, 256, 0, stream>>>(ostart, oend, onode, csr, h1h, dinv, b1, hbuf, stats, n);
    k_bncoef<<<1, 16, 0, stream>>>(stats, gamma, beta, (float)n);
    k_hops<<<(n + 255) / 256, 256, 0, stream>>>(hbuf, hh, stats, Wl, bl, dinv, n);
    k_gather2<<<nbkt * 4, 256, 0, stream>>>(ostart, oend, onode, csr, hh, dinv, agg2, n);
    k_final<<<(n + 255) / 256, 256, 0, stream>>>(agg2, W2, b2, out, n);
}

// Round 7
// 266.020 us; speedup vs baseline: 1.4129x; 1.0066x over previous
//
#include <hip/hip_runtime.h>
#include <hip/hip_fp16.h>
#include <math.h>

#define F_IN 128
#define H 16
#define C 40
#define K_HOPS 10
#define ALPHA 0.1f
#define BN_EPS 1e-5f

#define RB 256          // nodes per bucket
#define RB_BITS 8
#define NBKT_MAX 512    // ceil(100000/256)=391
#define SRC_MASK 0x1FFFF
#define PADQ 32         // node segment padded to multiple of 32 entries
#define NDUMMY 2048     // dummy zero rows spread over L2
#define CAPB_BITS 14    // fixed per-bucket capacity for temp AND csr (16384 entries)
#define CAPB (1 << CAPB_BITS)
#define STAGE_CAP 14336 // ints (56 KB) LDS staging for csr scatter

typedef int v4i __attribute__((ext_vector_type(4)));

// ---------------- zero: gcur = bucket bases, stats=0, dummy rows of both tables = 0 ----------------
__global__ void k_zero(int* __restrict__ gcur, float* __restrict__ stats,
                       __half* __restrict__ h1h, __half* __restrict__ hh, int n) {
    int id = blockIdx.x * blockDim.x + threadIdx.x;
    if (id < NBKT_MAX) gcur[id] = id << CAPB_BITS;
    if (id < 32) stats[id] = 0.0f;
    int* z1 = (int*)(h1h + (size_t)n * H);
    int* z2 = (int*)(hh + (size_t)n * H);
    if (id < NDUMMY * H / 2) { z1[id] = 0; z2[id] = 0; }
}

// ---------------- bin edges: LDS counting sort per block -> dense run writes ----------------
#define BIN_CHUNK 4096
__global__ __launch_bounds__(512) void k_bin(const int* __restrict__ src,
                                             const int* __restrict__ dst,
                                             int* __restrict__ gcur,
                                             int* __restrict__ temp, int e) {
    __shared__ int hist[NBKT_MAX];
    __shared__ int cur[NBKT_MAX];
    __shared__ int gofs[NBKT_MAX];
    __shared__ int wsum[8];
    __shared__ int stageV[BIN_CHUNK];
    __shared__ int stageD[BIN_CHUNK];
    int t = threadIdx.x;
    hist[t] = 0;
    __syncthreads();
    int base = blockIdx.x * BIN_CHUNK;
    int cnt = e - base; if (cnt > BIN_CHUNK) cnt = BIN_CHUNK;
    const v4i* s4 = reinterpret_cast<const v4i*>(src + base);
    const v4i* d4 = reinterpret_cast<const v4i*>(dst + base);
    v4i sv[2], dv[2];
#pragma unroll
    for (int i = 0; i < 2; ++i) {
        int e0 = (t * 2 + i) * 4;
        if (e0 + 3 < cnt) { sv[i] = s4[t * 2 + i]; dv[i] = d4[t * 2 + i]; }
        else if (e0 < cnt) {
            int ts[4], td[4];
#pragma unroll
            for (int j = 0; j < 4; ++j) {
                int ei = e0 + j;
                ts[j] = (ei < cnt) ? src[base + ei] : 0;
                td[j] = (ei < cnt) ? dst[base + ei] : -1;
            }
            sv[i] = *reinterpret_cast<v4i*>(ts); dv[i] = *reinterpret_cast<v4i*>(td);
        } else { dv[i] = (v4i){-1, -1, -1, -1}; sv[i] = dv[i]; }
    }
#pragma unroll
    for (int i = 0; i < 2; ++i) {
        if (dv[i].x >= 0) atomicAdd(&hist[dv[i].x >> RB_BITS], 1);
        if (dv[i].y >= 0) atomicAdd(&hist[dv[i].y >> RB_BITS], 1);
        if (dv[i].z >= 0) atomicAdd(&hist[dv[i].z >> RB_BITS], 1);
        if (dv[i].w >= 0) atomicAdd(&hist[dv[i].w >> RB_BITS], 1);
    }
    __syncthreads();
    int v = hist[t];
    int lane = t & 63, wv = t >> 6;
    int s = v;
#pragma unroll
    for (int off = 1; off < 64; off <<= 1) { int u = __shfl_up(s, off); if (lane >= off) s += u; }
    if (lane == 63) wsum[wv] = s;
    __syncthreads();
    if (t < 8) {
        int x = wsum[t];
#pragma unroll
        for (int off = 1; off < 8; off <<= 1) { int u = __shfl_up(x, off); if (t >= off) x += u; }
        wsum[t] = x;
    }
    __syncthreads();
    int excl = s - v + (wv ? wsum[wv - 1] : 0);
    cur[t] = excl;
    int g = v ? atomicAdd(&gcur[t], v) : 0;
    gofs[t] = g - excl;
    __syncthreads();
#pragma unroll
    for (int i = 0; i < 2; ++i) {
        int ds[4] = { dv[i].x, dv[i].y, dv[i].z, dv[i].w };
        int ssx[4] = { sv[i].x, sv[i].y, sv[i].z, sv[i].w };
#pragma unroll
        for (int j = 0; j < 4; ++j) {
            int d = ds[j];
            if (d >= 0) {
                int b = d >> RB_BITS;
                int pos = atomicAdd(&cur[b], 1);
                stageV[pos] = ssx[j] | ((d & (RB - 1)) << 17);
                stageD[pos] = gofs[b];
            }
        }
    }
    __syncthreads();
    for (int i = t; i < cnt; i += 512)
        temp[stageD[i] + i] = stageV[i];
}

// ---------------- per-bucket counting sort -> padded CSR (LDS-staged scatter, int4 loads);
//                  deg->dinv; HEAVY-FIRST degree-sorted node order ----------------
__global__ __launch_bounds__(256) void k_sort(const int* __restrict__ gcur,
                                              const int* __restrict__ temp,
                                              int* __restrict__ csr,
                                              int* __restrict__ ostart,
                                              int* __restrict__ oend,
                                              int* __restrict__ onode,
                                              float* __restrict__ dinv, int n) {
    __shared__ int hist[RB];
    __shared__ int cur[RB];
    __shared__ int wsum[8];
    __shared__ int qh[64];
    __shared__ int qb[64];
    __shared__ int ptotS;
    __shared__ int stage[STAGE_CAP];
    int t = threadIdx.x;
    int bkt = blockIdx.x;
    int start = bkt << CAPB_BITS;
    int endi = gcur[bkt];
    int nv = endi - start;
    int n4 = nv >> 2;
    const v4i* t4 = reinterpret_cast<const v4i*>(temp + start);
    hist[t] = 0;
    if (t < 64) qh[t] = 0;
    __syncthreads();
    for (int k = t; k < n4; k += 256) {
        v4i v = t4[k];
        atomicAdd(&hist[v.x >> 17], 1);
        atomicAdd(&hist[v.y >> 17], 1);
        atomicAdd(&hist[v.z >> 17], 1);
        atomicAdd(&hist[v.w >> 17], 1);
    }
    for (int k = start + (n4 << 2) + t; k < endi; k += 256)
        atomicAdd(&hist[temp[k] >> 17], 1);
    __syncthreads();
    int node = (bkt << RB_BITS) + t;
    int h = hist[t];
    int p = (h + PADQ - 1) & ~(PADQ - 1);
    bool va = (node < n);
    if (va) dinv[node] = rsqrtf((float)(h + 1));
    int lane = t & 63, wv = t >> 6;
    int s = p;
#pragma unroll
    for (int off = 1; off < 64; off <<= 1) { int u = __shfl_up(s, off); if (lane >= off) s += u; }
    if (lane == 63) wsum[wv] = s;
    __syncthreads();
    if (t < 4) {
        int x = wsum[t];
#pragma unroll
        for (int off = 1; off < 4; off <<= 1) { int u = __shfl_up(x, off); if (t >= off) x += u; }
        wsum[t] = x;
        if (t == 3) ptotS = x;
    }
    __syncthreads();
    int pexcl = s - p + (wv ? wsum[wv - 1] : 0);
    int s0 = start + pexcl;
    int q = 63 - min(p >> 5, 63);
    int r = atomicAdd(&qh[q], 1);
    __syncthreads();
    int ptotal = ptotS;
    if (t == 0) {
        int run = 0;
        for (int i = 0; i < 64; ++i) { qb[i] = run; run += qh[i]; }
    }
    __syncthreads();
    int ga = (bkt << RB_BITS) + qb[q] + r;
    ostart[ga] = s0; oend[ga] = s0 + p; onode[ga] = va ? node : -1;

    if (ptotal <= STAGE_CAP) {
        cur[t] = pexcl;
        for (int i = t; i < ptotal; i += 256) stage[i] = -1;
        __syncthreads();
        for (int k = t; k < n4; k += 256) {
            v4i v = t4[k];
            int p0 = atomicAdd(&cur[v.x >> 17], 1); stage[p0] = v.x & SRC_MASK;
            int p1 = atomicAdd(&cur[v.y >> 17], 1); stage[p1] = v.y & SRC_MASK;
            int p2 = atomicAdd(&cur[v.z >> 17], 1); stage[p2] = v.z & SRC_MASK;
            int p3 = atomicAdd(&cur[v.w >> 17], 1); stage[p3] = v.w & SRC_MASK;
        }
        for (int k = start + (n4 << 2) + t; k < endi; k += 256) {
            int v = temp[k];
            int pos = atomicAdd(&cur[v >> 17], 1);
            stage[pos] = v & SRC_MASK;
        }
        __syncthreads();
        for (int i = t * 4; i < ptotal; i += 1024) {
            v4i v = *reinterpret_cast<const v4i*>(&stage[i]);
            int gi = start + i;
            v.x = (v.x < 0) ? n + ((gi + 0) & (NDUMMY - 1)) : v.x;
            v.y = (v.y < 0) ? n + ((gi + 1) & (NDUMMY - 1)) : v.y;
            v.z = (v.z < 0) ? n + ((gi + 2) & (NDUMMY - 1)) : v.z;
            v.w = (v.w < 0) ? n + ((gi + 3) & (NDUMMY - 1)) : v.w;
            *reinterpret_cast<v4i*>(&csr[gi]) = v;
        }
    } else {
        cur[t] = s0;
        __syncthreads();
        for (int k = start + t; k < endi; k += 256) {
            int v = temp[k];
            int pos = atomicAdd(&cur[v >> 17], 1);
            csr[pos] = v & SRC_MASK;
        }
        __syncthreads();
        for (int i = s0 + h; i < s0 + p; ++i) csr[i] = n + (i & (NDUMMY - 1));
    }
}

// ---------------- h1' = dinv .* (x @ W1) -> fp16 table ----------------
__global__ __launch_bounds__(256) void k_mm1(const float* __restrict__ x,
                                             const float* __restrict__ W1,
                                             const float* __restrict__ dinv,
                                             __half* __restrict__ h1h, int n) {
    __shared__ __align__(16) float xs[16 * 132];
    __shared__ __align__(16) float ws[128 * 16];
    int t = threadIdx.x;
    int node0 = blockIdx.x * 16;
    const float4* x4 = reinterpret_cast<const float4*>(x);
    const float4* w4 = reinterpret_cast<const float4*>(W1);
#pragma unroll
    for (int r = 0; r < 2; ++r) {
        int f = t + r * 256;
        int nl = f >> 5, k4 = f & 31;
        int nn = node0 + nl; if (nn >= n) nn = n - 1;
        *reinterpret_cast<float4*>(&xs[nl * 132 + k4 * 4]) = x4[(size_t)nn * 32 + k4];
        *reinterpret_cast<float4*>(&ws[f * 4]) = w4[f];
    }
    __syncthreads();
    int nl = t >> 4, j = t & 15;
    float acc = 0.0f;
#pragma unroll 8
    for (int k = 0; k < 128; ++k)
        acc = fmaf(xs[nl * 132 + k], ws[k * 16 + j], acc);
    int node = node0 + nl;
    if (node < n) h1h[(size_t)node * H + j] = __float2half(acc * dinv[node]);
}

__device__ __forceinline__ void acc8(float* a, int4 gv) {
    const __half2* h = reinterpret_cast<const __half2*>(&gv);
    float2 f0 = __half22float2(h[0]);
    float2 f1 = __half22float2(h[1]);
    float2 f2 = __half22float2(h[2]);
    float2 f3 = __half22float2(h[3]);
    a[0] += f0.x; a[1] += f0.y; a[2] += f1.x; a[3] += f1.y;
    a[4] += f2.x; a[5] += f2.y; a[6] += f3.x; a[7] += f3.y;
}

// ---------------- gather conv1: 4 lanes/node, 16 gathers in flight/lane;
//                  heavy-first order; + bias + ReLU + BN stats ----------------
__global__ __launch_bounds__(256) void k_gather1(const int* __restrict__ ostart,
                                                 const int* __restrict__ oend,
                                                 const int* __restrict__ onode,
                                                 const int* __restrict__ csr,
                                                 const __half* __restrict__ h1h,
                                                 const float* __restrict__ dinv,
                                                 const float* __restrict__ b1,
                                                 float* __restrict__ hout,
                                                 float* __restrict__ stats, int n) {
    __shared__ float sm[32];
    __shared__ float b1s[16];
    int t = threadIdx.x;
    if (t < 32) sm[t] = 0.0f;
    if (t < 16) b1s[t] = b1[t];
    __syncthreads();
    int idx = blockIdx.x * 256 + t;
    int g = idx >> 2;
    int L = idx & 3, p = L >> 1, jj = L & 1;
    int node = __builtin_nontemporal_load(onode + g);
    float a[8];
#pragma unroll
    for (int k = 0; k < 8; ++k) a[k] = 0.0f;
    const int4* tab = reinterpret_cast<const int4*>(h1h);
    if (node >= 0) {
        int c  = (__builtin_nontemporal_load(ostart + g) >> 2) + (p << 2);
        int ce = __builtin_nontemporal_load(oend + g) >> 2;
        const v4i* csr4 = reinterpret_cast<const v4i*>(csr);
        for (; c < ce; c += 8) {
            v4i e0 = __builtin_nontemporal_load(csr4 + c);
            v4i e1 = __builtin_nontemporal_load(csr4 + c + 1);
            v4i e2 = __builtin_nontemporal_load(csr4 + c + 2);
            v4i e3 = __builtin_nontemporal_load(csr4 + c + 3);
            int4 g0  = tab[(size_t)e0.x * 2 + jj];
            int4 g1  = tab[(size_t)e0.y * 2 + jj];
            int4 g2  = tab[(size_t)e0.z * 2 + jj];
            int4 g3  = tab[(size_t)e0.w * 2 + jj];
            int4 g4  = tab[(size_t)e1.x * 2 + jj];
            int4 g5  = tab[(size_t)e1.y * 2 + jj];
            int4 g6  = tab[(size_t)e1.z * 2 + jj];
            int4 g7  = tab[(size_t)e1.w * 2 + jj];
            int4 g8  = tab[(size_t)e2.x * 2 + jj];
            int4 g9  = tab[(size_t)e2.y * 2 + jj];
            int4 g10 = tab[(size_t)e2.z * 2 + jj];
            int4 g11 = tab[(size_t)e2.w * 2 + jj];
            int4 g12 = tab[(size_t)e3.x * 2 + jj];
            int4 g13 = tab[(size_t)e3.y * 2 + jj];
            int4 g14 = tab[(size_t)e3.z * 2 + jj];
            int4 g15 = tab[(size_t)e3.w * 2 + jj];
            acc8(a, g0);  acc8(a, g1);  acc8(a, g2);  acc8(a, g3);
            acc8(a, g4);  acc8(a, g5);  acc8(a, g6);  acc8(a, g7);
            acc8(a, g8);  acc8(a, g9);  acc8(a, g10); acc8(a, g11);
            acc8(a, g12); acc8(a, g13); acc8(a, g14); acc8(a, g15);
        }
    }
#pragma unroll
    for (int k = 0; k < 8; ++k) a[k] += __shfl_xor(a[k], 2);
    float din = 0.0f;
    int4 sv = make_int4(0, 0, 0, 0);
    if (node >= 0) {
        din = dinv[node];
        sv = tab[(size_t)node * 2 + jj];
    }
    float v[8];
    {
        const __half2* h = reinterpret_cast<const __half2*>(&sv);
        float2 f0 = __half22float2(h[0]), f1 = __half22float2(h[1]);
        float2 f2 = __half22float2(h[2]), f3 = __half22float2(h[3]);
        float s8[8] = { f0.x, f0.y, f1.x, f1.y, f2.x, f2.y, f3.x, f3.y };
        bool writer = (node >= 0) && (p == 0);
#pragma unroll
        for (int k = 0; k < 8; ++k) {
            float val = fmaxf(din * (a[k] + s8[k]) + b1s[jj * 8 + k], 0.0f);
            v[k] = writer ? val : 0.0f;
        }
        if (writer) {
            float4* o = reinterpret_cast<float4*>(hout + (size_t)node * H + jj * 8);
            o[0] = make_float4(v[0], v[1], v[2], v[3]);
            o[1] = make_float4(v[4], v[5], v[6], v[7]);
        }
    }
#pragma unroll
    for (int k = 0; k < 8; ++k) {
        float s1 = v[k], s2 = v[k] * v[k];
        s1 += __shfl_xor(s1, 2);  s2 += __shfl_xor(s2, 2);
        s1 += __shfl_xor(s1, 4);  s2 += __shfl_xor(s2, 4);
        s1 += __shfl_xor(s1, 8);  s2 += __shfl_xor(s2, 8);
        s1 += __shfl_xor(s1, 16); s2 += __shfl_xor(s2, 16);
        s1 += __shfl_xor(s1, 32); s2 += __shfl_xor(s2, 32);
        if ((t & 63) < 2) {
            atomicAdd(&sm[jj * 8 + k], s1);
            atomicAdd(&sm[16 + jj * 8 + k], s2);
        }
    }
    __syncthreads();
    if (t < 32) atomicAdd(&stats[t], sm[t]);
}

// ---------------- BN(coef inline) apply + K_HOPS residual blocks -> scaled fp16 table ----------------
__global__ __launch_bounds__(256) void k_hops(const float* __restrict__ h,
                                              __half* __restrict__ hh,
                                              const float* __restrict__ stats,
                                              const float* __restrict__ gamma,
                                              const float* __restrict__ beta,
                                              const float* __restrict__ Wl,
                                              const float* __restrict__ bl,
                                              const float* __restrict__ dinv, int n, float nf) {
    __shared__ float wl[256], bls[16], av[16], cv[16];
    int t = threadIdx.x;
    wl[t] = Wl[(t & 15) * 16 + (t >> 4)];
    if (t < 16) {
        bls[t] = bl[t];
        float mean = stats[t] / nf;
        float var = stats[16 + t] / nf - mean * mean;
        float aa = gamma[t] * rsqrtf(var + BN_EPS);
        av[t] = aa;
        cv[t] = beta[t] - mean * aa;
    }
    __syncthreads();
    int node = blockIdx.x * 256 + t;
    if (node >= n) return;
    float hr[16];
    {
        const float4* hp = reinterpret_cast<const float4*>(h + (size_t)node * H);
        float4 v0 = hp[0], v1 = hp[1], v2 = hp[2], v3 = hp[3];
        hr[0] = v0.x; hr[1] = v0.y; hr[2] = v0.z; hr[3] = v0.w;
        hr[4] = v1.x; hr[5] = v1.y; hr[6] = v1.z; hr[7] = v1.w;
        hr[8] = v2.x; hr[9] = v2.y; hr[10] = v2.z; hr[11] = v2.w;
        hr[12] = v3.x; hr[13] = v3.y; hr[14] = v3.z; hr[15] = v3.w;
    }
#pragma unroll
    for (int j = 0; j < 16; ++j) hr[j] = hr[j] * av[j] + cv[j];
    for (int it = 0; it < K_HOPS; ++it) {
        float tmp[16];
#pragma unroll
        for (int j = 0; j < 16; ++j) {
            float a = bls[j];
#pragma unroll
            for (int k = 0; k < 16; ++k) a = fmaf(hr[k], wl[j * 16 + k], a);
            tmp[j] = fmaxf(a, 0.0f);
        }
#pragma unroll
        for (int j = 0; j < 16; ++j) hr[j] = ALPHA * tmp[j] + (1.0f - ALPHA) * hr[j];
    }
    {
        float din = dinv[node];
        __half2 ph[8];
#pragma unroll
        for (int i = 0; i < 8; ++i)
            ph[i] = __floats2half2_rn(hr[2 * i] * din, hr[2 * i + 1] * din);
        int4* hp = reinterpret_cast<int4*>(hh + (size_t)node * H);
        hp[0] = *reinterpret_cast<int4*>(&ph[0]);
        hp[1] = *reinterpret_cast<int4*>(&ph[4]);
    }
}

// ---------------- fused gather conv2 + final GEMV + log_softmax ----------------
__global__ __launch_bounds__(256) void k_g2f(const int* __restrict__ ostart,
                                             const int* __restrict__ oend,
                                             const int* __restrict__ onode,
                                             const int* __restrict__ csr,
                                             const __half* __restrict__ hh,
                                             const float* __restrict__ dinv,
                                             const float* __restrict__ W2,
                                             const float* __restrict__ b2,
                                             float* __restrict__ out, int n) {
    __shared__ __align__(16) float w2t[40 * 20];   // transposed, stride 20 (bank-safe, 16B aligned)
    __shared__ float b2s[40];
    __shared__ __align__(16) float feat[64 * 20];  // per-node 16 feats, stride 20
    int t = threadIdx.x;
    for (int i = t; i < 640; i += 256) w2t[(i >> 4) * 20 + (i & 15)] = W2[(i & 15) * 40 + (i >> 4)];
    if (t < 40) b2s[t] = b2[t];
    int idx = blockIdx.x * 256 + t;
    int g = idx >> 2;
    int L = idx & 3, p = L >> 1, jj = L & 1;
    int node = __builtin_nontemporal_load(onode + g);
    float a[8];
#pragma unroll
    for (int k = 0; k < 8; ++k) a[k] = 0.0f;
    const int4* tab = reinterpret_cast<const int4*>(hh);
    if (node >= 0) {
        int c  = (__builtin_nontemporal_load(ostart + g) >> 2) + (p << 2);
        int ce = __builtin_nontemporal_load(oend + g) >> 2;
        const v4i* csr4 = reinterpret_cast<const v4i*>(csr);
        for (; c < ce; c += 8) {
            v4i e0 = __builtin_nontemporal_load(csr4 + c);
            v4i e1 = __builtin_nontemporal_load(csr4 + c + 1);
            v4i e2 = __builtin_nontemporal_load(csr4 + c + 2);
            v4i e3 = __builtin_nontemporal_load(csr4 + c + 3);
            int4 g0  = tab[(size_t)e0.x * 2 + jj];
            int4 g1  = tab[(size_t)e0.y * 2 + jj];
            int4 g2  = tab[(size_t)e0.z * 2 + jj];
            int4 g3  = tab[(size_t)e0.w * 2 + jj];
            int4 g4  = tab[(size_t)e1.x * 2 + jj];
            int4 g5  = tab[(size_t)e1.y * 2 + jj];
            int4 g6  = tab[(size_t)e1.z * 2 + jj];
            int4 g7  = tab[(size_t)e1.w * 2 + jj];
            int4 g8  = tab[(size_t)e2.x * 2 + jj];
            int4 g9  = tab[(size_t)e2.y * 2 + jj];
            int4 g10 = tab[(size_t)e2.z * 2 + jj];
            int4 g11 = tab[(size_t)e2.w * 2 + jj];
            int4 g12 = tab[(size_t)e3.x * 2 + jj];
            int4 g13 = tab[(size_t)e3.y * 2 + jj];
            int4 g14 = tab[(size_t)e3.z * 2 + jj];
            int4 g15 = tab[(size_t)e3.w * 2 + jj];
            acc8(a, g0);  acc8(a, g1);  acc8(a, g2);  acc8(a, g3);
            acc8(a, g4);  acc8(a, g5);  acc8(a, g6);  acc8(a, g7);
            acc8(a, g8);  acc8(a, g9);  acc8(a, g10); acc8(a, g11);
            acc8(a, g12); acc8(a, g13); acc8(a, g14); acc8(a, g15);
        }
    }
#pragma unroll
    for (int k = 0; k < 8; ++k) a[k] += __shfl_xor(a[k], 2);
    int nl = t >> 2;
    if (node >= 0 && p == 0) {
        float din = dinv[node];
        int4 sv = tab[(size_t)node * 2 + jj];
        const __half2* h = reinterpret_cast<const __half2*>(&sv);
        float2 f0 = __half22float2(h[0]), f1 = __half22float2(h[1]);
        float2 f2 = __half22float2(h[2]), f3 = __half22float2(h[3]);
        float s8[8] = { f0.x, f0.y, f1.x, f1.y, f2.x, f2.y, f3.x, f3.y };
        float v[8];
#pragma unroll
        for (int k = 0; k < 8; ++k) v[k] = din * (a[k] + s8[k]);
        *reinterpret_cast<float4*>(&feat[nl * 20 + jj * 8])     = make_float4(v[0], v[1], v[2], v[3]);
        *reinterpret_cast<float4*>(&feat[nl * 20 + jj * 8 + 4]) = make_float4(v[4], v[5], v[6], v[7]);
    }
    __syncthreads();
    // GEMV: 4 lanes/node x 10 classes each, then group log_softmax
    float4 f0 = *reinterpret_cast<const float4*>(&feat[nl * 20]);
    float4 f1 = *reinterpret_cast<const float4*>(&feat[nl * 20 + 4]);
    float4 f2 = *reinterpret_cast<const float4*>(&feat[nl * 20 + 8]);
    float4 f3 = *reinterpret_cast<const float4*>(&feat[nl * 20 + 12]);
    int cb = (t & 3) * 10;
    float z[10];
#pragma unroll
    for (int j = 0; j < 10; ++j) {
        const float4* wr = reinterpret_cast<const float4*>(&w2t[(cb + j) * 20]);
        float4 w0 = wr[0], w1 = wr[1], w2v = wr[2], w3 = wr[3];
        float acc = b2s[cb + j];
        acc = fmaf(f0.x, w0.x, acc); acc = fmaf(f0.y, w0.y, acc);
        acc = fmaf(f0.z, w0.z, acc); acc = fmaf(f0.w, w0.w, acc);
        acc = fmaf(f1.x, w1.x, acc); acc = fmaf(f1.y, w1.y, acc);
        acc = fmaf(f1.z, w1.z, acc); acc = fmaf(f1.w, w1.w, acc);
        acc = fmaf(f2.x, w2v.x, acc); acc = fmaf(f2.y, w2v.y, acc);
        acc = fmaf(f2.z, w2v.z, acc); acc = fmaf(f2.w, w2v.w, acc);
        acc = fmaf(f3.x, w3.x, acc); acc = fmaf(f3.y, w3.y, acc);
        acc = fmaf(f3.z, w3.z, acc); acc = fmaf(f3.w, w3.w, acc);
        z[j] = acc;
    }
    float m = z[0];
#pragma unroll
    for (int j = 1; j < 10; ++j) m = fmaxf(m, z[j]);
    m = fmaxf(m, __shfl_xor(m, 1));
    m = fmaxf(m, __shfl_xor(m, 2));
    float s = 0.0f;
#pragma unroll
    for (int j = 0; j < 10; ++j) s += expf(z[j] - m);
    s += __shfl_xor(s, 1);
    s += __shfl_xor(s, 2);
    float lse = m + logf(s);
    if (node >= 0) {
        float2* o = reinterpret_cast<float2*>(out + (size_t)node * 40 + cb);
#pragma unroll
        for (int j = 0; j < 5; ++j)
            o[j] = make_float2(z[2 * j] - lse, z[2 * j + 1] - lse);
    }
}

extern "C" void kernel_launch(void* const* d_in, const int* in_sizes, int n_in,
                              void* d_out, int out_size, void* d_ws, size_t ws_size,
                              hipStream_t stream) {
    const float* x     = (const float*)d_in[0];
    const int*   src   = (const int*)d_in[1];
    const int*   dst   = (const int*)d_in[2];
    const float* W1    = (const float*)d_in[3];
    const float* b1    = (const float*)d_in[4];
    const float* gamma = (const float*)d_in[5];
    const float* beta  = (const float*)d_in[6];
    const float* Wl    = (const float*)d_in[7];
    const float* bl    = (const float*)d_in[8];
    const float* W2    = (const float*)d_in[9];
    const float* b2    = (const float*)d_in[10];
    float* out = (float*)d_out;

    int n = in_sizes[0] / F_IN;   // 100000
    int e = in_sizes[1];          // 3200000
    int nbkt = (n + RB - 1) >> RB_BITS;   // 391
    int nAlign = (n + 15) & ~15;
    int nG = nbkt * RB;                                      // ordered-node slots
    size_t bktB = (size_t)nbkt << CAPB_BITS;                 // fixed-capacity entries (temp & csr)
    size_t hTileB = (size_t)nAlign * H * 4;                  // 6.4 MB
    size_t unionB = bktB * 4;                                // temp (25.6 MB)
    if (unionB < hTileB) unionB = hTileB;                    // also holds hbuf later

    char* wsb = (char*)d_ws;
    int*    csr      = (int*)wsb;      wsb += (bktB + 64) * 4;
    char*   uni      = wsb;            wsb += unionB;
    int*    temp     = (int*)uni;                  // alive: k_bin .. k_sort
    float*  hbuf     = (float*)uni;                // alive: k_gather1 .. k_hops
    int*    ostart   = (int*)wsb;      wsb += (size_t)(nG + 16) * 4;
    int*    oend     = (int*)wsb;      wsb += (size_t)(nG + 16) * 4;
    int*    onode    = (int*)wsb;      wsb += (size_t)(nG + 16) * 4;
    float*  dinv     = (float*)wsb;    wsb += (size_t)nAlign * 4;
    int*    gcur     = (int*)wsb;      wsb += NBKT_MAX * 4;
    float*  stats    = (float*)wsb;    wsb += 64 * 4;
    __half* h1h      = (__half*)wsb;   wsb += (size_t)(nAlign + NDUMMY + 16) * H * 2;
    __half* hh       = (__half*)wsb;   wsb += (size_t)(nAlign + NDUMMY + 16) * H * 2;

    k_zero<<<64, 256, 0, stream>>>(gcur, stats, h1h, hh, n);
    k_bin<<<(e + BIN_CHUNK - 1) / BIN_CHUNK, 512, 0, stream>>>(src, dst, gcur, temp, e);
    k_sort<<<nbkt, 256, 0, stream>>>(gcur, temp, csr, ostart, oend, onode, dinv, n);
    k_mm1<<<(n + 15) / 16, 256, 0, stream>>>(x, W1, dinv, h1h, n);
    k_gather1<<<nbkt * 4, 256, 0, stream>>>(ostart, oend, onode, csr, h1h, dinv, b1, hbuf, stats, n);
    k_hops<<<(n + 255) / 256, 256, 0, stream>>>(hbuf, hh, stats, gamma, beta, Wl, bl, dinv, n, (float)n);
    k_g2f<<<nbkt * 4, 256, 0, stream>>>(ostart, oend, onode, csr, hh, dinv, W2, b2, out, n);
}

// Round 8
// 261.148 us; speedup vs baseline: 1.4392x; 1.0187x over previous
//
#include <hip/hip_runtime.h>
#include <hip/hip_fp16.h>
#include <math.h>

#define F_IN 128
#define H 16
#define C 40
#define K_HOPS 10
#define ALPHA 0.1f
#define BN_EPS 1e-5f

#define RB 256          // nodes per bucket
#define RB_BITS 8
#define NBKT_MAX 512    // ceil(100000/256)=391
#define SRC_MASK 0x1FFFF
#define PADQ 16         // node segment padded to multiple of 16 entries (one loop iter = 16 edges)
#define NDUMMY 2048     // dummy zero rows spread over L2
#define CAPB_BITS 14    // fixed per-bucket capacity for temp AND csr (16384 entries)
#define CAPB (1 << CAPB_BITS)
#define STAGE_CAP 14336 // ints (56 KB) LDS staging for csr scatter

typedef int v4i __attribute__((ext_vector_type(4)));

// ---------------- zero: gcur = bucket bases, stats=0, dummy rows of both tables = 0 ----------------
__global__ void k_zero(int* __restrict__ gcur, float* __restrict__ stats,
                       __half* __restrict__ h1h, __half* __restrict__ hh, int n) {
    int id = blockIdx.x * blockDim.x + threadIdx.x;
    if (id < NBKT_MAX) gcur[id] = id << CAPB_BITS;
    if (id < 32) stats[id] = 0.0f;
    int* z1 = (int*)(h1h + (size_t)n * H);
    int* z2 = (int*)(hh + (size_t)n * H);
    if (id < NDUMMY * H / 2) { z1[id] = 0; z2[id] = 0; }
}

// ---------------- bin edges: LDS counting sort per block -> dense run writes ----------------
#define BIN_CHUNK 4096
__global__ __launch_bounds__(512) void k_bin(const int* __restrict__ src,
                                             const int* __restrict__ dst,
                                             int* __restrict__ gcur,
                                             int* __restrict__ temp, int e) {
    __shared__ int hist[NBKT_MAX];
    __shared__ int cur[NBKT_MAX];
    __shared__ int gofs[NBKT_MAX];
    __shared__ int wsum[8];
    __shared__ int stageV[BIN_CHUNK];
    __shared__ int stageD[BIN_CHUNK];
    int t = threadIdx.x;
    hist[t] = 0;
    __syncthreads();
    int base = blockIdx.x * BIN_CHUNK;
    int cnt = e - base; if (cnt > BIN_CHUNK) cnt = BIN_CHUNK;
    const v4i* s4 = reinterpret_cast<const v4i*>(src + base);
    const v4i* d4 = reinterpret_cast<const v4i*>(dst + base);
    v4i sv[2], dv[2];
#pragma unroll
    for (int i = 0; i < 2; ++i) {
        int e0 = (t * 2 + i) * 4;
        if (e0 + 3 < cnt) { sv[i] = s4[t * 2 + i]; dv[i] = d4[t * 2 + i]; }
        else if (e0 < cnt) {
            int ts[4], td[4];
#pragma unroll
            for (int j = 0; j < 4; ++j) {
                int ei = e0 + j;
                ts[j] = (ei < cnt) ? src[base + ei] : 0;
                td[j] = (ei < cnt) ? dst[base + ei] : -1;
            }
            sv[i] = *reinterpret_cast<v4i*>(ts); dv[i] = *reinterpret_cast<v4i*>(td);
        } else { dv[i] = (v4i){-1, -1, -1, -1}; sv[i] = dv[i]; }
    }
#pragma unroll
    for (int i = 0; i < 2; ++i) {
        if (dv[i].x >= 0) atomicAdd(&hist[dv[i].x >> RB_BITS], 1);
        if (dv[i].y >= 0) atomicAdd(&hist[dv[i].y >> RB_BITS], 1);
        if (dv[i].z >= 0) atomicAdd(&hist[dv[i].z >> RB_BITS], 1);
        if (dv[i].w >= 0) atomicAdd(&hist[dv[i].w >> RB_BITS], 1);
    }
    __syncthreads();
    int v = hist[t];
    int lane = t & 63, wv = t >> 6;
    int s = v;
#pragma unroll
    for (int off = 1; off < 64; off <<= 1) { int u = __shfl_up(s, off); if (lane >= off) s += u; }
    if (lane == 63) wsum[wv] = s;
    __syncthreads();
    if (t < 8) {
        int x = wsum[t];
#pragma unroll
        for (int off = 1; off < 8; off <<= 1) { int u = __shfl_up(x, off); if (t >= off) x += u; }
        wsum[t] = x;
    }
    __syncthreads();
    int excl = s - v + (wv ? wsum[wv - 1] : 0);
    cur[t] = excl;
    int g = v ? atomicAdd(&gcur[t], v) : 0;
    gofs[t] = g - excl;
    __syncthreads();
#pragma unroll
    for (int i = 0; i < 2; ++i) {
        int ds[4] = { dv[i].x, dv[i].y, dv[i].z, dv[i].w };
        int ssx[4] = { sv[i].x, sv[i].y, sv[i].z, sv[i].w };
#pragma unroll
        for (int j = 0; j < 4; ++j) {
            int d = ds[j];
            if (d >= 0) {
                int b = d >> RB_BITS;
                int pos = atomicAdd(&cur[b], 1);
                stageV[pos] = ssx[j] | ((d & (RB - 1)) << 17);
                stageD[pos] = gofs[b];
            }
        }
    }
    __syncthreads();
    for (int i = t; i < cnt; i += 512)
        temp[stageD[i] + i] = stageV[i];
}

// ---------------- per-bucket counting sort -> padded CSR (LDS-staged scatter);
//                  512 threads; deg->dinv; HEAVY-FIRST order ----------------
__global__ __launch_bounds__(512) void k_sort(const int* __restrict__ gcur,
                                              const int* __restrict__ temp,
                                              int* __restrict__ csr,
                                              int* __restrict__ ostart,
                                              int* __restrict__ oend,
                                              int* __restrict__ onode,
                                              float* __restrict__ dinv, int n) {
    __shared__ int hist[RB];
    __shared__ int cur[RB];
    __shared__ int wsum[4];
    __shared__ int qh[64];
    __shared__ int qb[64];
    __shared__ int ptotS;
    __shared__ int stage[STAGE_CAP];
    int t = threadIdx.x;
    int bkt = blockIdx.x;
    int start = bkt << CAPB_BITS;
    int endi = gcur[bkt];
    int nv = endi - start;
    int n4 = nv >> 2;
    const v4i* t4 = reinterpret_cast<const v4i*>(temp + start);
    if (t < RB) hist[t] = 0;
    if (t < 64) qh[t] = 0;
    __syncthreads();
    for (int k = t; k < n4; k += 512) {
        v4i v = t4[k];
        atomicAdd(&hist[v.x >> 17], 1);
        atomicAdd(&hist[v.y >> 17], 1);
        atomicAdd(&hist[v.z >> 17], 1);
        atomicAdd(&hist[v.w >> 17], 1);
    }
    for (int k = start + (n4 << 2) + t; k < endi; k += 512)
        atomicAdd(&hist[temp[k] >> 17], 1);
    __syncthreads();
    int node = (bkt << RB_BITS) + t;
    int h = 0, pv = 0;
    bool va = false;
    if (t < RB) {
        h = hist[t];
        pv = (h + PADQ - 1) & ~(PADQ - 1);
        va = (node < n);
        if (va) dinv[node] = rsqrtf((float)(h + 1));
    }
    int lane = t & 63, wv = t >> 6;
    int s = pv;
#pragma unroll
    for (int off = 1; off < 64; off <<= 1) { int u = __shfl_up(s, off); if (lane >= off) s += u; }
    if (lane == 63 && wv < 4) wsum[wv] = s;
    __syncthreads();
    if (t < 4) {
        int x = wsum[t];
#pragma unroll
        for (int off = 1; off < 4; off <<= 1) { int u = __shfl_up(x, off); if (t >= off) x += u; }
        wsum[t] = x;
        if (t == 3) ptotS = x;
    }
    __syncthreads();
    int pexcl = 0, s0 = 0, q = 63, r = 0;
    if (t < RB) {
        pexcl = s - pv + (wv ? wsum[wv - 1] : 0);
        s0 = start + pexcl;
        q = 63 - min(pv >> 4, 63);
        r = atomicAdd(&qh[q], 1);
    }
    __syncthreads();
    int ptotal = ptotS;
    if (t == 0) {
        int run = 0;
        for (int i = 0; i < 64; ++i) { qb[i] = run; run += qh[i]; }
    }
    __syncthreads();
    if (t < RB) {
        int ga = (bkt << RB_BITS) + qb[q] + r;
        ostart[ga] = s0; oend[ga] = s0 + pv; onode[ga] = va ? node : -1;
    }
    if (ptotal <= STAGE_CAP) {
        if (t < RB) cur[t] = pexcl;
        for (int i = t; i < ptotal; i += 512) stage[i] = -1;
        __syncthreads();
        for (int k = t; k < n4; k += 512) {
            v4i v = t4[k];
            int p0 = atomicAdd(&cur[v.x >> 17], 1); stage[p0] = v.x & SRC_MASK;
            int p1 = atomicAdd(&cur[v.y >> 17], 1); stage[p1] = v.y & SRC_MASK;
            int p2 = atomicAdd(&cur[v.z >> 17], 1); stage[p2] = v.z & SRC_MASK;
            int p3 = atomicAdd(&cur[v.w >> 17], 1); stage[p3] = v.w & SRC_MASK;
        }
        for (int k = start + (n4 << 2) + t; k < endi; k += 512) {
            int v = temp[k];
            int pos = atomicAdd(&cur[v >> 17], 1);
            stage[pos] = v & SRC_MASK;
        }
        __syncthreads();
        for (int i = t * 4; i < ptotal; i += 2048) {
            v4i v = *reinterpret_cast<const v4i*>(&stage[i]);
            int gi = start + i;
            v.x = (v.x < 0) ? n + ((gi + 0) & (NDUMMY - 1)) : v.x;
            v.y = (v.y < 0) ? n + ((gi + 1) & (NDUMMY - 1)) : v.y;
            v.z = (v.z < 0) ? n + ((gi + 2) & (NDUMMY - 1)) : v.z;
            v.w = (v.w < 0) ? n + ((gi + 3) & (NDUMMY - 1)) : v.w;
            *reinterpret_cast<v4i*>(&csr[gi]) = v;
        }
    } else {
        if (t < RB) cur[t] = s0;
        __syncthreads();
        for (int k = start + t; k < endi; k += 512) {
            int v = temp[k];
            int pos = atomicAdd(&cur[v >> 17], 1);
            csr[pos] = v & SRC_MASK;
        }
        __syncthreads();
        if (t < RB) for (int i = s0 + h; i < s0 + pv; ++i) csr[i] = n + (i & (NDUMMY - 1));
    }
}

// ---------------- h1' = dinv .* (x @ W1) -> fp16 table ----------------
__global__ __launch_bounds__(256) void k_mm1(const float* __restrict__ x,
                                             const float* __restrict__ W1,
                                             const float* __restrict__ dinv,
                                             __half* __restrict__ h1h, int n) {
    __shared__ __align__(16) float xs[16 * 132];
    __shared__ __align__(16) float ws[128 * 16];
    int t = threadIdx.x;
    int node0 = blockIdx.x * 16;
    const float4* x4 = reinterpret_cast<const float4*>(x);
    const float4* w4 = reinterpret_cast<const float4*>(W1);
#pragma unroll
    for (int r = 0; r < 2; ++r) {
        int f = t + r * 256;
        int nl = f >> 5, k4 = f & 31;
        int nn = node0 + nl; if (nn >= n) nn = n - 1;
        *reinterpret_cast<float4*>(&xs[nl * 132 + k4 * 4]) = x4[(size_t)nn * 32 + k4];
        *reinterpret_cast<float4*>(&ws[f * 4]) = w4[f];
    }
    __syncthreads();
    int nl = t >> 4, j = t & 15;
    float acc = 0.0f;
#pragma unroll 8
    for (int k = 0; k < 128; ++k)
        acc = fmaf(xs[nl * 132 + k], ws[k * 16 + j], acc);
    int node = node0 + nl;
    if (node < n) h1h[(size_t)node * H + j] = __float2half(acc * dinv[node]);
}

__device__ __forceinline__ void acc8(float* a, int4 gv) {
    const __half2* h = reinterpret_cast<const __half2*>(&gv);
    float2 f0 = __half22float2(h[0]);
    float2 f1 = __half22float2(h[1]);
    float2 f2 = __half22float2(h[2]);
    float2 f3 = __half22float2(h[3]);
    a[0] += f0.x; a[1] += f0.y; a[2] += f1.x; a[3] += f1.y;
    a[4] += f2.x; a[5] += f2.y; a[6] += f3.x; a[7] += f3.y;
}

// ---------------- gather conv1: 4 lanes/node (2 pairs), 8 gathers/lane in flight;
//                  heavy-first order; + bias + ReLU + BN stats ----------------
__global__ __launch_bounds__(256) void k_gather1(const int* __restrict__ ostart,
                                                 const int* __restrict__ oend,
                                                 const int* __restrict__ onode,
                                                 const int* __restrict__ csr,
                                                 const __half* __restrict__ h1h,
                                                 const float* __restrict__ dinv,
                                                 const float* __restrict__ b1,
                                                 float* __restrict__ hout,
                                                 float* __restrict__ stats, int n) {
    __shared__ float sm[32];
    __shared__ float b1s[16];
    int t = threadIdx.x;
    if (t < 32) sm[t] = 0.0f;
    if (t < 16) b1s[t] = b1[t];
    __syncthreads();
    int idx = blockIdx.x * 256 + t;
    int g = idx >> 2;
    int L = idx & 3, p = L >> 1, jj = L & 1;
    int node = __builtin_nontemporal_load(onode + g);
    float a[8];
#pragma unroll
    for (int k = 0; k < 8; ++k) a[k] = 0.0f;
    const int4* tab = reinterpret_cast<const int4*>(h1h);
    if (node >= 0) {
        int c  = (__builtin_nontemporal_load(ostart + g) >> 2) + (p << 1);
        int ce = __builtin_nontemporal_load(oend + g) >> 2;
        const v4i* csr4 = reinterpret_cast<const v4i*>(csr);
        for (; c < ce; c += 4) {
            v4i e0 = __builtin_nontemporal_load(csr4 + c);
            v4i e1 = __builtin_nontemporal_load(csr4 + c + 1);
            int4 g0 = tab[(size_t)e0.x * 2 + jj];
            int4 g1 = tab[(size_t)e0.y * 2 + jj];
            int4 g2 = tab[(size_t)e0.z * 2 + jj];
            int4 g3 = tab[(size_t)e0.w * 2 + jj];
            int4 g4 = tab[(size_t)e1.x * 2 + jj];
            int4 g5 = tab[(size_t)e1.y * 2 + jj];
            int4 g6 = tab[(size_t)e1.z * 2 + jj];
            int4 g7 = tab[(size_t)e1.w * 2 + jj];
            acc8(a, g0); acc8(a, g1); acc8(a, g2); acc8(a, g3);
            acc8(a, g4); acc8(a, g5); acc8(a, g6); acc8(a, g7);
        }
    }
#pragma unroll
    for (int k = 0; k < 8; ++k) a[k] += __shfl_xor(a[k], 2);
    float din = 0.0f;
    int4 sv = make_int4(0, 0, 0, 0);
    if (node >= 0) {
        din = dinv[node];
        sv = tab[(size_t)node * 2 + jj];
    }
    float v[8];
    {
        const __half2* h = reinterpret_cast<const __half2*>(&sv);
        float2 f0 = __half22float2(h[0]), f1 = __half22float2(h[1]);
        float2 f2 = __half22float2(h[2]), f3 = __half22float2(h[3]);
        float s8[8] = { f0.x, f0.y, f1.x, f1.y, f2.x, f2.y, f3.x, f3.y };
        bool writer = (node >= 0) && (p == 0);
#pragma unroll
        for (int k = 0; k < 8; ++k) {
            float val = fmaxf(din * (a[k] + s8[k]) + b1s[jj * 8 + k], 0.0f);
            v[k] = writer ? val : 0.0f;
        }
        if (writer) {
            float4* o = reinterpret_cast<float4*>(hout + (size_t)node * H + jj * 8);
            o[0] = make_float4(v[0], v[1], v[2], v[3]);
            o[1] = make_float4(v[4], v[5], v[6], v[7]);
        }
    }
#pragma unroll
    for (int k = 0; k < 8; ++k) {
        float s1 = v[k], s2 = v[k] * v[k];
        s1 += __shfl_xor(s1, 2);  s2 += __shfl_xor(s2, 2);
        s1 += __shfl_xor(s1, 4);  s2 += __shfl_xor(s2, 4);
        s1 += __shfl_xor(s1, 8);  s2 += __shfl_xor(s2, 8);
        s1 += __shfl_xor(s1, 16); s2 += __shfl_xor(s2, 16);
        s1 += __shfl_xor(s1, 32); s2 += __shfl_xor(s2, 32);
        if ((t & 63) < 2) {
            atomicAdd(&sm[jj * 8 + k], s1);
            atomicAdd(&sm[16 + jj * 8 + k], s2);
        }
    }
    __syncthreads();
    if (t < 32) atomicAdd(&stats[t], sm[t]);
}

// ---------------- BN(coef inline) apply + K_HOPS residual blocks -> scaled fp16 table ----------------
__global__ __launch_bounds__(256) void k_hops(const float* __restrict__ h,
                                              __half* __restrict__ hh,
                                              const float* __restrict__ stats,
                                              const float* __restrict__ gamma,
                                              const float* __restrict__ beta,
                                              const float* __restrict__ Wl,
                                              const float* __restrict__ bl,
                                              const float* __restrict__ dinv, int n, float nf) {
    __shared__ float wl[256], bls[16], av[16], cv[16];
    int t = threadIdx.x;
    wl[t] = Wl[(t & 15) * 16 + (t >> 4)];
    if (t < 16) {
        bls[t] = bl[t];
        float mean = stats[t] / nf;
        float var = stats[16 + t] / nf - mean * mean;
        float aa = gamma[t] * rsqrtf(var + BN_EPS);
        av[t] = aa;
        cv[t] = beta[t] - mean * aa;
    }
    __syncthreads();
    int node = blockIdx.x * 256 + t;
    if (node >= n) return;
    float hr[16];
    {
        const float4* hp = reinterpret_cast<const float4*>(h + (size_t)node * H);
        float4 v0 = hp[0], v1 = hp[1], v2 = hp[2], v3 = hp[3];
        hr[0] = v0.x; hr[1] = v0.y; hr[2] = v0.z; hr[3] = v0.w;
        hr[4] = v1.x; hr[5] = v1.y; hr[6] = v1.z; hr[7] = v1.w;
        hr[8] = v2.x; hr[9] = v2.y; hr[10] = v2.z; hr[11] = v2.w;
        hr[12] = v3.x; hr[13] = v3.y; hr[14] = v3.z; hr[15] = v3.w;
    }
#pragma unroll
    for (int j = 0; j < 16; ++j) hr[j] = hr[j] * av[j] + cv[j];
    for (int it = 0; it < K_HOPS; ++it) {
        float tmp[16];
#pragma unroll
        for (int j = 0; j < 16; ++j) {
            float a = bls[j];
#pragma unroll
            for (int k = 0; k < 16; ++k) a = fmaf(hr[k], wl[j * 16 + k], a);
            tmp[j] = fmaxf(a, 0.0f);
        }
#pragma unroll
        for (int j = 0; j < 16; ++j) hr[j] = ALPHA * tmp[j] + (1.0f - ALPHA) * hr[j];
    }
    {
        float din = dinv[node];
        __half2 ph[8];
#pragma unroll
        for (int i = 0; i < 8; ++i)
            ph[i] = __floats2half2_rn(hr[2 * i] * din, hr[2 * i + 1] * din);
        int4* hp = reinterpret_cast<int4*>(hh + (size_t)node * H);
        hp[0] = *reinterpret_cast<int4*>(&ph[0]);
        hp[1] = *reinterpret_cast<int4*>(&ph[4]);
    }
}

// ---------------- fused gather conv2 + final GEMV + log_softmax ----------------
__global__ __launch_bounds__(256) void k_g2f(const int* __restrict__ ostart,
                                             const int* __restrict__ oend,
                                             const int* __restrict__ onode,
                                             const int* __restrict__ csr,
                                             const __half* __restrict__ hh,
                                             const float* __restrict__ dinv,
                                             const float* __restrict__ W2,
                                             const float* __restrict__ b2,
                                             float* __restrict__ out, int n) {
    __shared__ __align__(16) float w2t[40 * 20];
    __shared__ float b2s[40];
    __shared__ __align__(16) float feat[64 * 20];
    int t = threadIdx.x;
    for (int i = t; i < 640; i += 256) w2t[(i >> 4) * 20 + (i & 15)] = W2[(i & 15) * 40 + (i >> 4)];
    if (t < 40) b2s[t] = b2[t];
    int idx = blockIdx.x * 256 + t;
    int g = idx >> 2;
    int L = idx & 3, p = L >> 1, jj = L & 1;
    int node = __builtin_nontemporal_load(onode + g);
    float a[8];
#pragma unroll
    for (int k = 0; k < 8; ++k) a[k] = 0.0f;
    const int4* tab = reinterpret_cast<const int4*>(hh);
    if (node >= 0) {
        int c  = (__builtin_nontemporal_load(ostart + g) >> 2) + (p << 1);
        int ce = __builtin_nontemporal_load(oend + g) >> 2;
        const v4i* csr4 = reinterpret_cast<const v4i*>(csr);
        for (; c < ce; c += 4) {
            v4i e0 = __builtin_nontemporal_load(csr4 + c);
            v4i e1 = __builtin_nontemporal_load(csr4 + c + 1);
            int4 g0 = tab[(size_t)e0.x * 2 + jj];
            int4 g1 = tab[(size_t)e0.y * 2 + jj];
            int4 g2 = tab[(size_t)e0.z * 2 + jj];
            int4 g3 = tab[(size_t)e0.w * 2 + jj];
            int4 g4 = tab[(size_t)e1.x * 2 + jj];
            int4 g5 = tab[(size_t)e1.y * 2 + jj];
            int4 g6 = tab[(size_t)e1.z * 2 + jj];
            int4 g7 = tab[(size_t)e1.w * 2 + jj];
            acc8(a, g0); acc8(a, g1); acc8(a, g2); acc8(a, g3);
            acc8(a, g4); acc8(a, g5); acc8(a, g6); acc8(a, g7);
        }
    }
#pragma unroll
    for (int k = 0; k < 8; ++k) a[k] += __shfl_xor(a[k], 2);
    int nl = t >> 2;
    if (node >= 0 && p == 0) {
        float din = dinv[node];
        int4 sv = tab[(size_t)node * 2 + jj];
        const __half2* h = reinterpret_cast<const __half2*>(&sv);
        float2 f0 = __half22float2(h[0]), f1 = __half22float2(h[1]);
        float2 f2 = __half22float2(h[2]), f3 = __half22float2(h[3]);
        float s8[8] = { f0.x, f0.y, f1.x, f1.y, f2.x, f2.y, f3.x, f3.y };
        float v[8];
#pragma unroll
        for (int k = 0; k < 8; ++k) v[k] = din * (a[k] + s8[k]);
        *reinterpret_cast<float4*>(&feat[nl * 20 + jj * 8])     = make_float4(v[0], v[1], v[2], v[3]);
        *reinterpret_cast<float4*>(&feat[nl * 20 + jj * 8 + 4]) = make_float4(v[4], v[5], v[6], v[7]);
    }
    __syncthreads();
    float4 f0 = *reinterpret_cast<const float4*>(&feat[nl * 20]);
    float4 f1 = *reinterpret_cast<const float4*>(&feat[nl * 20 + 4]);
    float4 f2 = *reinterpret_cast<const float4*>(&feat[nl * 20 + 8]);
    float4 f3 = *reinterpret_cast<const float4*>(&feat[nl * 20 + 12]);
    int cb = (t & 3) * 10;
    float z[10];
#pragma unroll
    for (int j = 0; j < 10; ++j) {
        const float4* wr = reinterpret_cast<const float4*>(&w2t[(cb + j) * 20]);
        float4 w0 = wr[0], w1 = wr[1], w2v = wr[2], w3 = wr[3];
        float acc = b2s[cb + j];
        acc = fmaf(f0.x, w0.x, acc); acc = fmaf(f0.y, w0.y, acc);
        acc = fmaf(f0.z, w0.z, acc); acc = fmaf(f0.w, w0.w, acc);
        acc = fmaf(f1.x, w1.x, acc); acc = fmaf(f1.y, w1.y, acc);
        acc = fmaf(f1.z, w1.z, acc); acc = fmaf(f1.w, w1.w, acc);
        acc = fmaf(f2.x, w2v.x, acc); acc = fmaf(f2.y, w2v.y, acc);
        acc = fmaf(f2.z, w2v.z, acc); acc = fmaf(f2.w, w2v.w, acc);
        acc = fmaf(f3.x, w3.x, acc); acc = fmaf(f3.y, w3.y, acc);
        acc = fmaf(f3.z, w3.z, acc); acc = fmaf(f3.w, w3.w, acc);
        z[j] = acc;
    }
    float m = z[0];
#pragma unroll
    for (int j = 1; j < 10; ++j) m = fmaxf(m, z[j]);
    m = fmaxf(m, __shfl_xor(m, 1));
    m = fmaxf(m, __shfl_xor(m, 2));
    float s = 0.0f;
#pragma unroll
    for (int j = 0; j < 10; ++j) s += expf(z[j] - m);
    s += __shfl_xor(s, 1);
    s += __shfl_xor(s, 2);
    float lse = m + logf(s);
    if (node >= 0) {
        float2* o = reinterpret_cast<float2*>(out + (size_t)node * 40 + cb);
#pragma unroll
        for (int j = 0; j < 5; ++j)
            o[j] = make_float2(z[2 * j] - lse, z[2 * j + 1] - lse);
    }
}

extern "C" void kernel_launch(void* const* d_in, const int* in_sizes, int n_in,
                              void* d_out, int out_size, void* d_ws, size_t ws_size,
                              hipStream_t stream) {
    const float* x     = (const float*)d_in[0];
    const int*   src   = (const int*)d_in[1];
    const int*   dst   = (const int*)d_in[2];
    const float* W1    = (const float*)d_in[3];
    const float* b1    = (const float*)d_in[4];
    const float* gamma = (const float*)d_in[5];
    const float* beta  = (const float*)d_in[6];
    const float* Wl    = (const float*)d_in[7];
    const float* bl    = (const float*)d_in[8];
    const float* W2    = (const float*)d_in[9];
    const float* b2    = (const float*)d_in[10];
    float* out = (float*)d_out;

    int n = in_sizes[0] / F_IN;   // 100000
    int e = in_sizes[1];          // 3200000
    int nbkt = (n + RB - 1) >> RB_BITS;   // 391
    int nAlign = (n + 15) & ~15;
    int nG = nbkt * RB;                                      // ordered-node slots
    size_t bktB = (size_t)nbkt << CAPB_BITS;                 // fixed-capacity entries (temp & csr)
    size_t hTileB = (size_t)nAlign * H * 4;                  // 6.4 MB
    size_t unionB = bktB * 4;                                // temp (25.6 MB)
    if (unionB < hTileB) unionB = hTileB;                    // also holds hbuf later

    char* wsb = (char*)d_ws;
    int*    csr      = (int*)wsb;      wsb += (bktB + 64) * 4;
    char*   uni      = wsb;            wsb += unionB;
    int*    temp     = (int*)uni;                  // alive: k_bin .. k_sort
    float*  hbuf     = (float*)uni;                // alive: k_gather1 .. k_hops
    int*    ostart   = (int*)wsb;      wsb += (size_t)(nG + 16) * 4;
    int*    oend     = (int*)wsb;      wsb += (size_t)(nG + 16) * 4;
    int*    onode    = (int*)wsb;      wsb += (size_t)(nG + 16) * 4;
    float*  dinv     = (float*)wsb;    wsb += (size_t)nAlign * 4;
    int*    gcur     = (int*)wsb;      wsb += NBKT_MAX * 4;
    float*  stats    = (float*)wsb;    wsb += 64 * 4;
    __half* h1h      = (__half*)wsb;   wsb += (size_t)(nAlign + NDUMMY + 16) * H * 2;
    __half* hh       = (__half*)wsb;   wsb += (size_t)(nAlign + NDUMMY + 16) * H * 2;

    k_zero<<<64, 256, 0, stream>>>(gcur, stats, h1h, hh, n);
    k_bin<<<(e + BIN_CHUNK - 1) / BIN_CHUNK, 512, 0, stream>>>(src, dst, gcur, temp, e);
    k_sort<<<nbkt, 512, 0, stream>>>(gcur, temp, csr, ostart, oend, onode, dinv, n);
    k_mm1<<<(n + 15) / 16, 256, 0, stream>>>(x, W1, dinv, h1h, n);
    k_gather1<<<nbkt * 4, 256, 0, stream>>>(ostart, oend, onode, csr, h1h, dinv, b1, hbuf, stats, n);
    k_hops<<<(n + 255) / 256, 256, 0, stream>>>(hbuf, hh, stats, gamma, beta, Wl, bl, dinv, n, (float)n);
    k_g2f<<<nbkt * 4, 256, 0, stream>>>(ostart, oend, onode, csr, hh, dinv, W2, b2, out, n);
}